// Round 5
// baseline (1505.986 us; speedup 1.0000x reference)
//
#include <hip/hip_runtime.h>
#include <math.h>

#define B_ 4
#define H_ 8
#define L_ 1520
#define DM_ 512
#define DFF_ 2048
#define SK_ 40
#define ML_ (B_*L_)   /* 6080 rows */
#define MP_ 6144      /* padded rows for MFMA GEMM */
#define LP_ 1536      /* padded key count for V^T */

typedef unsigned short u16;
typedef short s8v __attribute__((ext_vector_type(8)));
typedef float f4 __attribute__((ext_vector_type(4)));

__device__ __forceinline__ u16 f2b(float x) {
  union { float f; unsigned u; } c; c.f = x;
  unsigned r = c.u + 0x7FFFu + ((c.u >> 16) & 1u);
  return (u16)(r >> 16);
}
__device__ __forceinline__ float b2f(u16 h) {
  union { unsigned u; float f; } c; c.u = ((unsigned)h) << 16;
  return c.f;
}
__device__ __forceinline__ float gelu_tanh(float x) {
  float x3 = x * x * x;
  return 0.5f * x * (1.f + tanhf(0.79788456080286536f * (x + 0.044715f * x3)));
}

// ---------------- positional encoding (double precision to match numpy) ----
__global__ __launch_bounds__(256) void pe_kernel(float* __restrict__ pe) {
  int idx = blockIdx.x * 256 + threadIdx.x;
  if (idx >= L_ * DM_) return;
  int pos = idx / DM_, i = idx % DM_;
  double expo = (double)(2 * (i / 2)) / (double)DM_;
  double ang = (double)pos / pow(10000.0, expo);
  pe[idx] = (i & 1) ? (float)cos(ang) : (float)sin(ang);
}

// ---------------- x = inflow[:,2:14].reshape (contiguous slice) -------------
__global__ __launch_bounds__(256) void extract_x(const float* __restrict__ inflow,
                                                 float* __restrict__ X) {
  int idx = blockIdx.x * 256 + threadIdx.x;
  if (idx >= ML_ * 12) return;
  int b = idx / (L_ * 12);
  int rem = idx - b * (L_ * 12);
  X[idx] = inflow[(size_t)b * 14 * L_ + 2 * L_ + rem];
}

// ---------------- weight convert + transpose: W[K][N] -> bf16 Wt[N][K] ------
__global__ __launch_bounds__(256) void cvt_wt(const float* __restrict__ W,
                                              u16* __restrict__ Wt, int K, int N) {
  int idx = blockIdx.x * 256 + threadIdx.x;
  int n = idx / K, k = idx % K;
  Wt[idx] = f2b(W[(size_t)k * N + n]);
}

// ---------------- activation fp32[6080][512] -> bf16[6144][512], pad 0 ------
__global__ __launch_bounds__(256) void cvt_act(const float* __restrict__ Xf,
                                               u16* __restrict__ Xb) {
  int idx = blockIdx.x * 256 + threadIdx.x;
  int row = idx >> 9;
  Xb[idx] = (row < ML_) ? f2b(Xf[idx]) : 0;
}

// ---------------- generic fp32 GEMM (small shapes only) ---------------------
__global__ __launch_bounds__(256) void gemm_f32(
    const float* __restrict__ A, const float* __restrict__ Bm,
    const float* __restrict__ bias, const float* __restrict__ res,
    float* __restrict__ C, int M, int N, int K, int res_mod, int act) {
  __shared__ float As[16][65];
  __shared__ float Bs[16][64];
  int bm = blockIdx.y * 64, bn = blockIdx.x * 64;
  int tid = threadIdx.x;
  int tx = tid % 16, ty = tid / 16;
  float acc[4][4] = {};
  for (int k0 = 0; k0 < K; k0 += 16) {
#pragma unroll
    for (int i = 0; i < 4; ++i) {
      int idx = tid + i * 256;
      int r = idx / 16, c = idx % 16;
      int gm = bm + r, gk = k0 + c;
      As[c][r] = (gm < M && gk < K) ? A[(size_t)gm * K + gk] : 0.f;
    }
#pragma unroll
    for (int i = 0; i < 4; ++i) {
      int idx = tid + i * 256;
      int r = idx / 64, c = idx % 64;
      int gk = k0 + r, gn = bn + c;
      Bs[r][c] = (gk < K && gn < N) ? Bm[(size_t)gk * N + gn] : 0.f;
    }
    __syncthreads();
#pragma unroll
    for (int kk = 0; kk < 16; ++kk) {
      float a[4], b[4];
#pragma unroll
      for (int i = 0; i < 4; ++i) a[i] = As[kk][ty + 16 * i];
#pragma unroll
      for (int j = 0; j < 4; ++j) b[j] = Bs[kk][tx + 16 * j];
#pragma unroll
      for (int i = 0; i < 4; ++i)
#pragma unroll
        for (int j = 0; j < 4; ++j) acc[i][j] += a[i] * b[j];
    }
    __syncthreads();
  }
#pragma unroll
  for (int i = 0; i < 4; ++i) {
    int gm = bm + ty + 16 * i;
    if (gm >= M) continue;
#pragma unroll
    for (int j = 0; j < 4; ++j) {
      int gn = bn + tx + 16 * j;
      if (gn >= N) continue;
      float v = acc[i][j];
      if (bias) v += bias[gn];
      if (res) v += res[(size_t)(gm % res_mod) * N + gn];
      if (act == 1) v = gelu_tanh(v);
      else if (act == 2) v = fmaxf(v, 0.f);
      C[(size_t)gm * N + gn] = v;
    }
  }
}

// ---------------- bf16 MFMA GEMM with global_load_lds staging ---------------
__global__ __launch_bounds__(256) void gemm_bf16(
    const u16* __restrict__ A, const u16* __restrict__ Bt,
    const float* __restrict__ bias, const float* __restrict__ res,
    float* __restrict__ Cf, u16* __restrict__ Cb,
    int N, int K, int act) {
  __shared__ __align__(16) u16 As[128 * 32];
  __shared__ __align__(16) u16 Bs[128 * 32];
  const int t = threadIdx.x, w = t >> 6, lane = t & 63;
  const int lg = lane >> 4, li = lane & 15;
  const int bm = blockIdx.y * 128, bn = blockIdx.x * 128;
  const int wr = (w >> 1) * 64, wc = (w & 1) * 64;
  f4 acc[4][4];
#pragma unroll
  for (int i = 0; i < 4; ++i)
#pragma unroll
    for (int j = 0; j < 4; ++j) acc[i][j] = f4{0.f, 0.f, 0.f, 0.f};
  const int r0 = w * 32 + (lane >> 2);
  const int ps = lane & 3;
  for (int k0 = 0; k0 < K; k0 += 32) {
#pragma unroll
    for (int j = 0; j < 2; ++j) {
      int r = r0 + j * 16;
      int ls = ps ^ ((r >> 1) & 3);
      __builtin_amdgcn_global_load_lds(
          (const __attribute__((address_space(1))) void*)(A + (size_t)(bm + r) * K + k0 + ls * 8),
          (__attribute__((address_space(3))) void*)(As + (w * 32 + j * 16) * 32),
          16, 0, 0);
      __builtin_amdgcn_global_load_lds(
          (const __attribute__((address_space(1))) void*)(Bt + (size_t)(bn + r) * K + k0 + ls * 8),
          (__attribute__((address_space(3))) void*)(Bs + (w * 32 + j * 16) * 32),
          16, 0, 0);
    }
    __syncthreads();
    s8v af[4], bf[4];
#pragma unroll
    for (int f = 0; f < 4; ++f) {
      int ra = wr + f * 16 + li;
      int rb = wc + f * 16 + li;
      af[f] = *(const s8v*)(As + ra * 32 + ((lg ^ ((ra >> 1) & 3)) * 8));
      bf[f] = *(const s8v*)(Bs + rb * 32 + ((lg ^ ((rb >> 1) & 3)) * 8));
    }
#pragma unroll
    for (int fi = 0; fi < 4; ++fi)
#pragma unroll
      for (int fj = 0; fj < 4; ++fj)
        acc[fi][fj] = __builtin_amdgcn_mfma_f32_16x16x32_bf16(af[fi], bf[fj], acc[fi][fj], 0, 0, 0);
    __syncthreads();
  }
#pragma unroll
  for (int fi = 0; fi < 4; ++fi)
#pragma unroll
    for (int fj = 0; fj < 4; ++fj)
#pragma unroll
      for (int r = 0; r < 4; ++r) {
        int row = bm + wr + fi * 16 + lg * 4 + r;
        int col = bn + wc + fj * 16 + li;
        float v = acc[fi][fj][r] + bias[col];
        if (res && row < ML_) v += res[(size_t)row * N + col];
        if (act == 1) v = gelu_tanh(v);
        if (Cf && row < ML_) Cf[(size_t)row * N + col] = v;
        if (Cb) Cb[(size_t)row * N + col] = f2b(v);
      }
}

// ---------------- layernorm: wave per row, vectorized -----------------------
__global__ __launch_bounds__(256) void layernorm_ip(float* __restrict__ Xb,
                                                    const float* __restrict__ g,
                                                    const float* __restrict__ bta,
                                                    u16* __restrict__ outb) {
  int row = blockIdx.x * 4 + (threadIdx.x >> 6);
  int lane = threadIdx.x & 63;
  float* x = Xb + (size_t)row * DM_;
  f4 a = *(f4*)(x + lane * 8);
  f4 b = *(f4*)(x + lane * 8 + 4);
  float s = a[0] + a[1] + a[2] + a[3] + b[0] + b[1] + b[2] + b[3];
  for (int off = 32; off; off >>= 1) s += __shfl_xor(s, off);
  float mu = s * (1.f / 512.f);
  float vs = 0.f;
#pragma unroll
  for (int i = 0; i < 4; ++i) { a[i] -= mu; b[i] -= mu; vs += a[i] * a[i] + b[i] * b[i]; }
  for (int off = 32; off; off >>= 1) vs += __shfl_xor(vs, off);
  float rs = rsqrtf(vs * (1.f / 512.f) + 1e-5f);
  f4 g0 = *(const f4*)(g + lane * 8), g1 = *(const f4*)(g + lane * 8 + 4);
  f4 c0 = *(const f4*)(bta + lane * 8), c1 = *(const f4*)(bta + lane * 8 + 4);
  u16 ob[8];
#pragma unroll
  for (int i = 0; i < 4; ++i) {
    float r1 = a[i] * rs * g0[i] + c0[i]; x[lane * 8 + i] = r1;     ob[i] = f2b(r1);
    float r2 = b[i] * rs * g1[i] + c1[i]; x[lane * 8 + 4 + i] = r2; ob[4 + i] = f2b(r2);
  }
  *(s8v*)(outb + (size_t)row * DM_ + lane * 8) = *(s8v*)ob;
}

// ---------------- ProbSparse sparsity measure M (bf16 qkv) ------------------
__global__ __launch_bounds__(256) void probM(const u16* __restrict__ qkv,
                                             const int* __restrict__ sidx,
                                             float* __restrict__ Mout) {
  int wid = threadIdx.x / 64, lane = threadIdx.x % 64;
  int g = blockIdx.x * 4 + wid;
  int l = g % L_;
  int bh = g / L_;
  int h = bh % H_, b = bh / H_;
  __shared__ float qs[4][64];
  qs[wid][lane] = b2f(qkv[((size_t)b * L_ + l) * 1536 + h * 64 + lane]);
  __syncthreads();
  float dot = 0.f;
  if (lane < SK_) {
    int ks = sidx[l * SK_ + lane];
    const u16* kr = qkv + ((size_t)b * L_ + ks) * 1536 + 512 + h * 64;
#pragma unroll
    for (int j = 0; j < 8; ++j) {
      s8v v = *(const s8v*)(kr + j * 8);
#pragma unroll
      for (int i = 0; i < 8; ++i) dot += qs[wid][j * 8 + i] * b2f((u16)v[i]);
    }
  }
  float vmax = (lane < SK_) ? dot : -INFINITY;
  float vsum = (lane < SK_) ? dot : 0.f;
  for (int off = 32; off; off >>= 1) {
    vmax = fmaxf(vmax, __shfl_xor(vmax, off));
    vsum += __shfl_xor(vsum, off);
  }
  if (lane == 0) Mout[g] = vmax - vsum / (float)L_;
}

// ---------------- radix-select top-40 (matches lax.top_k selection set) -----
__global__ __launch_bounds__(256) void radix_topk(const float* __restrict__ Mv,
                                                  int* __restrict__ top) {
  const int bh = blockIdx.x;
  const int t = threadIdx.x;
  const int base = t * 6;
  unsigned key[6];
#pragma unroll
  for (int i = 0; i < 6; ++i) {
    int ix = base + i;
    unsigned k = 0u;
    if (ix < L_) {
      union { float f; unsigned u; } c; c.f = Mv[(size_t)bh * L_ + ix];
      k = c.u ^ ((c.u & 0x80000000u) ? 0xFFFFFFFFu : 0x80000000u);
    }
    key[i] = k;
  }
  __shared__ int wred[4];
  __shared__ int s_a[256], s_b[256];
  unsigned prefix = 0u;
  for (int b = 31; b >= 0; --b) {
    unsigned cand = prefix | (1u << b);
    int c = 0;
#pragma unroll
    for (int i = 0; i < 6; ++i) c += (key[i] >= cand);
    for (int off = 32; off; off >>= 1) c += __shfl_xor(c, off);
    if ((t & 63) == 0) wred[t >> 6] = c;
    __syncthreads();
    int tot = wred[0] + wred[1] + wred[2] + wred[3];
    if (tot >= SK_) prefix = cand;
    __syncthreads();
  }
  const unsigned T = prefix;
  int gt = 0, tie = 0;
#pragma unroll
  for (int i = 0; i < 6; ++i) { gt += (key[i] > T); tie += (key[i] == T); }
  s_a[t] = gt; s_b[t] = tie;
  __syncthreads();
  for (int off = 1; off < 256; off <<= 1) {
    int va = (t >= off) ? s_a[t - off] : 0;
    int vb = (t >= off) ? s_b[t - off] : 0;
    __syncthreads();
    s_a[t] += va; s_b[t] += vb;
    __syncthreads();
  }
  const int n_strict = s_a[255];
  const int gt_base = s_a[t] - gt;
  const int tie_base = s_b[t] - tie;
  const int need = SK_ - n_strict;
  int lgt = 0, ltie = 0;
#pragma unroll
  for (int i = 0; i < 6; ++i) {
    int ix = base + i;
    if (key[i] > T) {
      top[bh * SK_ + gt_base + lgt] = ix; ++lgt;
    } else if (key[i] == T) {
      int r = tie_base + ltie; ++ltie;
      if (r < need) top[bh * SK_ + n_strict + r] = ix;
    }
  }
}

// ---------------- V^T build: VT[bh][64][LP_] from V columns -----------------
__global__ __launch_bounds__(256) void transpose_v(const u16* __restrict__ src,
                                                   int stride, int voff0,
                                                   u16* __restrict__ VT) {
  int kt = blockIdx.x % 24, bh = blockIdx.x / 24;
  int h = bh & 7, b = bh >> 3;
  int kb = kt * 64;
  __shared__ u16 tile[64][72];
  int t = threadIdx.x;
#pragma unroll
  for (int rr = 0; rr < 2; ++rr) {
    int slot = rr * 256 + t;
    int key = slot >> 3, d = (slot & 7) * 8;
    int gk = kb + key; if (gk >= L_) gk = L_ - 1;
    s8v v = *(const s8v*)(src + (size_t)(b * L_ + gk) * stride + voff0 + h * 64 + d);
    *(s8v*)(&tile[key][d]) = v;
  }
  __syncthreads();
  int dim = t >> 2, k0 = (t & 3) * 16;
  u16 buf[16];
#pragma unroll
  for (int i = 0; i < 16; ++i) {
    int key = k0 + i;
    buf[i] = (kb + key < L_) ? tile[key][dim] : (u16)0;
  }
  *(s8v*)(VT + ((size_t)bh * 64 + dim) * LP_ + kb + k0) = *(s8v*)buf;
  *(s8v*)(VT + ((size_t)bh * 64 + dim) * LP_ + kb + k0 + 8) = *(s8v*)(buf + 8);
}

// ---------------- pipelined barrier-free MFMA flash attention ----------------
// MODE 0: cross attn, 2-way K-split. blockIdx = bh*48 + qb*2 + sp.
//         Writes UNNORMALIZED bf16 partials ctx-shaped: sp0->PO0, sp1->PO1,
//         plus PM/PL[pid*64+qloc], pid=(bh*24+qb)*2+sp.
// MODE 1: prob attn (top-40 rows), 8 splits x 3 tiles; f32 partials POf.
template<int MODE>
__global__ __launch_bounds__(256) void flash_attn(
    const u16* __restrict__ Qm, const u16* __restrict__ Kg,
    const u16* __restrict__ VT, const int* __restrict__ top,
    float* __restrict__ POf, u16* PO0, u16* PO1,
    float* __restrict__ PM, float* __restrict__ PL) {
  constexpr int QSTR = (MODE == 0) ? 512 : 1536;
  constexpr int KSTR = (MODE == 0) ? 512 : 1536;
  constexpr int TILES = (MODE == 0) ? 12 : 3;
  __shared__ __align__(16) u16 P_lds[4][16 * 72];
  int bh, sp, qb;
  if (MODE == 0) {
    bh = blockIdx.x / 48; qb = (blockIdx.x >> 1) % 24; sp = blockIdx.x & 1;
  } else {
    bh = blockIdx.x / 8; sp = blockIdx.x % 8; qb = 0;
  }
  const int h = bh & 7, b = bh >> 3;
  const int qoff = h * 64;
  const int koff = ((MODE == 0) ? 0 : 512) + h * 64;
  const int t = threadIdx.x, w = t >> 6, lane = t & 63;
  const int lg = lane >> 4, li = lane & 15;
  const u16* vt = VT + (size_t)bh * 64 * LP_;

  int qrow;
  if (MODE == 0) {
    int q = qb * 64 + w * 16 + li;
    qrow = b * L_ + ((q < L_) ? q : (L_ - 1));
  } else {
    int u = w * 16 + li; if (u >= SK_) u = SK_ - 1;
    qrow = b * L_ + top[bh * SK_ + u];
  }
  s8v qf0 = *(const s8v*)(Qm + (size_t)qrow * QSTR + qoff + lg * 8);
  s8v qf1 = *(const s8v*)(Qm + (size_t)qrow * QSTR + qoff + 32 + lg * 8);

  f4 o[4];
#pragma unroll
  for (int n = 0; n < 4; ++n) o[n] = f4{0.f, 0.f, 0.f, 0.f};
  float m_run[4] = {-INFINITY, -INFINITY, -INFINITY, -INFINITY};
  float l_run[4] = {0.f, 0.f, 0.f, 0.f};
  const int kt0 = sp * TILES;

  auto LOADK = [&](int kt, s8v* kf) {
#pragma unroll
    for (int c = 0; c < 4; ++c) {
      int krow = kt * 64 + c * 16 + li; if (krow >= L_) krow = L_ - 1;
      const u16* kr = Kg + (size_t)(b * L_ + krow) * KSTR + koff;
      kf[c] = *(const s8v*)(kr + lg * 8);
      kf[4 + c] = *(const s8v*)(kr + 32 + lg * 8);
    }
  };

  auto BODY = [&](int kt, const s8v* kc, s8v* kn, bool pre) {
    const int kb = kt * 64;
    // S = Q @ K^T / 8
    f4 s[4];
#pragma unroll
    for (int c = 0; c < 4; ++c) {
      f4 z = f4{0.f, 0.f, 0.f, 0.f};
      z = __builtin_amdgcn_mfma_f32_16x16x32_bf16(qf0, kc[c], z, 0, 0, 0);
      z = __builtin_amdgcn_mfma_f32_16x16x32_bf16(qf1, kc[4 + c], z, 0, 0, 0);
      s[c] = z * 0.125f;
    }
    // prefetch next tile's K fragments (overlaps softmax + PV)
    if (pre) LOADK(kt + 1, kn);
    // prefetch this tile's V^T fragments (latency hidden under softmax)
    s8v vb[2][4];
#pragma unroll
    for (int ks = 0; ks < 2; ++ks)
#pragma unroll
      for (int n = 0; n < 4; ++n)
        vb[ks][n] = *(const s8v*)(vt + (size_t)(n * 16 + li) * LP_ + kb + ks * 32 + lg * 8);
    if (kb + 64 > L_) {
#pragma unroll
      for (int c = 0; c < 4; ++c)
        if (kb + c * 16 + li >= L_) {
          s[c][0] = -INFINITY; s[c][1] = -INFINITY; s[c][2] = -INFINITY; s[c][3] = -INFINITY;
        }
    }
    // online softmax per q-row
    float p[4][4];
#pragma unroll
    for (int r = 0; r < 4; ++r) {
      float tm = fmaxf(fmaxf(s[0][r], s[1][r]), fmaxf(s[2][r], s[3][r]));
      tm = fmaxf(tm, __shfl_xor(tm, 1));
      tm = fmaxf(tm, __shfl_xor(tm, 2));
      tm = fmaxf(tm, __shfl_xor(tm, 4));
      tm = fmaxf(tm, __shfl_xor(tm, 8));
      float mn = fmaxf(m_run[r], tm);
      float sc = __expf(m_run[r] - mn);
      float rs = 0.f;
#pragma unroll
      for (int c = 0; c < 4; ++c) { p[c][r] = __expf(s[c][r] - mn); rs += p[c][r]; }
      rs += __shfl_xor(rs, 1);
      rs += __shfl_xor(rs, 2);
      rs += __shfl_xor(rs, 4);
      rs += __shfl_xor(rs, 8);
      l_run[r] = l_run[r] * sc + rs;
      m_run[r] = mn;
#pragma unroll
      for (int n = 0; n < 4; ++n) o[n][r] *= sc;
    }
    // P -> per-wave LDS (no block barrier)
#pragma unroll
    for (int c = 0; c < 4; ++c)
#pragma unroll
      for (int r = 0; r < 4; ++r)
        P_lds[w][(lg * 4 + r) * 72 + c * 16 + li] = f2b(p[c][r]);
    // O += P @ V
#pragma unroll
    for (int ks = 0; ks < 2; ++ks) {
      s8v pa = *(const s8v*)(&P_lds[w][li * 72 + ks * 32 + lg * 8]);
#pragma unroll
      for (int n = 0; n < 4; ++n)
        o[n] = __builtin_amdgcn_mfma_f32_16x16x32_bf16(pa, vb[ks][n], o[n], 0, 0, 0);
    }
  };

  s8v ka[8], kb2[8];
  LOADK(kt0, ka);
#pragma unroll 1
  for (int ki = 0; ki < TILES; ki += 2) {
    BODY(kt0 + ki, ka, kb2, ki + 1 < TILES);
    if (ki + 1 < TILES) BODY(kt0 + ki + 1, kb2, ka, ki + 2 < TILES);
  }

  if (MODE == 0) {
    u16* PO = sp ? PO1 : PO0;
    const int pid = (bh * 24 + qb) * 2 + sp;
#pragma unroll
    for (int n = 0; n < 4; ++n)
#pragma unroll
      for (int r = 0; r < 4; ++r) {
        int q = qb * 64 + w * 16 + lg * 4 + r;
        if (q < L_)
          PO[((size_t)(b * L_ + q)) * DM_ + qoff + n * 16 + li] = f2b(o[n][r]);
      }
    if (li == 0) {
#pragma unroll
      for (int r = 0; r < 4; ++r) {
        PM[pid * 64 + w * 16 + lg * 4 + r] = m_run[r];
        PL[pid * 64 + w * 16 + lg * 4 + r] = l_run[r];
      }
    }
  } else {
    int base = (bh * 8 + sp) * 64;
#pragma unroll
    for (int n = 0; n < 4; ++n)
#pragma unroll
      for (int r = 0; r < 4; ++r)
        POf[((size_t)base + w * 16 + lg * 4 + r) * 64 + n * 16 + li] = o[n][r];
    if (li == 0) {
#pragma unroll
      for (int r = 0; r < 4; ++r) {
        PM[base + w * 16 + lg * 4 + r] = m_run[r];
        PL[base + w * 16 + lg * 4 + r] = l_run[r];
      }
    }
  }
}

// ---------------- combine 2-way cross partials (PO1 == ctxb, in place) ------
__global__ __launch_bounds__(256) void combine_cross(const u16* __restrict__ PO0,
                                                     const float* __restrict__ PM,
                                                     const float* __restrict__ PL,
                                                     u16* ctxb) {
  int idx = blockIdx.x * 256 + threadIdx.x;   // grid exact: ML_*DM_/256
  int row = idx >> 9, col = idx & 511;
  int b = row / L_, q = row - b * L_;
  int h = col >> 6;
  int bh = b * 8 + h, qbk = q >> 6, qi = q & 63;
  int p0 = ((bh * 24 + qbk) * 2) * 64 + qi;
  float m0 = PM[p0], m1 = PM[p0 + 64];
  float l0 = PL[p0], l1 = PL[p0 + 64];
  float M = fmaxf(m0, m1);
  float w0 = __expf(m0 - M), w1 = __expf(m1 - M);
  float inv = 1.f / (w0 * l0 + w1 * l1);
  float o0 = b2f(PO0[idx]);
  float o1 = b2f(ctxb[idx]);
  ctxb[idx] = f2b((w0 * o0 + w1 * o1) * inv);
}

// ---------------- combine split-K partials -> ctt ----------------------------
__global__ __launch_bounds__(256) void combine_prob(const float* __restrict__ PO,
                                                    const float* __restrict__ PM,
                                                    const float* __restrict__ PL,
                                                    float* __restrict__ ctt) {
  int bh = blockIdx.x;
  int t = threadIdx.x;
  int u = t >> 2, dg = (t & 3) * 16;
  if (u >= SK_) return;
  float M = -INFINITY;
  for (int s = 0; s < 8; ++s) M = fmaxf(M, PM[(bh * 8 + s) * 64 + u]);
  float wgt[8];
  float den = 0.f;
  for (int s = 0; s < 8; ++s) {
    wgt[s] = __expf(PM[(bh * 8 + s) * 64 + u] - M);
    den += wgt[s] * PL[(bh * 8 + s) * 64 + u];
  }
  float inv = 1.f / den;
  for (int d = dg; d < dg + 16; ++d) {
    float acc = 0.f;
    for (int s = 0; s < 8; ++s) acc += wgt[s] * PO[(((size_t)bh * 8 + s) * 64 + u) * 64 + d];
    ctt[((size_t)bh * SK_ + u) * 64 + d] = acc * inv;
  }
}

// ---------------- V mean over L per (b,h) -----------------------------------
__global__ __launch_bounds__(256) void vmean_k(const u16* __restrict__ qkv,
                                               float* __restrict__ vmean) {
  int bh = blockIdx.x;
  int h = bh % H_, b = bh / H_;
  int lane = threadIdx.x % 64, grp = threadIdx.x / 64;
  __shared__ float pv[4][64];
  float acc = 0.f;
  for (int k = grp; k < L_; k += 4)
    acc += b2f(qkv[((size_t)b * L_ + k) * 1536 + 1024 + h * 64 + lane]);
  pv[grp][lane] = acc;
  __syncthreads();
  if (threadIdx.x < 64)
    vmean[bh * 64 + threadIdx.x] =
        (pv[0][threadIdx.x] + pv[1][threadIdx.x] + pv[2][threadIdx.x] + pv[3][threadIdx.x]) / (float)L_;
}

// ---------------- ctx = broadcast vmean (bf16), then scatter top ------------
__global__ __launch_bounds__(256) void fill_ctx(const float* __restrict__ vmean,
                                                u16* __restrict__ ctxb) {
  int idx = blockIdx.x * 256 + threadIdx.x;
  int d = idx % 64;
  int h = (idx / 64) % H_;
  int b = idx / (L_ * DM_);
  ctxb[idx] = f2b(vmean[(b * H_ + h) * 64 + d]);
}

__global__ __launch_bounds__(256) void scatter_ctx(const float* __restrict__ ctt,
                                                   const int* __restrict__ top,
                                                   u16* __restrict__ ctxb) {
  int idx = blockIdx.x * 256 + threadIdx.x;
  int d = idx % 64;
  int u = (idx / 64) % SK_;
  int bh = idx / (64 * SK_);
  int h = bh % H_, b = bh / H_;
  int l = top[bh * SK_ + u];
  ctxb[((size_t)b * L_ + l) * DM_ + h * 64 + d] = f2b(ctt[idx]);
}

// ---------------- host side --------------------------------------------------
extern "C" void kernel_launch(void* const* d_in, const int* in_sizes, int n_in,
                              void* d_out, int out_size, void* d_ws, size_t ws_size,
                              hipStream_t stream) {
  const float* inflow   = (const float*)d_in[4];
  const float* W_emb_e  = (const float*)d_in[5];
  const float* b_emb_e  = (const float*)d_in[6];
  const float* W_emb_d  = (const float*)d_in[7];
  const float* b_emb_d  = (const float*)d_in[8];
  const float* enc_Wqkv = (const float*)d_in[9];
  const float* enc_bqkv = (const float*)d_in[10];
  const float* enc_Wo   = (const float*)d_in[11];
  const float* enc_bo   = (const float*)d_in[12];
  const float* enc_ln1g = (const float*)d_in[13];
  const float* enc_ln1b = (const float*)d_in[14];
  const float* enc_Wf1  = (const float*)d_in[15];
  const float* enc_bf1  = (const float*)d_in[16];
  const float* enc_Wf2  = (const float*)d_in[17];
  const float* enc_bf2  = (const float*)d_in[18];
  const float* enc_ln2g = (const float*)d_in[19];
  const float* enc_ln2b = (const float*)d_in[20];
  const float* enc_ng   = (const float*)d_in[21];
  const float* enc_nb   = (const float*)d_in[22];
  const float* dec_Wqkv = (const float*)d_in[23];
  const float* dec_bqkv = (const float*)d_in[24];
  const float* dec_Wo_s = (const float*)d_in[25];
  const float* dec_bo_s = (const float*)d_in[26];
  const float* dec_ln1g = (const float*)d_in[27];
  const float* dec_ln1b = (const float*)d_in[28];
  const float* dec_Wq_c = (const float*)d_in[29];
  const float* dec_bq_c = (const float*)d_in[30];
  const float* dec_Wkv  = (const float*)d_in[31];
  const float* dec_bkv  = (const float*)d_in[32];
  const float* dec_Wo_c = (const float*)d_in[33];
  const float* dec_bo_c = (const float*)d_in[34];
  const float* dec_ln2g = (const float*)d_in[35];
  const float* dec_ln2b = (const float*)d_in[36];
  const float* dec_Wf1  = (const float*)d_in[37];
  const float* dec_bf1  = (const float*)d_in[38];
  const float* dec_Wf2  = (const float*)d_in[39];
  const float* dec_bf2  = (const float*)d_in[40];
  const float* dec_ln3g = (const float*)d_in[41];
  const float* dec_ln3b = (const float*)d_in[42];
  const float* W_proj   = (const float*)d_in[43];
  const float* b_proj   = (const float*)d_in[44];
  const float* W1       = (const float*)d_in[45];
  const float* b1       = (const float*)d_in[46];
  const float* W3       = (const float*)d_in[47];
  const float* b3       = (const float*)d_in[48];
  const int*   samp     = (const int*)d_in[49];
  float* out = (float*)d_out;

  float* ws  = (float*)d_ws;
  float* PE  = ws;                       // 778240 f (dead after embeds -> PM/PL)
  float* X   = PE + 778240;              // 72960 f
  float* ACT = X + 72960;                // 3112960 f
  float* REG = ACT + 3112960;            // 6291456 f shared region
  float* MME = REG + 6291456;            // 48640 f
  float* CTT = MME + 48640;              // 81920 f
  float* VME = CTT + 81920;              // 2048 f
  int*   TOP = (int*)(VME + 2048);       // 1280 i
  float* TAIL = VME + 2048 + 1280;
  u16* ENCb = (u16*)TAIL;                       // 6144*512 u16
  u16* DECb = (u16*)(TAIL + 1572864);
  u16* CTXb = (u16*)(TAIL + 2 * 1572864);
  u16* WBF  = (u16*)(TAIL + 3 * 1572864);       // 10485760 u16

  // region overlays (prob phase)
  u16* QKVb = (u16*)REG;                 // [6144][1536]
  u16* FFb  = (u16*)REG;                 // [6144][2048]
  u16* VT   = (u16*)REG + 9437184;       // [32][64][1536] u16
  // region overlays (cross phase)
  u16* QCb  = (u16*)REG;                 // [6144][512]
  u16* Kc   = (u16*)REG + 3145728;       // [6144][512]
  u16* Vc   = (u16*)REG + 6291456;       // [6144][512]; becomes PO0 after transpose
  float* O12 = REG;                      // head overlays
  float* H1  = REG + 72960;
  // prob split-K partials overlay CTXb (rebuilt by fill_ctx afterwards)
  float* POp = (float*)CTXb;             // 32*8*64*64 f
  float* PMp = POp + 1048576;
  float* PLp = PMp + 16384;
  // cross partial stats in dead PE region
  float* PMc = PE;                       // 1536*64 f
  float* PLc = PE + 98304;

  u16* Wt_qkv_e0 = WBF + 0;
  u16* Wt_qkv_e1 = WBF + 786432;
  u16* Wt_o_e0   = WBF + 1572864;
  u16* Wt_o_e1   = WBF + 1835008;
  u16* Wt_f1_e0  = WBF + 2097152;
  u16* Wt_f1_e1  = WBF + 3145728;
  u16* Wt_f2_e0  = WBF + 4194304;
  u16* Wt_f2_e1  = WBF + 5242880;
  u16* Wt_qkv_d  = WBF + 6291456;
  u16* Wt_o_s    = WBF + 7077888;
  u16* Wt_q_c    = WBF + 7340032;
  u16* Wt_kv_c   = WBF + 7602176;
  u16* Wt_o_c    = WBF + 8126464;
  u16* Wt_f1_d   = WBF + 8388608;
  u16* Wt_f2_d   = WBF + 9437184;

  auto CW = [&](const float* src, u16* dst, int K, int N) {
    cvt_wt<<<(N * K) / 256, 256, 0, stream>>>(src, dst, K, N);
  };
  auto GB = [&](const u16* A, const u16* Bt, const float* bias, const float* res,
                float* Cf, u16* Cb, int N, int K, int act) {
    dim3 g(N / 128, MP_ / 128);
    gemm_bf16<<<g, 256, 0, stream>>>(A, Bt, bias, res, Cf, Cb, N, K, act);
  };
  auto GF = [&](const float* A, const float* Bm, const float* bias, const float* res,
                float* C, int M, int N, int K, int res_mod, int act) {
    dim3 g((N + 63) / 64, (M + 63) / 64);
    gemm_f32<<<g, 256, 0, stream>>>(A, Bm, bias, res, C, M, N, K, res_mod, act);
  };
  auto PROB = [&](const int* sidx) {
    probM<<<B_ * H_ * L_ / 4, 256, 0, stream>>>(QKVb, sidx, MME);
    radix_topk<<<B_ * H_, 256, 0, stream>>>(MME, TOP);
    transpose_v<<<B_ * H_ * 24, 256, 0, stream>>>(QKVb, 1536, 1024, VT);
    flash_attn<1><<<B_ * H_ * 8, 256, 0, stream>>>(QKVb, QKVb, VT, TOP, POp, nullptr, nullptr, PMp, PLp);
    combine_prob<<<B_ * H_, 256, 0, stream>>>(POp, PMp, PLp, CTT);
    vmean_k<<<B_ * H_, 256, 0, stream>>>(QKVb, VME);
    fill_ctx<<<ML_ * DM_ / 256, 256, 0, stream>>>(VME, CTXb);
    scatter_ctx<<<B_ * H_ * SK_ * 64 / 256, 256, 0, stream>>>(CTT, TOP, CTXb);
  };

  pe_kernel<<<(L_ * DM_ + 255) / 256, 256, 0, stream>>>(PE);
  extract_x<<<(ML_ * 12 + 255) / 256, 256, 0, stream>>>(inflow, X);

  CW(enc_Wqkv,                 Wt_qkv_e0, 512, 1536);
  CW(enc_Wqkv + 512 * 1536,    Wt_qkv_e1, 512, 1536);
  CW(enc_Wo,                   Wt_o_e0,   512, 512);
  CW(enc_Wo + 512 * 512,       Wt_o_e1,   512, 512);
  CW(enc_Wf1,                  Wt_f1_e0,  512, 2048);
  CW(enc_Wf1 + 512 * 2048,     Wt_f1_e1,  512, 2048);
  CW(enc_Wf2,                  Wt_f2_e0,  2048, 512);
  CW(enc_Wf2 + 2048 * 512,     Wt_f2_e1,  2048, 512);
  CW(dec_Wqkv,                 Wt_qkv_d,  512, 1536);
  CW(dec_Wo_s,                 Wt_o_s,    512, 512);
  CW(dec_Wq_c,                 Wt_q_c,    512, 512);
  CW(dec_Wkv,                  Wt_kv_c,   512, 1024);
  CW(dec_Wo_c,                 Wt_o_c,    512, 512);
  CW(dec_Wf1,                  Wt_f1_d,   512, 2048);
  CW(dec_Wf2,                  Wt_f2_d,   2048, 512);

  // ---------------- encoder ----------------
  GF(X, W_emb_e, b_emb_e, PE, ACT, ML_, DM_, 12, L_, 0);
  cvt_act<<<MP_ * DM_ / 256, 256, 0, stream>>>(ACT, ENCb);

  const u16* Wqkv_e[2] = {Wt_qkv_e0, Wt_qkv_e1};
  const u16* Wo_e[2]   = {Wt_o_e0, Wt_o_e1};
  const u16* Wf1_e[2]  = {Wt_f1_e0, Wt_f1_e1};
  const u16* Wf2_e[2]  = {Wt_f2_e0, Wt_f2_e1};
  for (int i = 0; i < 2; ++i) {
    GB(ENCb, Wqkv_e[i], enc_bqkv + i * 1536, nullptr, nullptr, QKVb, 1536, 512, 0);
    PROB(samp + (size_t)i * L_ * SK_);
    GB(CTXb, Wo_e[i], enc_bo + i * 512, ACT, ACT, nullptr, 512, 512, 0);
    layernorm_ip<<<ML_ / 4, 256, 0, stream>>>(ACT, enc_ln1g + i * 512, enc_ln1b + i * 512, ENCb);
    GB(ENCb, Wf1_e[i], enc_bf1 + i * 2048, nullptr, nullptr, FFb, 2048, 512, 1);
    GB(FFb, Wf2_e[i], enc_bf2 + i * 512, ACT, ACT, nullptr, 512, 2048, 0);
    layernorm_ip<<<ML_ / 4, 256, 0, stream>>>(ACT, enc_ln2g + i * 512, enc_ln2b + i * 512, ENCb);
  }
  layernorm_ip<<<ML_ / 4, 256, 0, stream>>>(ACT, enc_ng, enc_nb, ENCb);

  // ---------------- decoder ----------------
  GF(X, W_emb_d, b_emb_d, PE, ACT, ML_, DM_, 12, L_, 0);
  cvt_act<<<MP_ * DM_ / 256, 256, 0, stream>>>(ACT, DECb);
  GB(DECb, Wt_qkv_d, dec_bqkv, nullptr, nullptr, QKVb, 1536, 512, 0);
  PROB(samp + (size_t)2 * L_ * SK_);
  GB(CTXb, Wt_o_s, dec_bo_s, ACT, ACT, nullptr, 512, 512, 0);
  layernorm_ip<<<ML_ / 4, 256, 0, stream>>>(ACT, dec_ln1g, dec_ln1b, DECb);

  // cross attention: Q, K, V as separate [*,512] GEMMs; V buffer becomes PO0
  GB(DECb, Wt_q_c, dec_bq_c, nullptr, nullptr, QCb, 512, 512, 0);
  GB(ENCb, Wt_kv_c, dec_bkv, nullptr, nullptr, Kc, 512, 512, 0);
  GB(ENCb, Wt_kv_c + 512 * 512, dec_bkv + 512, nullptr, nullptr, Vc, 512, 512, 0);
  transpose_v<<<B_ * H_ * 24, 256, 0, stream>>>(Vc, 512, 0, VT);
  flash_attn<0><<<B_ * H_ * 48, 256, 0, stream>>>(QCb, Kc, VT, nullptr, nullptr, Vc, CTXb, PMc, PLc);
  combine_cross<<<ML_ * DM_ / 256, 256, 0, stream>>>(Vc, PMc, PLc, CTXb);
  GB(CTXb, Wt_o_c, dec_bo_c, ACT, ACT, nullptr, 512, 512, 0);
  layernorm_ip<<<ML_ / 4, 256, 0, stream>>>(ACT, dec_ln2g, dec_ln2b, DECb);

  GB(DECb, Wt_f1_d, dec_bf1, nullptr, nullptr, FFb, 2048, 512, 1);
  GB(FFb, Wt_f2_d, dec_bf2, ACT, ACT, nullptr, 512, 2048, 0);
  layernorm_ip<<<ML_ / 4, 256, 0, stream>>>(ACT, dec_ln3g, dec_ln3b, DECb);

  GF(ACT, W_proj, b_proj, X, O12, ML_, 12, DM_, ML_, 0);
  GF(O12, W1, b1, nullptr, H1, ML_, 128, 12, ML_, 2);
  GF(H1, W3, b3, nullptr, out, ML_, 3, 128, ML_, 0);
}

// Round 6
// 1151.683 us; speedup vs baseline: 1.3076x; 1.3076x over previous
//
#include <hip/hip_runtime.h>
#include <math.h>

#define B_ 4
#define H_ 8
#define L_ 1520
#define DM_ 512
#define DFF_ 2048
#define SK_ 40
#define ML_ (B_*L_)   /* 6080 rows */
#define MP_ 6144      /* padded rows for MFMA GEMM */
#define LP_ 1536      /* padded key count for V^T */

typedef unsigned short u16;
typedef short s8v __attribute__((ext_vector_type(8)));
typedef float f4 __attribute__((ext_vector_type(4)));

__device__ __forceinline__ u16 f2b(float x) {
  union { float f; unsigned u; } c; c.f = x;
  unsigned r = c.u + 0x7FFFu + ((c.u >> 16) & 1u);
  return (u16)(r >> 16);
}
__device__ __forceinline__ float b2f(u16 h) {
  union { unsigned u; float f; } c; c.u = ((unsigned)h) << 16;
  return c.f;
}
__device__ __forceinline__ float gelu_tanh(float x) {
  float x3 = x * x * x;
  return 0.5f * x * (1.f + tanhf(0.79788456080286536f * (x + 0.044715f * x3)));
}

// ---------------- positional encoding (double precision to match numpy) ----
__global__ __launch_bounds__(256) void pe_kernel(float* __restrict__ pe) {
  int idx = blockIdx.x * 256 + threadIdx.x;
  if (idx >= L_ * DM_) return;
  int pos = idx / DM_, i = idx % DM_;
  double expo = (double)(2 * (i / 2)) / (double)DM_;
  double ang = (double)pos / pow(10000.0, expo);
  pe[idx] = (i & 1) ? (float)cos(ang) : (float)sin(ang);
}

// ---------------- x = inflow[:,2:14].reshape (contiguous slice) -------------
__global__ __launch_bounds__(256) void extract_x(const float* __restrict__ inflow,
                                                 float* __restrict__ X) {
  int idx = blockIdx.x * 256 + threadIdx.x;
  if (idx >= ML_ * 12) return;
  int b = idx / (L_ * 12);
  int rem = idx - b * (L_ * 12);
  X[idx] = inflow[(size_t)b * 14 * L_ + 2 * L_ + rem];
}

// ---------------- fused weight convert+transpose into contiguous WBF --------
struct CvtArgs {
  const float* src[15];
  unsigned cum[16];
  unsigned lk[15];
};
__global__ __launch_bounds__(256) void cvt_all(CvtArgs a, u16* __restrict__ dst) {
  unsigned idx = blockIdx.x * 256 + threadIdx.x;   // grid exact: 10485760/256
  int s = 0;
#pragma unroll
  for (int i = 1; i < 15; ++i) s += (idx >= a.cum[i]);
  unsigned local = idx - a.cum[s];
  unsigned lk = a.lk[s];
  unsigned K = 1u << lk;
  unsigned N = (a.cum[s + 1] - a.cum[s]) >> lk;
  unsigned n = local >> lk, k = local & (K - 1);
  dst[idx] = f2b(a.src[s][(size_t)k * N + n]);
}

// ---------------- activation fp32[6080][512] -> bf16[6144][512], pad 0 ------
__global__ __launch_bounds__(256) void cvt_act(const float* __restrict__ Xf,
                                               u16* __restrict__ Xb) {
  int idx = blockIdx.x * 256 + threadIdx.x;
  int row = idx >> 9;
  Xb[idx] = (row < ML_) ? f2b(Xf[idx]) : 0;
}

// ---------------- generic fp32 GEMM (small shapes only) ---------------------
__global__ __launch_bounds__(256) void gemm_f32(
    const float* __restrict__ A, const float* __restrict__ Bm,
    const float* __restrict__ bias, const float* __restrict__ res,
    float* __restrict__ C, int M, int N, int K, int res_mod, int act) {
  __shared__ float As[16][65];
  __shared__ float Bs[16][64];
  int bm = blockIdx.y * 64, bn = blockIdx.x * 64;
  int tid = threadIdx.x;
  int tx = tid % 16, ty = tid / 16;
  float acc[4][4] = {};
  for (int k0 = 0; k0 < K; k0 += 16) {
#pragma unroll
    for (int i = 0; i < 4; ++i) {
      int idx = tid + i * 256;
      int r = idx / 16, c = idx % 16;
      int gm = bm + r, gk = k0 + c;
      As[c][r] = (gm < M && gk < K) ? A[(size_t)gm * K + gk] : 0.f;
    }
#pragma unroll
    for (int i = 0; i < 4; ++i) {
      int idx = tid + i * 256;
      int r = idx / 64, c = idx % 64;
      int gk = k0 + r, gn = bn + c;
      Bs[r][c] = (gk < K && gn < N) ? Bm[(size_t)gk * N + gn] : 0.f;
    }
    __syncthreads();
#pragma unroll
    for (int kk = 0; kk < 16; ++kk) {
      float a[4], b[4];
#pragma unroll
      for (int i = 0; i < 4; ++i) a[i] = As[kk][ty + 16 * i];
#pragma unroll
      for (int j = 0; j < 4; ++j) b[j] = Bs[kk][tx + 16 * j];
#pragma unroll
      for (int i = 0; i < 4; ++i)
#pragma unroll
        for (int j = 0; j < 4; ++j) acc[i][j] += a[i] * b[j];
    }
    __syncthreads();
  }
#pragma unroll
  for (int i = 0; i < 4; ++i) {
    int gm = bm + ty + 16 * i;
    if (gm >= M) continue;
#pragma unroll
    for (int j = 0; j < 4; ++j) {
      int gn = bn + tx + 16 * j;
      if (gn >= N) continue;
      float v = acc[i][j];
      if (bias) v += bias[gn];
      if (res) v += res[(size_t)(gm % res_mod) * N + gn];
      if (act == 1) v = gelu_tanh(v);
      else if (act == 2) v = fmaxf(v, 0.f);
      C[(size_t)gm * N + gn] = v;
    }
  }
}

// ---------------- bf16 MFMA GEMM, templated tile height ---------------------
// A [MP_][K] bf16, Bt [N][K] bf16, K%32==0, N%128==0. BM in {64,128}.
template<int BM>
__global__ __launch_bounds__(256) void gemm_bf16(
    const u16* __restrict__ A, const u16* __restrict__ Bt,
    const float* __restrict__ bias, const float* __restrict__ res,
    float* __restrict__ Cf, u16* __restrict__ Cb,
    int N, int K, int act) {
  __shared__ __align__(16) u16 As[BM * 32];
  __shared__ __align__(16) u16 Bs[128 * 32];
  constexpr int MI = BM / 32;
  const int t = threadIdx.x, w = t >> 6, lane = t & 63;
  const int lg = lane >> 4, li = lane & 15;
  const int bm = blockIdx.y * BM, bn = blockIdx.x * 128;
  const int wr = (w >> 1) * (BM / 2), wc = (w & 1) * 64;
  f4 acc[MI][4];
#pragma unroll
  for (int i = 0; i < MI; ++i)
#pragma unroll
    for (int j = 0; j < 4; ++j) acc[i][j] = f4{0.f, 0.f, 0.f, 0.f};
  const int rB = w * 32 + (lane >> 2);
  const int rA = (BM == 128) ? rB : (w * 16 + (lane >> 2));
  const int ps = lane & 3;
  for (int k0 = 0; k0 < K; k0 += 32) {
    if (BM == 128) {
#pragma unroll
      for (int j = 0; j < 2; ++j) {
        int r = rA + j * 16;
        int ls = ps ^ ((r >> 1) & 3);
        __builtin_amdgcn_global_load_lds(
            (const __attribute__((address_space(1))) void*)(A + (size_t)(bm + r) * K + k0 + ls * 8),
            (__attribute__((address_space(3))) void*)(As + (w * 32 + j * 16) * 32),
            16, 0, 0);
      }
    } else {
      int ls = ps ^ ((rA >> 1) & 3);
      __builtin_amdgcn_global_load_lds(
          (const __attribute__((address_space(1))) void*)(A + (size_t)(bm + rA) * K + k0 + ls * 8),
          (__attribute__((address_space(3))) void*)(As + (w * 16) * 32),
          16, 0, 0);
    }
#pragma unroll
    for (int j = 0; j < 2; ++j) {
      int r = rB + j * 16;
      int ls = ps ^ ((r >> 1) & 3);
      __builtin_amdgcn_global_load_lds(
          (const __attribute__((address_space(1))) void*)(Bt + (size_t)(bn + r) * K + k0 + ls * 8),
          (__attribute__((address_space(3))) void*)(Bs + (w * 32 + j * 16) * 32),
          16, 0, 0);
    }
    __syncthreads();
    s8v af[MI], bf[4];
#pragma unroll
    for (int f = 0; f < MI; ++f) {
      int ra = wr + f * 16 + li;
      af[f] = *(const s8v*)(As + ra * 32 + ((lg ^ ((ra >> 1) & 3)) * 8));
    }
#pragma unroll
    for (int f = 0; f < 4; ++f) {
      int rb = wc + f * 16 + li;
      bf[f] = *(const s8v*)(Bs + rb * 32 + ((lg ^ ((rb >> 1) & 3)) * 8));
    }
#pragma unroll
    for (int fi = 0; fi < MI; ++fi)
#pragma unroll
      for (int fj = 0; fj < 4; ++fj)
        acc[fi][fj] = __builtin_amdgcn_mfma_f32_16x16x32_bf16(af[fi], bf[fj], acc[fi][fj], 0, 0, 0);
    __syncthreads();
  }
#pragma unroll
  for (int fi = 0; fi < MI; ++fi)
#pragma unroll
    for (int fj = 0; fj < 4; ++fj)
#pragma unroll
      for (int r = 0; r < 4; ++r) {
        int row = bm + wr + fi * 16 + lg * 4 + r;
        int col = bn + wc + fj * 16 + li;
        float v = acc[fi][fj][r] + bias[col];
        if (res && row < ML_) v += res[(size_t)row * N + col];
        if (act == 1) v = gelu_tanh(v);
        if (Cf && row < ML_) Cf[(size_t)row * N + col] = v;
        if (Cb) Cb[(size_t)row * N + col] = f2b(v);
      }
}

// ---------------- layernorm: wave per row, vectorized -----------------------
__global__ __launch_bounds__(256) void layernorm_ip(float* __restrict__ Xb,
                                                    const float* __restrict__ g,
                                                    const float* __restrict__ bta,
                                                    u16* __restrict__ outb) {
  int row = blockIdx.x * 4 + (threadIdx.x >> 6);
  int lane = threadIdx.x & 63;
  float* x = Xb + (size_t)row * DM_;
  f4 a = *(f4*)(x + lane * 8);
  f4 b = *(f4*)(x + lane * 8 + 4);
  float s = a[0] + a[1] + a[2] + a[3] + b[0] + b[1] + b[2] + b[3];
  for (int off = 32; off; off >>= 1) s += __shfl_xor(s, off);
  float mu = s * (1.f / 512.f);
  float vs = 0.f;
#pragma unroll
  for (int i = 0; i < 4; ++i) { a[i] -= mu; b[i] -= mu; vs += a[i] * a[i] + b[i] * b[i]; }
  for (int off = 32; off; off >>= 1) vs += __shfl_xor(vs, off);
  float rs = rsqrtf(vs * (1.f / 512.f) + 1e-5f);
  f4 g0 = *(const f4*)(g + lane * 8), g1 = *(const f4*)(g + lane * 8 + 4);
  f4 c0 = *(const f4*)(bta + lane * 8), c1 = *(const f4*)(bta + lane * 8 + 4);
  u16 ob[8];
#pragma unroll
  for (int i = 0; i < 4; ++i) {
    float r1 = a[i] * rs * g0[i] + c0[i]; x[lane * 8 + i] = r1;     ob[i] = f2b(r1);
    float r2 = b[i] * rs * g1[i] + c1[i]; x[lane * 8 + 4 + i] = r2; ob[4 + i] = f2b(r2);
  }
  *(s8v*)(outb + (size_t)row * DM_ + lane * 8) = *(s8v*)ob;
}

// ---------------- ProbSparse sparsity measure M (bf16 qkv) ------------------
__global__ __launch_bounds__(256) void probM(const u16* __restrict__ qkv,
                                             const int* __restrict__ sidx,
                                             float* __restrict__ Mout) {
  int wid = threadIdx.x / 64, lane = threadIdx.x % 64;
  int g = blockIdx.x * 4 + wid;
  int l = g % L_;
  int bh = g / L_;
  int h = bh % H_, b = bh / H_;
  __shared__ float qs[4][64];
  qs[wid][lane] = b2f(qkv[((size_t)b * L_ + l) * 1536 + h * 64 + lane]);
  __syncthreads();
  float dot = 0.f;
  if (lane < SK_) {
    int ks = sidx[l * SK_ + lane];
    const u16* kr = qkv + ((size_t)b * L_ + ks) * 1536 + 512 + h * 64;
#pragma unroll
    for (int j = 0; j < 8; ++j) {
      s8v v = *(const s8v*)(kr + j * 8);
#pragma unroll
      for (int i = 0; i < 8; ++i) dot += qs[wid][j * 8 + i] * b2f((u16)v[i]);
    }
  }
  float vmax = (lane < SK_) ? dot : -INFINITY;
  float vsum = (lane < SK_) ? dot : 0.f;
  for (int off = 32; off; off >>= 1) {
    vmax = fmaxf(vmax, __shfl_xor(vmax, off));
    vsum += __shfl_xor(vsum, off);
  }
  if (lane == 0) Mout[g] = vmax - vsum / (float)L_;
}

// ---------------- radix-select top-40 (matches lax.top_k selection set) -----
__global__ __launch_bounds__(256) void radix_topk(const float* __restrict__ Mv,
                                                  int* __restrict__ top) {
  const int bh = blockIdx.x;
  const int t = threadIdx.x;
  const int base = t * 6;
  unsigned key[6];
#pragma unroll
  for (int i = 0; i < 6; ++i) {
    int ix = base + i;
    unsigned k = 0u;
    if (ix < L_) {
      union { float f; unsigned u; } c; c.f = Mv[(size_t)bh * L_ + ix];
      k = c.u ^ ((c.u & 0x80000000u) ? 0xFFFFFFFFu : 0x80000000u);
    }
    key[i] = k;
  }
  __shared__ int wred[4];
  __shared__ int s_a[256], s_b[256];
  unsigned prefix = 0u;
  for (int b = 31; b >= 0; --b) {
    unsigned cand = prefix | (1u << b);
    int c = 0;
#pragma unroll
    for (int i = 0; i < 6; ++i) c += (key[i] >= cand);
    for (int off = 32; off; off >>= 1) c += __shfl_xor(c, off);
    if ((t & 63) == 0) wred[t >> 6] = c;
    __syncthreads();
    int tot = wred[0] + wred[1] + wred[2] + wred[3];
    if (tot >= SK_) prefix = cand;
    __syncthreads();
  }
  const unsigned T = prefix;
  int gt = 0, tie = 0;
#pragma unroll
  for (int i = 0; i < 6; ++i) { gt += (key[i] > T); tie += (key[i] == T); }
  s_a[t] = gt; s_b[t] = tie;
  __syncthreads();
  for (int off = 1; off < 256; off <<= 1) {
    int va = (t >= off) ? s_a[t - off] : 0;
    int vb = (t >= off) ? s_b[t - off] : 0;
    __syncthreads();
    s_a[t] += va; s_b[t] += vb;
    __syncthreads();
  }
  const int n_strict = s_a[255];
  const int gt_base = s_a[t] - gt;
  const int tie_base = s_b[t] - tie;
  const int need = SK_ - n_strict;
  int lgt = 0, ltie = 0;
#pragma unroll
  for (int i = 0; i < 6; ++i) {
    int ix = base + i;
    if (key[i] > T) {
      top[bh * SK_ + gt_base + lgt] = ix; ++lgt;
    } else if (key[i] == T) {
      int r = tie_base + ltie; ++ltie;
      if (r < need) top[bh * SK_ + n_strict + r] = ix;
    }
  }
}

// ---------------- V^T build: VT[bh][64][LP_] from V columns -----------------
__global__ __launch_bounds__(256) void transpose_v(const u16* __restrict__ src,
                                                   int stride, int voff0,
                                                   u16* __restrict__ VT) {
  int kt = blockIdx.x % 24, bh = blockIdx.x / 24;
  int h = bh & 7, b = bh >> 3;
  int kb = kt * 64;
  __shared__ u16 tile[64][72];
  int t = threadIdx.x;
#pragma unroll
  for (int rr = 0; rr < 2; ++rr) {
    int slot = rr * 256 + t;
    int key = slot >> 3, d = (slot & 7) * 8;
    int gk = kb + key; if (gk >= L_) gk = L_ - 1;
    s8v v = *(const s8v*)(src + (size_t)(b * L_ + gk) * stride + voff0 + h * 64 + d);
    *(s8v*)(&tile[key][d]) = v;
  }
  __syncthreads();
  int dim = t >> 2, k0 = (t & 3) * 16;
  u16 buf[16];
#pragma unroll
  for (int i = 0; i < 16; ++i) {
    int key = k0 + i;
    buf[i] = (kb + key < L_) ? tile[key][dim] : (u16)0;
  }
  *(s8v*)(VT + ((size_t)bh * 64 + dim) * LP_ + kb + k0) = *(s8v*)buf;
  *(s8v*)(VT + ((size_t)bh * 64 + dim) * LP_ + kb + k0 + 8) = *(s8v*)(buf + 8);
}

// ---------------- swapped-operand MFMA flash attention -----------------------
// Computes S^T = K@Q^T per tile so each lane owns a full q-row slice:
// lane li = q, regs = 16 keys (c*16+lg*4+r). m/l are per-lane scalars; row
// reduce = in-reg tree + 2 shfls. PV: O^T = V^T @ P^T with P exchanged via
// 8 packed-u32 per-wave LDS stores + 2 b128 reads. Barrier-free.
// MODE 0: cross attn, 2-way K-split, blockIdx = bh*48 + qb*2 + sp.
// MODE 1: prob attn (top-40 rows), 8 splits x 3 tiles.
template<int MODE>
__global__ __launch_bounds__(256) void flash_attn(
    const u16* __restrict__ Qm, const u16* __restrict__ Kg,
    const u16* __restrict__ VT, const int* __restrict__ top,
    float* __restrict__ POf, u16* PO0, u16* PO1,
    float* __restrict__ PM, float* __restrict__ PL) {
  constexpr int QSTR = (MODE == 0) ? 512 : 1536;
  constexpr int KSTR = (MODE == 0) ? 512 : 1536;
  constexpr int TILES = (MODE == 0) ? 12 : 3;
  __shared__ __align__(16) unsigned Xch[4][576];   // per-wave exchange region
  int bh, sp, qb;
  if (MODE == 0) {
    bh = blockIdx.x / 48; qb = (blockIdx.x >> 1) % 24; sp = blockIdx.x & 1;
  } else {
    bh = blockIdx.x / 8; sp = blockIdx.x % 8; qb = 0;
  }
  const int h = bh & 7, b = bh >> 3;
  const int qoff = h * 64;
  const int koff = ((MODE == 0) ? 0 : 512) + h * 64;
  const int t = threadIdx.x, w = t >> 6, lane = t & 63;
  const int lg = lane >> 4, li = lane & 15;
  const u16* vt = VT + (size_t)bh * 64 * LP_;
  unsigned* xw = Xch[w];
  u16* xw16 = (u16*)xw;

  // Q as B-operand fragment: lane li = q column
  int qrow;
  if (MODE == 0) {
    int q = qb * 64 + w * 16 + li;
    qrow = b * L_ + ((q < L_) ? q : (L_ - 1));
  } else {
    int u = w * 16 + li; if (u >= SK_) u = SK_ - 1;
    qrow = b * L_ + top[bh * SK_ + u];
  }
  s8v qf0 = *(const s8v*)(Qm + (size_t)qrow * QSTR + qoff + lg * 8);
  s8v qf1 = *(const s8v*)(Qm + (size_t)qrow * QSTR + qoff + 32 + lg * 8);

  f4 o[4];                           // o[n][r] = O^T[d=n*16+lg*4+r][q=li]
#pragma unroll
  for (int n = 0; n < 4; ++n) o[n] = f4{0.f, 0.f, 0.f, 0.f};
  float m_run = -INFINITY, l_run = 0.f;   // per-lane (q=li)
  const int kt0 = sp * TILES;

#pragma unroll 1
  for (int ki = 0; ki < TILES; ++ki) {
    const int kb = (kt0 + ki) * 64;
    // K fragments as A-operand (rows = keys); same addresses as before
    s8v kf[4], kg[4];
#pragma unroll
    for (int c = 0; c < 4; ++c) {
      const u16* kr = Kg + (size_t)(b * L_ + kb + c * 16 + li) * KSTR + koff;
      kf[c] = *(const s8v*)(kr + lg * 8);
      kg[c] = *(const s8v*)(kr + 32 + lg * 8);
    }
    // S^T = K @ Q^T / 8 : s[c][r] = S[key=kb+c*16+lg*4+r][q=li]
    f4 s[4];
#pragma unroll
    for (int c = 0; c < 4; ++c) {
      f4 z = f4{0.f, 0.f, 0.f, 0.f};
      z = __builtin_amdgcn_mfma_f32_16x16x32_bf16(kf[c], qf0, z, 0, 0, 0);
      z = __builtin_amdgcn_mfma_f32_16x16x32_bf16(kg[c], qf1, z, 0, 0, 0);
      s[c] = z * 0.125f;
    }
    if (kb + 64 > L_) {
#pragma unroll
      for (int c = 0; c < 4; ++c)
#pragma unroll
        for (int r = 0; r < 4; ++r)
          if (kb + c * 16 + lg * 4 + r >= L_) s[c][r] = -INFINITY;
    }
    // in-register row max + 2 cross-lg shfls
    float tm = -INFINITY;
#pragma unroll
    for (int c = 0; c < 4; ++c)
      tm = fmaxf(tm, fmaxf(fmaxf(s[c][0], s[c][1]), fmaxf(s[c][2], s[c][3])));
    tm = fmaxf(tm, __shfl_xor(tm, 16));
    tm = fmaxf(tm, __shfl_xor(tm, 32));
    float mn = fmaxf(m_run, tm);
    float sc = __expf(m_run - mn);
    float p[4][4];
    float rs = 0.f;
#pragma unroll
    for (int c = 0; c < 4; ++c)
#pragma unroll
      for (int r = 0; r < 4; ++r) { p[c][r] = __expf(s[c][r] - mn); rs += p[c][r]; }
    rs += __shfl_xor(rs, 16);
    rs += __shfl_xor(rs, 32);
    l_run = l_run * sc + rs;
    m_run = mn;
#pragma unroll
    for (int n = 0; n < 4; ++n) o[n] *= sc;
    // pack P by key order into per-wave LDS: u32 idx = key>>1 = c*8+lg*2+rp
#pragma unroll
    for (int c = 0; c < 4; ++c)
#pragma unroll
      for (int rp = 0; rp < 2; ++rp) {
        unsigned v = (unsigned)f2b(p[c][2 * rp]) | ((unsigned)f2b(p[c][2 * rp + 1]) << 16);
        xw[li * 36 + c * 8 + lg * 2 + rp] = v;
      }
    // read B-operand fragments: keys ks*32+lg*8 .. +7  (16B aligned: li*144B)
    s8v pb0 = *(const s8v*)(xw + li * 36 + lg * 4);
    s8v pb1 = *(const s8v*)(xw + li * 36 + 16 + lg * 4);
    // O^T += V^T @ P^T
#pragma unroll
    for (int n = 0; n < 4; ++n) {
      s8v vb0 = *(const s8v*)(vt + (size_t)(n * 16 + li) * LP_ + kb + lg * 8);
      o[n] = __builtin_amdgcn_mfma_f32_16x16x32_bf16(vb0, pb0, o[n], 0, 0, 0);
    }
#pragma unroll
    for (int n = 0; n < 4; ++n) {
      s8v vb1 = *(const s8v*)(vt + (size_t)(n * 16 + li) * LP_ + kb + 32 + lg * 8);
      o[n] = __builtin_amdgcn_mfma_f32_16x16x32_bf16(vb1, pb1, o[n], 0, 0, 0);
    }
  }

  if (MODE == 0) {
    // per-wave LDS transpose [q][d], then coalesced unnormalized bf16 store
#pragma unroll
    for (int n = 0; n < 4; ++n)
#pragma unroll
      for (int r = 0; r < 4; ++r)
        xw16[li * 72 + n * 16 + lg * 4 + r] = f2b(o[n][r]);
    u16* PO = sp ? PO1 : PO0;
    const int pid = (bh * 24 + qb) * 2 + sp;
    int q_local = lane >> 2, d0 = (lane & 3) * 16;
    int q = qb * 64 + w * 16 + q_local;
    s8v v0 = *(const s8v*)(xw16 + q_local * 72 + d0);
    s8v v1 = *(const s8v*)(xw16 + q_local * 72 + d0 + 8);
    if (q < L_) {
      u16* dst = PO + ((size_t)(b * L_ + q)) * DM_ + qoff + d0;
      *(s8v*)dst = v0;
      *(s8v*)(dst + 8) = v1;
    }
    if (lg == 0) {
      PM[pid * 64 + w * 16 + li] = m_run;
      PL[pid * 64 + w * 16 + li] = l_run;
    }
  } else {
    int base = (bh * 8 + sp) * 64 + w * 16 + li;
#pragma unroll
    for (int n = 0; n < 4; ++n)
#pragma unroll
      for (int r = 0; r < 4; ++r)
        POf[(size_t)base * 64 + n * 16 + lg * 4 + r] = o[n][r];
    if (lg == 0) {
      PM[base] = m_run;
      PL[base] = l_run;
    }
  }
}

// ---------------- combine 2-way cross partials (PO1 == ctxb, in place) ------
__global__ __launch_bounds__(256) void combine_cross(const u16* __restrict__ PO0,
                                                     const float* __restrict__ PM,
                                                     const float* __restrict__ PL,
                                                     u16* ctxb) {
  int idx = blockIdx.x * 256 + threadIdx.x;   // grid exact: ML_*DM_/256
  int row = idx >> 9, col = idx & 511;
  int b = row / L_, q = row - b * L_;
  int h = col >> 6;
  int bh = b * 8 + h, qbk = q >> 6, qi = q & 63;
  int p0 = ((bh * 24 + qbk) * 2) * 64 + qi;
  float m0 = PM[p0], m1 = PM[p0 + 64];
  float l0 = PL[p0], l1 = PL[p0 + 64];
  float M = fmaxf(m0, m1);
  float w0 = __expf(m0 - M), w1 = __expf(m1 - M);
  float inv = 1.f / (w0 * l0 + w1 * l1);
  float o0 = b2f(PO0[idx]);
  float o1 = b2f(ctxb[idx]);
  ctxb[idx] = f2b((w0 * o0 + w1 * o1) * inv);
}

// ---------------- combine split-K partials -> ctt ----------------------------
__global__ __launch_bounds__(256) void combine_prob(const float* __restrict__ PO,
                                                    const float* __restrict__ PM,
                                                    const float* __restrict__ PL,
                                                    float* __restrict__ ctt) {
  int bh = blockIdx.x;
  int t = threadIdx.x;
  int u = t >> 2, dg = (t & 3) * 16;
  if (u >= SK_) return;
  float M = -INFINITY;
  for (int s = 0; s < 8; ++s) M = fmaxf(M, PM[(bh * 8 + s) * 64 + u]);
  float wgt[8];
  float den = 0.f;
  for (int s = 0; s < 8; ++s) {
    wgt[s] = __expf(PM[(bh * 8 + s) * 64 + u] - M);
    den += wgt[s] * PL[(bh * 8 + s) * 64 + u];
  }
  float inv = 1.f / den;
  for (int d = dg; d < dg + 16; ++d) {
    float acc = 0.f;
    for (int s = 0; s < 8; ++s) acc += wgt[s] * PO[(((size_t)bh * 8 + s) * 64 + u) * 64 + d];
    ctt[((size_t)bh * SK_ + u) * 64 + d] = acc * inv;
  }
}

// ---------------- V mean: 8-way partial + combine ---------------------------
__global__ __launch_bounds__(256) void vmean_part(const u16* __restrict__ qkv,
                                                  float* __restrict__ part) {
  int g = blockIdx.x;          // bh*8 + seg
  int bh = g >> 3, seg = g & 7;
  int h = bh & 7, b = bh >> 3;
  int lane = threadIdx.x & 63, grp = threadIdx.x >> 6;
  int k0 = seg * 190, k1 = k0 + 190;
  float acc = 0.f;
  for (int k = k0 + grp; k < k1; k += 4)
    acc += b2f(qkv[((size_t)b * L_ + k) * 1536 + 1024 + h * 64 + lane]);
  __shared__ float pv[4][64];
  pv[grp][lane] = acc;
  __syncthreads();
  if (threadIdx.x < 64)
    part[g * 64 + threadIdx.x] =
        pv[0][threadIdx.x] + pv[1][threadIdx.x] + pv[2][threadIdx.x] + pv[3][threadIdx.x];
}

__global__ __launch_bounds__(256) void vmean_comb(const float* __restrict__ part,
                                                  float* __restrict__ vmean) {
  int idx = blockIdx.x * 256 + threadIdx.x;   // 2048
  int bh = idx >> 6, d = idx & 63;
  float s = 0.f;
#pragma unroll
  for (int seg = 0; seg < 8; ++seg) s += part[(bh * 8 + seg) * 64 + d];
  vmean[idx] = s / (float)L_;
}

// ---------------- ctx = broadcast vmean (bf16), then scatter top ------------
__global__ __launch_bounds__(256) void fill_ctx(const float* __restrict__ vmean,
                                                u16* __restrict__ ctxb) {
  int idx = blockIdx.x * 256 + threadIdx.x;
  int d = idx % 64;
  int h = (idx / 64) % H_;
  int b = idx / (L_ * DM_);
  ctxb[idx] = f2b(vmean[(b * H_ + h) * 64 + d]);
}

__global__ __launch_bounds__(256) void scatter_ctx(const float* __restrict__ ctt,
                                                   const int* __restrict__ top,
                                                   u16* __restrict__ ctxb) {
  int idx = blockIdx.x * 256 + threadIdx.x;
  int d = idx % 64;
  int u = (idx / 64) % SK_;
  int bh = idx / (64 * SK_);
  int h = bh % H_, b = bh / H_;
  int l = top[bh * SK_ + u];
  ctxb[((size_t)b * L_ + l) * DM_ + h * 64 + d] = f2b(ctt[idx]);
}

// ---------------- host side --------------------------------------------------
extern "C" void kernel_launch(void* const* d_in, const int* in_sizes, int n_in,
                              void* d_out, int out_size, void* d_ws, size_t ws_size,
                              hipStream_t stream) {
  const float* inflow   = (const float*)d_in[4];
  const float* W_emb_e  = (const float*)d_in[5];
  const float* b_emb_e  = (const float*)d_in[6];
  const float* W_emb_d  = (const float*)d_in[7];
  const float* b_emb_d  = (const float*)d_in[8];
  const float* enc_Wqkv = (const float*)d_in[9];
  const float* enc_bqkv = (const float*)d_in[10];
  const float* enc_Wo   = (const float*)d_in[11];
  const float* enc_bo   = (const float*)d_in[12];
  const float* enc_ln1g = (const float*)d_in[13];
  const float* enc_ln1b = (const float*)d_in[14];
  const float* enc_Wf1  = (const float*)d_in[15];
  const float* enc_bf1  = (const float*)d_in[16];
  const float* enc_Wf2  = (const float*)d_in[17];
  const float* enc_bf2  = (const float*)d_in[18];
  const float* enc_ln2g = (const float*)d_in[19];
  const float* enc_ln2b = (const float*)d_in[20];
  const float* enc_ng   = (const float*)d_in[21];
  const float* enc_nb   = (const float*)d_in[22];
  const float* dec_Wqkv = (const float*)d_in[23];
  const float* dec_bqkv = (const float*)d_in[24];
  const float* dec_Wo_s = (const float*)d_in[25];
  const float* dec_bo_s = (const float*)d_in[26];
  const float* dec_ln1g = (const float*)d_in[27];
  const float* dec_ln1b = (const float*)d_in[28];
  const float* dec_Wq_c = (const float*)d_in[29];
  const float* dec_bq_c = (const float*)d_in[30];
  const float* dec_Wkv  = (const float*)d_in[31];
  const float* dec_bkv  = (const float*)d_in[32];
  const float* dec_Wo_c = (const float*)d_in[33];
  const float* dec_bo_c = (const float*)d_in[34];
  const float* dec_ln2g = (const float*)d_in[35];
  const float* dec_ln2b = (const float*)d_in[36];
  const float* dec_Wf1  = (const float*)d_in[37];
  const float* dec_bf1  = (const float*)d_in[38];
  const float* dec_Wf2  = (const float*)d_in[39];
  const float* dec_bf2  = (const float*)d_in[40];
  const float* dec_ln3g = (const float*)d_in[41];
  const float* dec_ln3b = (const float*)d_in[42];
  const float* W_proj   = (const float*)d_in[43];
  const float* b_proj   = (const float*)d_in[44];
  const float* W1       = (const float*)d_in[45];
  const float* b1       = (const float*)d_in[46];
  const float* W3       = (const float*)d_in[47];
  const float* b3       = (const float*)d_in[48];
  const int*   samp     = (const int*)d_in[49];
  float* out = (float*)d_out;

  float* ws  = (float*)d_ws;
  float* PE  = ws;                       // 778240 f (dead after embeds -> PM/PL)
  float* X   = PE + 778240;              // 72960 f
  float* ACT = X + 72960;                // 3112960 f
  float* REG = ACT + 3112960;            // 6291456 f shared region
  float* MME = REG + 6291456;            // 48640 f (VME8 overlay after topk)
  float* CTT = MME + 48640;              // 81920 f
  float* VME = CTT + 81920;              // 2048 f
  int*   TOP = (int*)(VME + 2048);       // 1280 i
  float* TAIL = VME + 2048 + 1280;
  u16* ENCb = (u16*)TAIL;                       // 6144*512 u16
  u16* DECb = (u16*)(TAIL + 1572864);
  u16* CTXb = (u16*)(TAIL + 2 * 1572864);
  u16* WBF  = (u16*)(TAIL + 3 * 1572864);       // 10485760 u16

  // region overlays (prob phase)
  u16* QKVb = (u16*)REG;                 // [6144][1536]
  u16* FFb  = (u16*)REG;                 // [6144][2048]
  u16* VT   = (u16*)REG + 9437184;       // [32][64][1536] u16
  // region overlays (cross phase)
  u16* QCb  = (u16*)REG;                 // [6144][512]
  u16* Kc   = (u16*)REG + 3145728;       // [6144][512]
  u16* Vc   = (u16*)REG + 6291456;       // [6144][512]; becomes PO0 after transpose
  float* O12 = REG;                      // head overlays
  float* H1  = REG + 72960;
  // prob split-K partials overlay CTXb (rebuilt by fill_ctx afterwards)
  float* POp = (float*)CTXb;             // 32*8*64*64 f
  float* PMp = POp + 1048576;
  float* PLp = PMp + 16384;
  // cross partial stats in dead PE region
  float* PMc = PE;                       // 1536*64 f
  float* PLc = PE + 98304;
  float* VME8 = MME;                     // 16384 f (after radix_topk)

  auto GB = [&](const u16* A, const u16* Bt, const float* bias, const float* res,
                float* Cf, u16* Cb, int N, int K, int act) {
    if (N <= 512) {
      dim3 g(N / 128, MP_ / 64);
      gemm_bf16<64><<<g, 256, 0, stream>>>(A, Bt, bias, res, Cf, Cb, N, K, act);
    } else {
      dim3 g(N / 128, MP_ / 128);
      gemm_bf16<128><<<g, 256, 0, stream>>>(A, Bt, bias, res, Cf, Cb, N, K, act);
    }
  };
  auto GF = [&](const float* A, const float* Bm, const float* bias, const float* res,
                float* C, int M, int N, int K, int res_mod, int act) {
    dim3 g((N + 63) / 64, (M + 63) / 64);
    gemm_f32<<<g, 256, 0, stream>>>(A, Bm, bias, res, C, M, N, K, res_mod, act);
  };
  auto PROB = [&](const int* sidx) {
    probM<<<B_ * H_ * L_ / 4, 256, 0, stream>>>(QKVb, sidx, MME);
    radix_topk<<<B_ * H_, 256, 0, stream>>>(MME, TOP);
    transpose_v<<<B_ * H_ * 24, 256, 0, stream>>>(QKVb, 1536, 1024, VT);
    flash_attn<1><<<B_ * H_ * 8, 256, 0, stream>>>(QKVb, QKVb, VT, TOP, POp, nullptr, nullptr, PMp, PLp);
    combine_prob<<<B_ * H_, 256, 0, stream>>>(POp, PMp, PLp, CTT);
    vmean_part<<<B_ * H_ * 8, 256, 0, stream>>>(QKVb, VME8);
    vmean_comb<<<8, 256, 0, stream>>>(VME8, VME);
    fill_ctx<<<ML_ * DM_ / 256, 256, 0, stream>>>(VME, CTXb);
    scatter_ctx<<<B_ * H_ * SK_ * 64 / 256, 256, 0, stream>>>(CTT, TOP, CTXb);
  };

  pe_kernel<<<(L_ * DM_ + 255) / 256, 256, 0, stream>>>(PE);
  extract_x<<<(ML_ * 12 + 255) / 256, 256, 0, stream>>>(inflow, X);

  // one fused weight-conversion dispatch (WBF slots are contiguous)
  {
    CvtArgs a;
    const float* s[15] = {
      enc_Wqkv, enc_Wqkv + 512 * 1536, enc_Wo, enc_Wo + 512 * 512,
      enc_Wf1, enc_Wf1 + 512 * 2048, enc_Wf2, enc_Wf2 + 2048 * 512,
      dec_Wqkv, dec_Wo_s, dec_Wq_c, dec_Wkv, dec_Wo_c, dec_Wf1, dec_Wf2 };
    unsigned cum[16] = { 0u, 786432u, 1572864u, 1835008u, 2097152u, 3145728u,
                         4194304u, 5242880u, 6291456u, 7077888u, 7340032u,
                         7602176u, 8126464u, 8388608u, 9437184u, 10485760u };
    unsigned lk[15] = { 9, 9, 9, 9, 9, 9, 11, 11, 9, 9, 9, 9, 9, 9, 11 };
    for (int i = 0; i < 15; ++i) { a.src[i] = s[i]; a.lk[i] = lk[i]; }
    for (int i = 0; i < 16; ++i) a.cum[i] = cum[i];
    cvt_all<<<10485760 / 256, 256, 0, stream>>>(a, WBF);
  }
  u16* Wt_qkv_e0 = WBF + 0;
  u16* Wt_qkv_e1 = WBF + 786432;
  u16* Wt_o_e0   = WBF + 1572864;
  u16* Wt_o_e1   = WBF + 1835008;
  u16* Wt_f1_e0  = WBF + 2097152;
  u16* Wt_f1_e1  = WBF + 3145728;
  u16* Wt_f2_e0  = WBF + 4194304;
  u16* Wt_f2_e1  = WBF + 5242880;
  u16* Wt_qkv_d  = WBF + 6291456;
  u16* Wt_o_s    = WBF + 7077888;
  u16* Wt_q_c    = WBF + 7340032;
  u16* Wt_kv_c   = WBF + 7602176;
  u16* Wt_o_c    = WBF + 8126464;
  u16* Wt_f1_d   = WBF + 8388608;
  u16* Wt_f2_d   = WBF + 9437184;

  // ---------------- encoder ----------------
  GF(X, W_emb_e, b_emb_e, PE, ACT, ML_, DM_, 12, L_, 0);
  cvt_act<<<MP_ * DM_ / 256, 256, 0, stream>>>(ACT, ENCb);

  const u16* Wqkv_e[2] = {Wt_qkv_e0, Wt_qkv_e1};
  const u16* Wo_e[2]   = {Wt_o_e0, Wt_o_e1};
  const u16* Wf1_e[2]  = {Wt_f1_e0, Wt_f1_e1};
  const u16* Wf2_e[2]  = {Wt_f2_e0, Wt_f2_e1};
  for (int i = 0; i < 2; ++i) {
    GB(ENCb, Wqkv_e[i], enc_bqkv + i * 1536, nullptr, nullptr, QKVb, 1536, 512, 0);
    PROB(samp + (size_t)i * L_ * SK_);
    GB(CTXb, Wo_e[i], enc_bo + i * 512, ACT, ACT, nullptr, 512, 512, 0);
    layernorm_ip<<<ML_ / 4, 256, 0, stream>>>(ACT, enc_ln1g + i * 512, enc_ln1b + i * 512, ENCb);
    GB(ENCb, Wf1_e[i], enc_bf1 + i * 2048, nullptr, nullptr, FFb, 2048, 512, 1);
    GB(FFb, Wf2_e[i], enc_bf2 + i * 512, ACT, ACT, nullptr, 512, 2048, 0);
    layernorm_ip<<<ML_ / 4, 256, 0, stream>>>(ACT, enc_ln2g + i * 512, enc_ln2b + i * 512, ENCb);
  }
  layernorm_ip<<<ML_ / 4, 256, 0, stream>>>(ACT, enc_ng, enc_nb, ENCb);

  // ---------------- decoder ----------------
  GF(X, W_emb_d, b_emb_d, PE, ACT, ML_, DM_, 12, L_, 0);
  cvt_act<<<MP_ * DM_ / 256, 256, 0, stream>>>(ACT, DECb);
  GB(DECb, Wt_qkv_d, dec_bqkv, nullptr, nullptr, QKVb, 1536, 512, 0);
  PROB(samp + (size_t)2 * L_ * SK_);
  GB(CTXb, Wt_o_s, dec_bo_s, ACT, ACT, nullptr, 512, 512, 0);
  layernorm_ip<<<ML_ / 4, 256, 0, stream>>>(ACT, dec_ln1g, dec_ln1b, DECb);

  // cross attention: Q, K, V as separate [*,512] GEMMs; V buffer becomes PO0
  GB(DECb, Wt_q_c, dec_bq_c, nullptr, nullptr, QCb, 512, 512, 0);
  GB(ENCb, Wt_kv_c, dec_bkv, nullptr, nullptr, Kc, 512, 512, 0);
  GB(ENCb, Wt_kv_c + 512 * 512, dec_bkv + 512, nullptr, nullptr, Vc, 512, 512, 0);
  transpose_v<<<B_ * H_ * 24, 256, 0, stream>>>(Vc, 512, 0, VT);
  flash_attn<0><<<B_ * H_ * 48, 256, 0, stream>>>(QCb, Kc, VT, nullptr, nullptr, Vc, CTXb, PMc, PLc);
  combine_cross<<<ML_ * DM_ / 256, 256, 0, stream>>>(Vc, PMc, PLc, CTXb);
  GB(CTXb, Wt_o_c, dec_bo_c, ACT, ACT, nullptr, 512, 512, 0);
  layernorm_ip<<<ML_ / 4, 256, 0, stream>>>(ACT, dec_ln2g, dec_ln2b, DECb);

  GB(DECb, Wt_f1_d, dec_bf1, nullptr, nullptr, FFb, 2048, 512, 1);
  GB(FFb, Wt_f2_d, dec_bf2, ACT, ACT, nullptr, 512, 2048, 0);
  layernorm_ip<<<ML_ / 4, 256, 0, stream>>>(ACT, dec_ln3g, dec_ln3b, DECb);

  GF(ACT, W_proj, b_proj, X, O12, ML_, 12, DM_, ML_, 0);
  GF(O12, W1, b1, nullptr, H1, ML_, 128, 12, ML_, 2);
  GF(H1, W3, b3, nullptr, out, ML_, 3, 128, ML_, 0);
}

// Round 7
// 1121.761 us; speedup vs baseline: 1.3425x; 1.0267x over previous
//
#include <hip/hip_runtime.h>
#include <math.h>

#define B_ 4
#define H_ 8
#define L_ 1520
#define DM_ 512
#define DFF_ 2048
#define SK_ 40
#define ML_ (B_*L_)   /* 6080 rows */
#define MP_ 6144      /* padded rows for MFMA GEMM */
#define LP_ 1536      /* padded key count for V^T */

typedef unsigned short u16;
typedef short s8v __attribute__((ext_vector_type(8)));
typedef float f4 __attribute__((ext_vector_type(4)));

__device__ __forceinline__ u16 f2b(float x) {
  union { float f; unsigned u; } c; c.f = x;
  unsigned r = c.u + 0x7FFFu + ((c.u >> 16) & 1u);
  return (u16)(r >> 16);
}
__device__ __forceinline__ float b2f(u16 h) {
  union { unsigned u; float f; } c; c.u = ((unsigned)h) << 16;
  return c.f;
}
__device__ __forceinline__ float gelu_tanh(float x) {
  float x3 = x * x * x;
  return 0.5f * x * (1.f + tanhf(0.79788456080286536f * (x + 0.044715f * x3)));
}
// XCD-chunked bijective swizzle; requires nwg % 8 == 0 (cpx = nwg/8).
__device__ __forceinline__ int xswz(int bid, int cpx) {
  return (bid & 7) * cpx + (bid >> 3);
}

// ---------------- positional encoding (double precision to match numpy) ----
__global__ __launch_bounds__(256) void pe_kernel(float* __restrict__ pe) {
  int idx = blockIdx.x * 256 + threadIdx.x;
  if (idx >= L_ * DM_) return;
  int pos = idx / DM_, i = idx % DM_;
  double expo = (double)(2 * (i / 2)) / (double)DM_;
  double ang = (double)pos / pow(10000.0, expo);
  pe[idx] = (i & 1) ? (float)cos(ang) : (float)sin(ang);
}

// ---------------- x = inflow[:,2:14].reshape (contiguous slice) -------------
__global__ __launch_bounds__(256) void extract_x(const float* __restrict__ inflow,
                                                 float* __restrict__ X) {
  int idx = blockIdx.x * 256 + threadIdx.x;
  if (idx >= ML_ * 12) return;
  int b = idx / (L_ * 12);
  int rem = idx - b * (L_ * 12);
  X[idx] = inflow[(size_t)b * 14 * L_ + 2 * L_ + rem];
}

// ---------------- fused weight convert+transpose into contiguous WBF --------
struct CvtArgs {
  const float* src[15];
  unsigned cum[16];
  unsigned lk[15];
};
__global__ __launch_bounds__(256) void cvt_all(CvtArgs a, u16* __restrict__ dst) {
  unsigned idx = blockIdx.x * 256 + threadIdx.x;   // grid exact: 10485760/256
  int s = 0;
#pragma unroll
  for (int i = 1; i < 15; ++i) s += (idx >= a.cum[i]);
  unsigned local = idx - a.cum[s];
  unsigned lk = a.lk[s];
  unsigned K = 1u << lk;
  unsigned N = (a.cum[s + 1] - a.cum[s]) >> lk;
  unsigned n = local >> lk, k = local & (K - 1);
  dst[idx] = f2b(a.src[s][(size_t)k * N + n]);
}

// ---------------- activation fp32[6080][512] -> bf16[6144][512], pad 0 ------
__global__ __launch_bounds__(256) void cvt_act(const float* __restrict__ Xf,
                                               u16* __restrict__ Xb) {
  int idx = blockIdx.x * 256 + threadIdx.x;
  int row = idx >> 9;
  Xb[idx] = (row < ML_) ? f2b(Xf[idx]) : 0;
}

// ---------------- generic fp32 GEMM (small shapes only) ---------------------
__global__ __launch_bounds__(256) void gemm_f32(
    const float* __restrict__ A, const float* __restrict__ Bm,
    const float* __restrict__ bias, const float* __restrict__ res,
    float* __restrict__ C, int M, int N, int K, int res_mod, int act) {
  __shared__ float As[16][65];
  __shared__ float Bs[16][64];
  int bm = blockIdx.y * 64, bn = blockIdx.x * 64;
  int tid = threadIdx.x;
  int tx = tid % 16, ty = tid / 16;
  float acc[4][4] = {};
  for (int k0 = 0; k0 < K; k0 += 16) {
#pragma unroll
    for (int i = 0; i < 4; ++i) {
      int idx = tid + i * 256;
      int r = idx / 16, c = idx % 16;
      int gm = bm + r, gk = k0 + c;
      As[c][r] = (gm < M && gk < K) ? A[(size_t)gm * K + gk] : 0.f;
    }
#pragma unroll
    for (int i = 0; i < 4; ++i) {
      int idx = tid + i * 256;
      int r = idx / 64, c = idx % 64;
      int gk = k0 + r, gn = bn + c;
      Bs[r][c] = (gk < K && gn < N) ? Bm[(size_t)gk * N + gn] : 0.f;
    }
    __syncthreads();
#pragma unroll
    for (int kk = 0; kk < 16; ++kk) {
      float a[4], b[4];
#pragma unroll
      for (int i = 0; i < 4; ++i) a[i] = As[kk][ty + 16 * i];
#pragma unroll
      for (int j = 0; j < 4; ++j) b[j] = Bs[kk][tx + 16 * j];
#pragma unroll
      for (int i = 0; i < 4; ++i)
#pragma unroll
        for (int j = 0; j < 4; ++j) acc[i][j] += a[i] * b[j];
    }
    __syncthreads();
  }
#pragma unroll
  for (int i = 0; i < 4; ++i) {
    int gm = bm + ty + 16 * i;
    if (gm >= M) continue;
#pragma unroll
    for (int j = 0; j < 4; ++j) {
      int gn = bn + tx + 16 * j;
      if (gn >= N) continue;
      float v = acc[i][j];
      if (bias) v += bias[gn];
      if (res) v += res[(size_t)(gm % res_mod) * N + gn];
      if (act == 1) v = gelu_tanh(v);
      else if (act == 2) v = fmaxf(v, 0.f);
      C[(size_t)gm * N + gn] = v;
    }
  }
}

// ---------------- bf16 MFMA GEMM, templated tile height, XCD-swizzled -------
// A [MP_][K] bf16, Bt [N][K] bf16, K%32==0, N%128==0. BM in {64,128}.
// Grid (x*y) must be divisible by 8.
template<int BM>
__global__ __launch_bounds__(256) void gemm_bf16(
    const u16* __restrict__ A, const u16* __restrict__ Bt,
    const float* __restrict__ bias, const float* __restrict__ res,
    float* __restrict__ Cf, u16* __restrict__ Cb,
    int N, int K, int act) {
  __shared__ __align__(16) u16 As[BM * 32];
  __shared__ __align__(16) u16 Bs[128 * 32];
  constexpr int MI = BM / 32;
  const int nwg = gridDim.x * gridDim.y;
  const int lin = blockIdx.y * gridDim.x + blockIdx.x;
  const int o = xswz(lin, nwg >> 3);
  const int bxi = o % gridDim.x, byi = o / gridDim.x;
  const int t = threadIdx.x, w = t >> 6, lane = t & 63;
  const int lg = lane >> 4, li = lane & 15;
  const int bm = byi * BM, bn = bxi * 128;
  const int wr = (w >> 1) * (BM / 2), wc = (w & 1) * 64;
  f4 acc[MI][4];
#pragma unroll
  for (int i = 0; i < MI; ++i)
#pragma unroll
    for (int j = 0; j < 4; ++j) acc[i][j] = f4{0.f, 0.f, 0.f, 0.f};
  const int rB = w * 32 + (lane >> 2);
  const int rA = (BM == 128) ? rB : (w * 16 + (lane >> 2));
  const int ps = lane & 3;
  for (int k0 = 0; k0 < K; k0 += 32) {
    if (BM == 128) {
#pragma unroll
      for (int j = 0; j < 2; ++j) {
        int r = rA + j * 16;
        int ls = ps ^ ((r >> 1) & 3);
        __builtin_amdgcn_global_load_lds(
            (const __attribute__((address_space(1))) void*)(A + (size_t)(bm + r) * K + k0 + ls * 8),
            (__attribute__((address_space(3))) void*)(As + (w * 32 + j * 16) * 32),
            16, 0, 0);
      }
    } else {
      int ls = ps ^ ((rA >> 1) & 3);
      __builtin_amdgcn_global_load_lds(
          (const __attribute__((address_space(1))) void*)(A + (size_t)(bm + rA) * K + k0 + ls * 8),
          (__attribute__((address_space(3))) void*)(As + (w * 16) * 32),
          16, 0, 0);
    }
#pragma unroll
    for (int j = 0; j < 2; ++j) {
      int r = rB + j * 16;
      int ls = ps ^ ((r >> 1) & 3);
      __builtin_amdgcn_global_load_lds(
          (const __attribute__((address_space(1))) void*)(Bt + (size_t)(bn + r) * K + k0 + ls * 8),
          (__attribute__((address_space(3))) void*)(Bs + (w * 32 + j * 16) * 32),
          16, 0, 0);
    }
    __syncthreads();
    s8v af[MI], bf[4];
#pragma unroll
    for (int f = 0; f < MI; ++f) {
      int ra = wr + f * 16 + li;
      af[f] = *(const s8v*)(As + ra * 32 + ((lg ^ ((ra >> 1) & 3)) * 8));
    }
#pragma unroll
    for (int f = 0; f < 4; ++f) {
      int rb = wc + f * 16 + li;
      bf[f] = *(const s8v*)(Bs + rb * 32 + ((lg ^ ((rb >> 1) & 3)) * 8));
    }
#pragma unroll
    for (int fi = 0; fi < MI; ++fi)
#pragma unroll
      for (int fj = 0; fj < 4; ++fj)
        acc[fi][fj] = __builtin_amdgcn_mfma_f32_16x16x32_bf16(af[fi], bf[fj], acc[fi][fj], 0, 0, 0);
    __syncthreads();
  }
#pragma unroll
  for (int fi = 0; fi < MI; ++fi)
#pragma unroll
    for (int fj = 0; fj < 4; ++fj)
#pragma unroll
      for (int r = 0; r < 4; ++r) {
        int row = bm + wr + fi * 16 + lg * 4 + r;
        int col = bn + wc + fj * 16 + li;
        float v = acc[fi][fj][r] + bias[col];
        if (res && row < ML_) v += res[(size_t)row * N + col];
        if (act == 1) v = gelu_tanh(v);
        if (Cf && row < ML_) Cf[(size_t)row * N + col] = v;
        if (Cb) Cb[(size_t)row * N + col] = f2b(v);
      }
}

// ---------------- layernorm: wave per row, vectorized -----------------------
__global__ __launch_bounds__(256) void layernorm_ip(float* __restrict__ Xb,
                                                    const float* __restrict__ g,
                                                    const float* __restrict__ bta,
                                                    u16* __restrict__ outb) {
  int row = blockIdx.x * 4 + (threadIdx.x >> 6);
  int lane = threadIdx.x & 63;
  float* x = Xb + (size_t)row * DM_;
  f4 a = *(f4*)(x + lane * 8);
  f4 b = *(f4*)(x + lane * 8 + 4);
  float s = a[0] + a[1] + a[2] + a[3] + b[0] + b[1] + b[2] + b[3];
  for (int off = 32; off; off >>= 1) s += __shfl_xor(s, off);
  float mu = s * (1.f / 512.f);
  float vs = 0.f;
#pragma unroll
  for (int i = 0; i < 4; ++i) { a[i] -= mu; b[i] -= mu; vs += a[i] * a[i] + b[i] * b[i]; }
  for (int off = 32; off; off >>= 1) vs += __shfl_xor(vs, off);
  float rs = rsqrtf(vs * (1.f / 512.f) + 1e-5f);
  f4 g0 = *(const f4*)(g + lane * 8), g1 = *(const f4*)(g + lane * 8 + 4);
  f4 c0 = *(const f4*)(bta + lane * 8), c1 = *(const f4*)(bta + lane * 8 + 4);
  u16 ob[8];
#pragma unroll
  for (int i = 0; i < 4; ++i) {
    float r1 = a[i] * rs * g0[i] + c0[i]; x[lane * 8 + i] = r1;     ob[i] = f2b(r1);
    float r2 = b[i] * rs * g1[i] + c1[i]; x[lane * 8 + 4 + i] = r2; ob[4 + i] = f2b(r2);
  }
  *(s8v*)(outb + (size_t)row * DM_ + lane * 8) = *(s8v*)ob;
}

// ---------------- ProbSparse sparsity measure M (bf16 qkv), swizzled --------
__global__ __launch_bounds__(256) void probM(const u16* __restrict__ qkv,
                                             const int* __restrict__ sidx,
                                             float* __restrict__ Mout) {
  int wid = threadIdx.x / 64, lane = threadIdx.x % 64;
  int o = xswz(blockIdx.x, (B_ * H_ * L_ / 4) >> 3);
  int g = o * 4 + wid;
  int l = g % L_;
  int bh = g / L_;
  int h = bh % H_, b = bh / H_;
  __shared__ float qs[4][64];
  qs[wid][lane] = b2f(qkv[((size_t)b * L_ + l) * 1536 + h * 64 + lane]);
  __syncthreads();
  float dot = 0.f;
  if (lane < SK_) {
    int ks = sidx[l * SK_ + lane];
    const u16* kr = qkv + ((size_t)b * L_ + ks) * 1536 + 512 + h * 64;
#pragma unroll
    for (int j = 0; j < 8; ++j) {
      s8v v = *(const s8v*)(kr + j * 8);
#pragma unroll
      for (int i = 0; i < 8; ++i) dot += qs[wid][j * 8 + i] * b2f((u16)v[i]);
    }
  }
  float vmax = (lane < SK_) ? dot : -INFINITY;
  float vsum = (lane < SK_) ? dot : 0.f;
  for (int off = 32; off; off >>= 1) {
    vmax = fmaxf(vmax, __shfl_xor(vmax, off));
    vsum += __shfl_xor(vsum, off);
  }
  if (lane == 0) Mout[g] = vmax - vsum / (float)L_;
}

// ---------------- radix-select top-40 (matches lax.top_k selection set) -----
__global__ __launch_bounds__(256) void radix_topk(const float* __restrict__ Mv,
                                                  int* __restrict__ top) {
  const int bh = blockIdx.x;
  const int t = threadIdx.x;
  const int base = t * 6;
  unsigned key[6];
#pragma unroll
  for (int i = 0; i < 6; ++i) {
    int ix = base + i;
    unsigned k = 0u;
    if (ix < L_) {
      union { float f; unsigned u; } c; c.f = Mv[(size_t)bh * L_ + ix];
      k = c.u ^ ((c.u & 0x80000000u) ? 0xFFFFFFFFu : 0x80000000u);
    }
    key[i] = k;
  }
  __shared__ int wred[4];
  __shared__ int s_a[256], s_b[256];
  unsigned prefix = 0u;
  for (int b = 31; b >= 0; --b) {
    unsigned cand = prefix | (1u << b);
    int c = 0;
#pragma unroll
    for (int i = 0; i < 6; ++i) c += (key[i] >= cand);
    for (int off = 32; off; off >>= 1) c += __shfl_xor(c, off);
    if ((t & 63) == 0) wred[t >> 6] = c;
    __syncthreads();
    int tot = wred[0] + wred[1] + wred[2] + wred[3];
    if (tot >= SK_) prefix = cand;
    __syncthreads();
  }
  const unsigned T = prefix;
  int gt = 0, tie = 0;
#pragma unroll
  for (int i = 0; i < 6; ++i) { gt += (key[i] > T); tie += (key[i] == T); }
  s_a[t] = gt; s_b[t] = tie;
  __syncthreads();
  for (int off = 1; off < 256; off <<= 1) {
    int va = (t >= off) ? s_a[t - off] : 0;
    int vb = (t >= off) ? s_b[t - off] : 0;
    __syncthreads();
    s_a[t] += va; s_b[t] += vb;
    __syncthreads();
  }
  const int n_strict = s_a[255];
  const int gt_base = s_a[t] - gt;
  const int tie_base = s_b[t] - tie;
  const int need = SK_ - n_strict;
  int lgt = 0, ltie = 0;
#pragma unroll
  for (int i = 0; i < 6; ++i) {
    int ix = base + i;
    if (key[i] > T) {
      top[bh * SK_ + gt_base + lgt] = ix; ++lgt;
    } else if (key[i] == T) {
      int r = tie_base + ltie; ++ltie;
      if (r < need) top[bh * SK_ + n_strict + r] = ix;
    }
  }
}

// ---------------- V^T build: VT[bh][64][LP_] from V columns, swizzled -------
__global__ __launch_bounds__(256) void transpose_v(const u16* __restrict__ src,
                                                   int stride, int voff0,
                                                   u16* __restrict__ VT) {
  int o = xswz(blockIdx.x, (B_ * H_ * 24) >> 3);
  int kt = o % 24, bh = o / 24;
  int h = bh & 7, b = bh >> 3;
  int kb = kt * 64;
  __shared__ u16 tile[64][72];
  int t = threadIdx.x;
#pragma unroll
  for (int rr = 0; rr < 2; ++rr) {
    int slot = rr * 256 + t;
    int key = slot >> 3, d = (slot & 7) * 8;
    int gk = kb + key; if (gk >= L_) gk = L_ - 1;
    s8v v = *(const s8v*)(src + (size_t)(b * L_ + gk) * stride + voff0 + h * 64 + d);
    *(s8v*)(&tile[key][d]) = v;
  }
  __syncthreads();
  int dim = t >> 2, k0 = (t & 3) * 16;
  u16 buf[16];
#pragma unroll
  for (int i = 0; i < 16; ++i) {
    int key = k0 + i;
    buf[i] = (kb + key < L_) ? tile[key][dim] : (u16)0;
  }
  *(s8v*)(VT + ((size_t)bh * 64 + dim) * LP_ + kb + k0) = *(s8v*)buf;
  *(s8v*)(VT + ((size_t)bh * 64 + dim) * LP_ + kb + k0 + 8) = *(s8v*)(buf + 8);
}

// ---------------- swapped-operand MFMA flash attention, XCD-swizzled ---------
// MODE 0: cross attn, 4-way K-split. orig = bh*96 + qb*4 + sp (6 tiles each).
//         Writes UNNORMALIZED bf16 partials ctx-shaped into POs[sp],
//         stats PM/PL[pid*64+qloc], pid=(bh*24+qb)*4+sp.
// MODE 1: prob attn (top-40 rows), 8 splits x 3 tiles; f32 partials POf.
template<int MODE>
__global__ __launch_bounds__(256) void flash_attn(
    const u16* __restrict__ Qm, const u16* __restrict__ Kg,
    const u16* __restrict__ VT, const int* __restrict__ top,
    float* __restrict__ POf, u16* POa, u16* POb, u16* POc, u16* POd,
    float* __restrict__ PM, float* __restrict__ PL) {
  constexpr int QSTR = (MODE == 0) ? 512 : 1536;
  constexpr int KSTR = (MODE == 0) ? 512 : 1536;
  constexpr int TILES = (MODE == 0) ? 6 : 3;
  constexpr int NB = (MODE == 0) ? 96 : 8;
  __shared__ __align__(16) unsigned Xch[4][576];   // per-wave exchange region
  const int o = xswz(blockIdx.x, (B_ * H_ * NB) >> 3);
  int bh, sp, qb;
  if (MODE == 0) {
    bh = o / 96; int rem = o % 96; qb = rem >> 2; sp = rem & 3;
  } else {
    bh = o / 8; sp = o % 8; qb = 0;
  }
  const int h = bh & 7, b = bh >> 3;
  const int qoff = h * 64;
  const int koff = ((MODE == 0) ? 0 : 512) + h * 64;
  const int t = threadIdx.x, w = t >> 6, lane = t & 63;
  const int lg = lane >> 4, li = lane & 15;
  const u16* vt = VT + (size_t)bh * 64 * LP_;
  unsigned* xw = Xch[w];
  u16* xw16 = (u16*)xw;

  // Q as B-operand fragment: lane li = q column
  int qrow;
  if (MODE == 0) {
    int q = qb * 64 + w * 16 + li;
    qrow = b * L_ + ((q < L_) ? q : (L_ - 1));
  } else {
    int u = w * 16 + li; if (u >= SK_) u = SK_ - 1;
    qrow = b * L_ + top[bh * SK_ + u];
  }
  s8v qf0 = *(const s8v*)(Qm + (size_t)qrow * QSTR + qoff + lg * 8);
  s8v qf1 = *(const s8v*)(Qm + (size_t)qrow * QSTR + qoff + 32 + lg * 8);

  f4 o4[4];                          // o4[n][r] = O^T[d=n*16+lg*4+r][q=li]
#pragma unroll
  for (int n = 0; n < 4; ++n) o4[n] = f4{0.f, 0.f, 0.f, 0.f};
  float m_run = -INFINITY, l_run = 0.f;   // per-lane (q=li)
  const int kt0 = sp * TILES;

#pragma unroll 1
  for (int ki = 0; ki < TILES; ++ki) {
    const int kb = (kt0 + ki) * 64;
    s8v kf[4], kg[4];
#pragma unroll
    for (int c = 0; c < 4; ++c) {
      const u16* kr = Kg + (size_t)(b * L_ + kb + c * 16 + li) * KSTR + koff;
      kf[c] = *(const s8v*)(kr + lg * 8);
      kg[c] = *(const s8v*)(kr + 32 + lg * 8);
    }
    // S^T = K @ Q^T / 8 : s[c][r] = S[key=kb+c*16+lg*4+r][q=li]
    f4 s[4];
#pragma unroll
    for (int c = 0; c < 4; ++c) {
      f4 z = f4{0.f, 0.f, 0.f, 0.f};
      z = __builtin_amdgcn_mfma_f32_16x16x32_bf16(kf[c], qf0, z, 0, 0, 0);
      z = __builtin_amdgcn_mfma_f32_16x16x32_bf16(kg[c], qf1, z, 0, 0, 0);
      s[c] = z * 0.125f;
    }
    if (kb + 64 > L_) {
#pragma unroll
      for (int c = 0; c < 4; ++c)
#pragma unroll
        for (int r = 0; r < 4; ++r)
          if (kb + c * 16 + lg * 4 + r >= L_) s[c][r] = -INFINITY;
    }
    float tm = -INFINITY;
#pragma unroll
    for (int c = 0; c < 4; ++c)
      tm = fmaxf(tm, fmaxf(fmaxf(s[c][0], s[c][1]), fmaxf(s[c][2], s[c][3])));
    tm = fmaxf(tm, __shfl_xor(tm, 16));
    tm = fmaxf(tm, __shfl_xor(tm, 32));
    float mn = fmaxf(m_run, tm);
    float sc = __expf(m_run - mn);
    float p[4][4];
    float rs = 0.f;
#pragma unroll
    for (int c = 0; c < 4; ++c)
#pragma unroll
      for (int r = 0; r < 4; ++r) { p[c][r] = __expf(s[c][r] - mn); rs += p[c][r]; }
    rs += __shfl_xor(rs, 16);
    rs += __shfl_xor(rs, 32);
    l_run = l_run * sc + rs;
    m_run = mn;
#pragma unroll
    for (int n = 0; n < 4; ++n) o4[n] *= sc;
    // pack P by key order into per-wave LDS: u32 idx = key>>1 = c*8+lg*2+rp
#pragma unroll
    for (int c = 0; c < 4; ++c)
#pragma unroll
      for (int rp = 0; rp < 2; ++rp) {
        unsigned v = (unsigned)f2b(p[c][2 * rp]) | ((unsigned)f2b(p[c][2 * rp + 1]) << 16);
        xw[li * 36 + c * 8 + lg * 2 + rp] = v;
      }
    s8v pb0 = *(const s8v*)(xw + li * 36 + lg * 4);
    s8v pb1 = *(const s8v*)(xw + li * 36 + 16 + lg * 4);
    // O^T += V^T @ P^T
#pragma unroll
    for (int n = 0; n < 4; ++n) {
      s8v vb0 = *(const s8v*)(vt + (size_t)(n * 16 + li) * LP_ + kb + lg * 8);
      o4[n] = __builtin_amdgcn_mfma_f32_16x16x32_bf16(vb0, pb0, o4[n], 0, 0, 0);
    }
#pragma unroll
    for (int n = 0; n < 4; ++n) {
      s8v vb1 = *(const s8v*)(vt + (size_t)(n * 16 + li) * LP_ + kb + 32 + lg * 8);
      o4[n] = __builtin_amdgcn_mfma_f32_16x16x32_bf16(vb1, pb1, o4[n], 0, 0, 0);
    }
  }

  if (MODE == 0) {
    // per-wave LDS transpose [q][d], then coalesced unnormalized bf16 store
#pragma unroll
    for (int n = 0; n < 4; ++n)
#pragma unroll
      for (int r = 0; r < 4; ++r)
        xw16[li * 72 + n * 16 + lg * 4 + r] = f2b(o4[n][r]);
    u16* POs[4] = {POa, POb, POc, POd};
    u16* PO = POs[sp];
    const int pid = (bh * 24 + qb) * 4 + sp;
    int q_local = lane >> 2, d0 = (lane & 3) * 16;
    int q = qb * 64 + w * 16 + q_local;
    s8v v0 = *(const s8v*)(xw16 + q_local * 72 + d0);
    s8v v1 = *(const s8v*)(xw16 + q_local * 72 + d0 + 8);
    if (q < L_) {
      u16* dst = PO + ((size_t)(b * L_ + q)) * DM_ + qoff + d0;
      *(s8v*)dst = v0;
      *(s8v*)(dst + 8) = v1;
    }
    if (lg == 0) {
      PM[pid * 64 + w * 16 + li] = m_run;
      PL[pid * 64 + w * 16 + li] = l_run;
    }
  } else {
    int base = (bh * 8 + sp) * 64 + w * 16 + li;
#pragma unroll
    for (int n = 0; n < 4; ++n)
#pragma unroll
      for (int r = 0; r < 4; ++r)
        POf[(size_t)base * 64 + n * 16 + lg * 4 + r] = o4[n][r];
    if (lg == 0) {
      PM[base] = m_run;
      PL[base] = l_run;
    }
  }
}

// ---------------- combine 4-way cross partials (POd == ctxb, in place) ------
__global__ __launch_bounds__(256) void combine_cross(const u16* __restrict__ POa,
                                                     const u16* __restrict__ POb,
                                                     const u16* __restrict__ POc,
                                                     const float* __restrict__ PM,
                                                     const float* __restrict__ PL,
                                                     u16* ctxb) {
  int idx = blockIdx.x * 256 + threadIdx.x;   // grid exact: ML_*DM_/256
  int row = idx >> 9, col = idx & 511;
  int b = row / L_, q = row - b * L_;
  int h = col >> 6;
  int bh = b * 8 + h, qbk = q >> 6, qi = q & 63;
  int p0 = ((bh * 24 + qbk) * 4) * 64 + qi;
  float m0 = PM[p0], m1 = PM[p0 + 64], m2 = PM[p0 + 128], m3 = PM[p0 + 192];
  float M = fmaxf(fmaxf(m0, m1), fmaxf(m2, m3));
  float w0 = __expf(m0 - M), w1 = __expf(m1 - M);
  float w2 = __expf(m2 - M), w3 = __expf(m3 - M);
  float den = w0 * PL[p0] + w1 * PL[p0 + 64] + w2 * PL[p0 + 128] + w3 * PL[p0 + 192];
  float acc = w0 * b2f(POa[idx]) + w1 * b2f(POb[idx]) +
              w2 * b2f(POc[idx]) + w3 * b2f(ctxb[idx]);
  ctxb[idx] = f2b(acc / den);
}

// ---------------- combine split-K partials -> ctt ----------------------------
__global__ __launch_bounds__(256) void combine_prob(const float* __restrict__ PO,
                                                    const float* __restrict__ PM,
                                                    const float* __restrict__ PL,
                                                    float* __restrict__ ctt) {
  int bh = blockIdx.x;
  int t = threadIdx.x;
  int u = t >> 2, dg = (t & 3) * 16;
  if (u >= SK_) return;
  float M = -INFINITY;
  for (int s = 0; s < 8; ++s) M = fmaxf(M, PM[(bh * 8 + s) * 64 + u]);
  float wgt[8];
  float den = 0.f;
  for (int s = 0; s < 8; ++s) {
    wgt[s] = __expf(PM[(bh * 8 + s) * 64 + u] - M);
    den += wgt[s] * PL[(bh * 8 + s) * 64 + u];
  }
  float inv = 1.f / den;
  for (int d = dg; d < dg + 16; ++d) {
    float acc = 0.f;
    for (int s = 0; s < 8; ++s) acc += wgt[s] * PO[(((size_t)bh * 8 + s) * 64 + u) * 64 + d];
    ctt[((size_t)bh * SK_ + u) * 64 + d] = acc * inv;
  }
}

// ---------------- V mean: 8-way partial + combine, swizzled -----------------
__global__ __launch_bounds__(256) void vmean_part(const u16* __restrict__ qkv,
                                                  float* __restrict__ part) {
  int g = xswz(blockIdx.x, (B_ * H_ * 8) >> 3);
  int bh = g >> 3, seg = g & 7;
  int h = bh & 7, b = bh >> 3;
  int lane = threadIdx.x & 63, grp = threadIdx.x >> 6;
  int k0 = seg * 190, k1 = k0 + 190;
  float acc = 0.f;
  for (int k = k0 + grp; k < k1; k += 4)
    acc += b2f(qkv[((size_t)b * L_ + k) * 1536 + 1024 + h * 64 + lane]);
  __shared__ float pv[4][64];
  pv[grp][lane] = acc;
  __syncthreads();
  if (threadIdx.x < 64)
    part[g * 64 + threadIdx.x] =
        pv[0][threadIdx.x] + pv[1][threadIdx.x] + pv[2][threadIdx.x] + pv[3][threadIdx.x];
}

__global__ __launch_bounds__(256) void vmean_comb(const float* __restrict__ part,
                                                  float* __restrict__ vmean) {
  int idx = blockIdx.x * 256 + threadIdx.x;   // 2048
  int bh = idx >> 6, d = idx & 63;
  float s = 0.f;
#pragma unroll
  for (int seg = 0; seg < 8; ++seg) s += part[(bh * 8 + seg) * 64 + d];
  vmean[idx] = s / (float)L_;
}

// ---------------- ctx = broadcast vmean (bf16), then scatter top ------------
__global__ __launch_bounds__(256) void fill_ctx(const float* __restrict__ vmean,
                                                u16* __restrict__ ctxb) {
  int idx = blockIdx.x * 256 + threadIdx.x;
  int d = idx % 64;
  int h = (idx / 64) % H_;
  int b = idx / (L_ * DM_);
  ctxb[idx] = f2b(vmean[(b * H_ + h) * 64 + d]);
}

__global__ __launch_bounds__(256) void scatter_ctx(const float* __restrict__ ctt,
                                                   const int* __restrict__ top,
                                                   u16* __restrict__ ctxb) {
  int idx = blockIdx.x * 256 + threadIdx.x;
  int d = idx % 64;
  int u = (idx / 64) % SK_;
  int bh = idx / (64 * SK_);
  int h = bh % H_, b = bh / H_;
  int l = top[bh * SK_ + u];
  ctxb[((size_t)b * L_ + l) * DM_ + h * 64 + d] = f2b(ctt[idx]);
}

// ---------------- host side --------------------------------------------------
extern "C" void kernel_launch(void* const* d_in, const int* in_sizes, int n_in,
                              void* d_out, int out_size, void* d_ws, size_t ws_size,
                              hipStream_t stream) {
  const float* inflow   = (const float*)d_in[4];
  const float* W_emb_e  = (const float*)d_in[5];
  const float* b_emb_e  = (const float*)d_in[6];
  const float* W_emb_d  = (const float*)d_in[7];
  const float* b_emb_d  = (const float*)d_in[8];
  const float* enc_Wqkv = (const float*)d_in[9];
  const float* enc_bqkv = (const float*)d_in[10];
  const float* enc_Wo   = (const float*)d_in[11];
  const float* enc_bo   = (const float*)d_in[12];
  const float* enc_ln1g = (const float*)d_in[13];
  const float* enc_ln1b = (const float*)d_in[14];
  const float* enc_Wf1  = (const float*)d_in[15];
  const float* enc_bf1  = (const float*)d_in[16];
  const float* enc_Wf2  = (const float*)d_in[17];
  const float* enc_bf2  = (const float*)d_in[18];
  const float* enc_ln2g = (const float*)d_in[19];
  const float* enc_ln2b = (const float*)d_in[20];
  const float* enc_ng   = (const float*)d_in[21];
  const float* enc_nb   = (const float*)d_in[22];
  const float* dec_Wqkv = (const float*)d_in[23];
  const float* dec_bqkv = (const float*)d_in[24];
  const float* dec_Wo_s = (const float*)d_in[25];
  const float* dec_bo_s = (const float*)d_in[26];
  const float* dec_ln1g = (const float*)d_in[27];
  const float* dec_ln1b = (const float*)d_in[28];
  const float* dec_Wq_c = (const float*)d_in[29];
  const float* dec_bq_c = (const float*)d_in[30];
  const float* dec_Wkv  = (const float*)d_in[31];
  const float* dec_bkv  = (const float*)d_in[32];
  const float* dec_Wo_c = (const float*)d_in[33];
  const float* dec_bo_c = (const float*)d_in[34];
  const float* dec_ln2g = (const float*)d_in[35];
  const float* dec_ln2b = (const float*)d_in[36];
  const float* dec_Wf1  = (const float*)d_in[37];
  const float* dec_bf1  = (const float*)d_in[38];
  const float* dec_Wf2  = (const float*)d_in[39];
  const float* dec_bf2  = (const float*)d_in[40];
  const float* dec_ln3g = (const float*)d_in[41];
  const float* dec_ln3b = (const float*)d_in[42];
  const float* W_proj   = (const float*)d_in[43];
  const float* b_proj   = (const float*)d_in[44];
  const float* W1       = (const float*)d_in[45];
  const float* b1       = (const float*)d_in[46];
  const float* W3       = (const float*)d_in[47];
  const float* b3       = (const float*)d_in[48];
  const int*   samp     = (const int*)d_in[49];
  float* out = (float*)d_out;

  float* ws  = (float*)d_ws;
  float* PE  = ws;                       // 778240 f (dead after embeds -> PM/PL)
  float* X   = PE + 778240;              // 72960 f
  float* ACT = X + 72960;                // 3112960 f
  float* REG = ACT + 3112960;            // 6291456 f shared region
  float* MME = REG + 6291456;            // 48640 f (VME8 overlay after topk)
  float* CTT = MME + 48640;              // 81920 f
  float* VME = CTT + 81920;              // 2048 f
  int*   TOP = (int*)(VME + 2048);       // 1280 i
  float* TAIL = VME + 2048 + 1280;
  u16* ENCb = (u16*)TAIL;                       // 6144*512 u16
  u16* DECb = (u16*)(TAIL + 1572864);
  u16* CTXb = (u16*)(TAIL + 2 * 1572864);
  u16* WBF  = (u16*)(TAIL + 3 * 1572864);       // 10485760 u16
  u16* EXT0 = WBF + 10485760;                   // 3145728 u16 (cross partial)
  u16* EXT1 = EXT0 + 3145728;                   // 3145728 u16 (cross partial)

  // region overlays (prob phase)
  u16* QKVb = (u16*)REG;                 // [6144][1536]
  u16* FFb  = (u16*)REG;                 // [6144][2048]
  u16* VT   = (u16*)REG + 9437184;       // [32][64][1536] u16
  // region overlays (cross phase)
  u16* QCb  = (u16*)REG;                 // [6144][512]
  u16* Kc   = (u16*)REG + 3145728;       // [6144][512]
  u16* Vc   = (u16*)REG + 6291456;       // [6144][512]; becomes PO-split0 after transpose
  float* O12 = REG;                      // head overlays
  float* H1  = REG + 72960;
  // prob split-K partials overlay CTXb (rebuilt by fill_ctx afterwards)
  float* POp = (float*)CTXb;             // 32*8*64*64 f
  float* PMp = POp + 1048576;
  float* PLp = PMp + 16384;
  // cross partial stats in dead PE region (32*24*4*64 = 196608 each)
  float* PMc = PE;
  float* PLc = PE + 196608;
  float* VME8 = MME;                     // 16384 f (after radix_topk)

  auto GB = [&](const u16* A, const u16* Bt, const float* bias, const float* res,
                float* Cf, u16* Cb, int N, int K, int act) {
    if (N <= 512) {
      dim3 g(N / 128, MP_ / 64);
      gemm_bf16<64><<<g, 256, 0, stream>>>(A, Bt, bias, res, Cf, Cb, N, K, act);
    } else {
      dim3 g(N / 128, MP_ / 128);
      gemm_bf16<128><<<g, 256, 0, stream>>>(A, Bt, bias, res, Cf, Cb, N, K, act);
    }
  };
  auto GF = [&](const float* A, const float* Bm, const float* bias, const float* res,
                float* C, int M, int N, int K, int res_mod, int act) {
    dim3 g((N + 63) / 64, (M + 63) / 64);
    gemm_f32<<<g, 256, 0, stream>>>(A, Bm, bias, res, C, M, N, K, res_mod, act);
  };
  auto PROB = [&](const int* sidx) {
    probM<<<B_ * H_ * L_ / 4, 256, 0, stream>>>(QKVb, sidx, MME);
    radix_topk<<<B_ * H_, 256, 0, stream>>>(MME, TOP);
    transpose_v<<<B_ * H_ * 24, 256, 0, stream>>>(QKVb, 1536, 1024, VT);
    flash_attn<1><<<B_ * H_ * 8, 256, 0, stream>>>(QKVb, QKVb, VT, TOP, POp,
                                                   nullptr, nullptr, nullptr, nullptr, PMp, PLp);
    combine_prob<<<B_ * H_, 256, 0, stream>>>(POp, PMp, PLp, CTT);
    vmean_part<<<B_ * H_ * 8, 256, 0, stream>>>(QKVb, VME8);
    vmean_comb<<<8, 256, 0, stream>>>(VME8, VME);
    fill_ctx<<<ML_ * DM_ / 256, 256, 0, stream>>>(VME, CTXb);
    scatter_ctx<<<B_ * H_ * SK_ * 64 / 256, 256, 0, stream>>>(CTT, TOP, CTXb);
  };

  pe_kernel<<<(L_ * DM_ + 255) / 256, 256, 0, stream>>>(PE);
  extract_x<<<(ML_ * 12 + 255) / 256, 256, 0, stream>>>(inflow, X);

  // one fused weight-conversion dispatch (WBF slots are contiguous)
  {
    CvtArgs a;
    const float* s[15] = {
      enc_Wqkv, enc_Wqkv + 512 * 1536, enc_Wo, enc_Wo + 512 * 512,
      enc_Wf1, enc_Wf1 + 512 * 2048, enc_Wf2, enc_Wf2 + 2048 * 512,
      dec_Wqkv, dec_Wo_s, dec_Wq_c, dec_Wkv, dec_Wo_c, dec_Wf1, dec_Wf2 };
    unsigned cum[16] = { 0u, 786432u, 1572864u, 1835008u, 2097152u, 3145728u,
                         4194304u, 5242880u, 6291456u, 7077888u, 7340032u,
                         7602176u, 8126464u, 8388608u, 9437184u, 10485760u };
    unsigned lk[15] = { 9, 9, 9, 9, 9, 9, 11, 11, 9, 9, 9, 9, 9, 9, 11 };
    for (int i = 0; i < 15; ++i) { a.src[i] = s[i]; a.lk[i] = lk[i]; }
    for (int i = 0; i < 16; ++i) a.cum[i] = cum[i];
    cvt_all<<<10485760 / 256, 256, 0, stream>>>(a, WBF);
  }
  u16* Wt_qkv_e0 = WBF + 0;
  u16* Wt_qkv_e1 = WBF + 786432;
  u16* Wt_o_e0   = WBF + 1572864;
  u16* Wt_o_e1   = WBF + 1835008;
  u16* Wt_f1_e0  = WBF + 2097152;
  u16* Wt_f1_e1  = WBF + 3145728;
  u16* Wt_f2_e0  = WBF + 4194304;
  u16* Wt_f2_e1  = WBF + 5242880;
  u16* Wt_qkv_d  = WBF + 6291456;
  u16* Wt_o_s    = WBF + 7077888;
  u16* Wt_q_c    = WBF + 7340032;
  u16* Wt_kv_c   = WBF + 7602176;
  u16* Wt_o_c    = WBF + 8126464;
  u16* Wt_f1_d   = WBF + 8388608;
  u16* Wt_f2_d   = WBF + 9437184;

  // ---------------- encoder ----------------
  GF(X, W_emb_e, b_emb_e, PE, ACT, ML_, DM_, 12, L_, 0);
  cvt_act<<<MP_ * DM_ / 256, 256, 0, stream>>>(ACT, ENCb);

  const u16* Wqkv_e[2] = {Wt_qkv_e0, Wt_qkv_e1};
  const u16* Wo_e[2]   = {Wt_o_e0, Wt_o_e1};
  const u16* Wf1_e[2]  = {Wt_f1_e0, Wt_f1_e1};
  const u16* Wf2_e[2]  = {Wt_f2_e0, Wt_f2_e1};
  for (int i = 0; i < 2; ++i) {
    GB(ENCb, Wqkv_e[i], enc_bqkv + i * 1536, nullptr, nullptr, QKVb, 1536, 512, 0);
    PROB(samp + (size_t)i * L_ * SK_);
    GB(CTXb, Wo_e[i], enc_bo + i * 512, ACT, ACT, nullptr, 512, 512, 0);
    layernorm_ip<<<ML_ / 4, 256, 0, stream>>>(ACT, enc_ln1g + i * 512, enc_ln1b + i * 512, ENCb);
    GB(ENCb, Wf1_e[i], enc_bf1 + i * 2048, nullptr, nullptr, FFb, 2048, 512, 1);
    GB(FFb, Wf2_e[i], enc_bf2 + i * 512, ACT, ACT, nullptr, 512, 2048, 0);
    layernorm_ip<<<ML_ / 4, 256, 0, stream>>>(ACT, enc_ln2g + i * 512, enc_ln2b + i * 512, ENCb);
  }
  layernorm_ip<<<ML_ / 4, 256, 0, stream>>>(ACT, enc_ng, enc_nb, ENCb);

  // ---------------- decoder ----------------
  GF(X, W_emb_d, b_emb_d, PE, ACT, ML_, DM_, 12, L_, 0);
  cvt_act<<<MP_ * DM_ / 256, 256, 0, stream>>>(ACT, DECb);
  GB(DECb, Wt_qkv_d, dec_bqkv, nullptr, nullptr, QKVb, 1536, 512, 0);
  PROB(samp + (size_t)2 * L_ * SK_);
  GB(CTXb, Wt_o_s, dec_bo_s, ACT, ACT, nullptr, 512, 512, 0);
  layernorm_ip<<<ML_ / 4, 256, 0, stream>>>(ACT, dec_ln1g, dec_ln1b, DECb);

  // cross attention: Q, K, V as separate [*,512] GEMMs; V buffer becomes split-0
  GB(DECb, Wt_q_c, dec_bq_c, nullptr, nullptr, QCb, 512, 512, 0);
  GB(ENCb, Wt_kv_c, dec_bkv, nullptr, nullptr, Kc, 512, 512, 0);
  GB(ENCb, Wt_kv_c + 512 * 512, dec_bkv + 512, nullptr, nullptr, Vc, 512, 512, 0);
  transpose_v<<<B_ * H_ * 24, 256, 0, stream>>>(Vc, 512, 0, VT);
  flash_attn<0><<<B_ * H_ * 96, 256, 0, stream>>>(QCb, Kc, VT, nullptr, nullptr,
                                                  Vc, EXT0, EXT1, CTXb, PMc, PLc);
  combine_cross<<<ML_ * DM_ / 256, 256, 0, stream>>>(Vc, EXT0, EXT1, PMc, PLc, CTXb);
  GB(CTXb, Wt_o_c, dec_bo_c, ACT, ACT, nullptr, 512, 512, 0);
  layernorm_ip<<<ML_ / 4, 256, 0, stream>>>(ACT, dec_ln2g, dec_ln2b, DECb);

  GB(DECb, Wt_f1_d, dec_bf1, nullptr, nullptr, FFb, 2048, 512, 1);
  GB(FFb, Wt_f2_d, dec_bf2, ACT, ACT, nullptr, 512, 2048, 0);
  layernorm_ip<<<ML_ / 4, 256, 0, stream>>>(ACT, dec_ln3g, dec_ln3b, DECb);

  GF(ACT, W_proj, b_proj, X, O12, ML_, 12, DM_, ML_, 0);
  GF(O12, W1, b1, nullptr, H1, ML_, 128, 12, ML_, 2);
  GF(H1, W3, b3, nullptr, out, ML_, 3, 128, ML_, 0);
}

// Round 8
// 1028.034 us; speedup vs baseline: 1.4649x; 1.0912x over previous
//
#include <hip/hip_runtime.h>
#include <math.h>

#define B_ 4
#define H_ 8
#define L_ 1520
#define DM_ 512
#define DFF_ 2048
#define SK_ 40
#define ML_ (B_*L_)   /* 6080 rows */
#define MP_ 6144      /* padded rows for MFMA GEMM */
#define LP_ 1536      /* padded key count for V^T */

typedef unsigned short u16;
typedef short s8v __attribute__((ext_vector_type(8)));
typedef float f4 __attribute__((ext_vector_type(4)));

__device__ __forceinline__ u16 f2b(float x) {
  union { float f; unsigned u; } c; c.f = x;
  unsigned r = c.u + 0x7FFFu + ((c.u >> 16) & 1u);
  return (u16)(r >> 16);
}
__device__ __forceinline__ float b2f(u16 h) {
  union { unsigned u; float f; } c; c.u = ((unsigned)h) << 16;
  return c.f;
}
__device__ __forceinline__ float gelu_tanh(float x) {
  float x3 = x * x * x;
  return 0.5f * x * (1.f + tanhf(0.79788456080286536f * (x + 0.044715f * x3)));
}
// XCD-chunked bijective swizzle; requires nwg % 8 == 0 (cpx = nwg/8).
__device__ __forceinline__ int xswz(int bid, int cpx) {
  return (bid & 7) * cpx + (bid >> 3);
}

// ---------------- positional encoding (double precision to match numpy) ----
__global__ __launch_bounds__(256) void pe_kernel(float* __restrict__ pe) {
  int idx = blockIdx.x * 256 + threadIdx.x;
  if (idx >= L_ * DM_) return;
  int pos = idx / DM_, i = idx % DM_;
  double expo = (double)(2 * (i / 2)) / (double)DM_;
  double ang = (double)pos / pow(10000.0, expo);
  pe[idx] = (i & 1) ? (float)cos(ang) : (float)sin(ang);
}

// ---------------- x = inflow[:,2:14].reshape (contiguous slice) -------------
__global__ __launch_bounds__(256) void extract_x(const float* __restrict__ inflow,
                                                 float* __restrict__ X) {
  int idx = blockIdx.x * 256 + threadIdx.x;
  if (idx >= ML_ * 12) return;
  int b = idx / (L_ * 12);
  int rem = idx - b * (L_ * 12);
  X[idx] = inflow[(size_t)b * 14 * L_ + 2 * L_ + rem];
}

// ---------------- fused weight convert+transpose into contiguous WBF --------
struct CvtArgs {
  const float* src[15];
  unsigned cum[16];
  unsigned lk[15];
};
__global__ __launch_bounds__(256) void cvt_all(CvtArgs a, u16* __restrict__ dst) {
  unsigned idx = blockIdx.x * 256 + threadIdx.x;   // grid exact: 10485760/256
  int s = 0;
#pragma unroll
  for (int i = 1; i < 15; ++i) s += (idx >= a.cum[i]);
  unsigned local = idx - a.cum[s];
  unsigned lk = a.lk[s];
  unsigned K = 1u << lk;
  unsigned N = (a.cum[s + 1] - a.cum[s]) >> lk;
  unsigned n = local >> lk, k = local & (K - 1);
  dst[idx] = f2b(a.src[s][(size_t)k * N + n]);
}

// ---------------- activation fp32[6080][512] -> bf16[6144][512], pad 0 ------
__global__ __launch_bounds__(256) void cvt_act(const float* __restrict__ Xf,
                                               u16* __restrict__ Xb) {
  int idx = blockIdx.x * 256 + threadIdx.x;
  int row = idx >> 9;
  Xb[idx] = (row < ML_) ? f2b(Xf[idx]) : 0;
}

// ---------------- generic fp32 GEMM (small shapes only) ---------------------
__global__ __launch_bounds__(256) void gemm_f32(
    const float* __restrict__ A, const float* __restrict__ Bm,
    const float* __restrict__ bias, const float* __restrict__ res,
    float* __restrict__ C, int M, int N, int K, int res_mod, int act) {
  __shared__ float As[16][65];
  __shared__ float Bs[16][64];
  int bm = blockIdx.y * 64, bn = blockIdx.x * 64;
  int tid = threadIdx.x;
  int tx = tid % 16, ty = tid / 16;
  float acc[4][4] = {};
  for (int k0 = 0; k0 < K; k0 += 16) {
#pragma unroll
    for (int i = 0; i < 4; ++i) {
      int idx = tid + i * 256;
      int r = idx / 16, c = idx % 16;
      int gm = bm + r, gk = k0 + c;
      As[c][r] = (gm < M && gk < K) ? A[(size_t)gm * K + gk] : 0.f;
    }
#pragma unroll
    for (int i = 0; i < 4; ++i) {
      int idx = tid + i * 256;
      int r = idx / 64, c = idx % 64;
      int gk = k0 + r, gn = bn + c;
      Bs[r][c] = (gk < K && gn < N) ? Bm[(size_t)gk * N + gn] : 0.f;
    }
    __syncthreads();
#pragma unroll
    for (int kk = 0; kk < 16; ++kk) {
      float a[4], b[4];
#pragma unroll
      for (int i = 0; i < 4; ++i) a[i] = As[kk][ty + 16 * i];
#pragma unroll
      for (int j = 0; j < 4; ++j) b[j] = Bs[kk][tx + 16 * j];
#pragma unroll
      for (int i = 0; i < 4; ++i)
#pragma unroll
        for (int j = 0; j < 4; ++j) acc[i][j] += a[i] * b[j];
    }
    __syncthreads();
  }
#pragma unroll
  for (int i = 0; i < 4; ++i) {
    int gm = bm + ty + 16 * i;
    if (gm >= M) continue;
#pragma unroll
    for (int j = 0; j < 4; ++j) {
      int gn = bn + tx + 16 * j;
      if (gn >= N) continue;
      float v = acc[i][j];
      if (bias) v += bias[gn];
      if (res) v += res[(size_t)(gm % res_mod) * N + gn];
      if (act == 1) v = gelu_tanh(v);
      else if (act == 2) v = fmaxf(v, 0.f);
      C[(size_t)gm * N + gn] = v;
    }
  }
}

// ---------------- bf16 MFMA GEMM, templated tile height, XCD-swizzled -------
template<int BM>
__global__ __launch_bounds__(256) void gemm_bf16(
    const u16* __restrict__ A, const u16* __restrict__ Bt,
    const float* __restrict__ bias, const float* __restrict__ res,
    float* __restrict__ Cf, u16* __restrict__ Cb,
    int N, int K, int act) {
  __shared__ __align__(16) u16 As[BM * 32];
  __shared__ __align__(16) u16 Bs[128 * 32];
  constexpr int MI = BM / 32;
  const int nwg = gridDim.x * gridDim.y;
  const int lin = blockIdx.y * gridDim.x + blockIdx.x;
  const int o = xswz(lin, nwg >> 3);
  const int bxi = o % gridDim.x, byi = o / gridDim.x;
  const int t = threadIdx.x, w = t >> 6, lane = t & 63;
  const int lg = lane >> 4, li = lane & 15;
  const int bm = byi * BM, bn = bxi * 128;
  const int wr = (w >> 1) * (BM / 2), wc = (w & 1) * 64;
  f4 acc[MI][4];
#pragma unroll
  for (int i = 0; i < MI; ++i)
#pragma unroll
    for (int j = 0; j < 4; ++j) acc[i][j] = f4{0.f, 0.f, 0.f, 0.f};
  const int rB = w * 32 + (lane >> 2);
  const int rA = (BM == 128) ? rB : (w * 16 + (lane >> 2));
  const int ps = lane & 3;
  for (int k0 = 0; k0 < K; k0 += 32) {
    if (BM == 128) {
#pragma unroll
      for (int j = 0; j < 2; ++j) {
        int r = rA + j * 16;
        int ls = ps ^ ((r >> 1) & 3);
        __builtin_amdgcn_global_load_lds(
            (const __attribute__((address_space(1))) void*)(A + (size_t)(bm + r) * K + k0 + ls * 8),
            (__attribute__((address_space(3))) void*)(As + (w * 32 + j * 16) * 32),
            16, 0, 0);
      }
    } else {
      int ls = ps ^ ((rA >> 1) & 3);
      __builtin_amdgcn_global_load_lds(
          (const __attribute__((address_space(1))) void*)(A + (size_t)(bm + rA) * K + k0 + ls * 8),
          (__attribute__((address_space(3))) void*)(As + (w * 16) * 32),
          16, 0, 0);
    }
#pragma unroll
    for (int j = 0; j < 2; ++j) {
      int r = rB + j * 16;
      int ls = ps ^ ((r >> 1) & 3);
      __builtin_amdgcn_global_load_lds(
          (const __attribute__((address_space(1))) void*)(Bt + (size_t)(bn + r) * K + k0 + ls * 8),
          (__attribute__((address_space(3))) void*)(Bs + (w * 32 + j * 16) * 32),
          16, 0, 0);
    }
    __syncthreads();
    s8v af[MI], bf[4];
#pragma unroll
    for (int f = 0; f < MI; ++f) {
      int ra = wr + f * 16 + li;
      af[f] = *(const s8v*)(As + ra * 32 + ((lg ^ ((ra >> 1) & 3)) * 8));
    }
#pragma unroll
    for (int f = 0; f < 4; ++f) {
      int rb = wc + f * 16 + li;
      bf[f] = *(const s8v*)(Bs + rb * 32 + ((lg ^ ((rb >> 1) & 3)) * 8));
    }
#pragma unroll
    for (int fi = 0; fi < MI; ++fi)
#pragma unroll
      for (int fj = 0; fj < 4; ++fj)
        acc[fi][fj] = __builtin_amdgcn_mfma_f32_16x16x32_bf16(af[fi], bf[fj], acc[fi][fj], 0, 0, 0);
    __syncthreads();
  }
#pragma unroll
  for (int fi = 0; fi < MI; ++fi)
#pragma unroll
    for (int fj = 0; fj < 4; ++fj)
#pragma unroll
      for (int r = 0; r < 4; ++r) {
        int row = bm + wr + fi * 16 + lg * 4 + r;
        int col = bn + wc + fj * 16 + li;
        float v = acc[fi][fj][r] + bias[col];
        if (res && row < ML_) v += res[(size_t)row * N + col];
        if (act == 1) v = gelu_tanh(v);
        if (Cf && row < ML_) Cf[(size_t)row * N + col] = v;
        if (Cb) Cb[(size_t)row * N + col] = f2b(v);
      }
}

// ---------------- layernorm: wave per row, vectorized -----------------------
__global__ __launch_bounds__(256) void layernorm_ip(float* __restrict__ Xb,
                                                    const float* __restrict__ g,
                                                    const float* __restrict__ bta,
                                                    u16* __restrict__ outb) {
  int row = blockIdx.x * 4 + (threadIdx.x >> 6);
  int lane = threadIdx.x & 63;
  float* x = Xb + (size_t)row * DM_;
  f4 a = *(f4*)(x + lane * 8);
  f4 b = *(f4*)(x + lane * 8 + 4);
  float s = a[0] + a[1] + a[2] + a[3] + b[0] + b[1] + b[2] + b[3];
  for (int off = 32; off; off >>= 1) s += __shfl_xor(s, off);
  float mu = s * (1.f / 512.f);
  float vs = 0.f;
#pragma unroll
  for (int i = 0; i < 4; ++i) { a[i] -= mu; b[i] -= mu; vs += a[i] * a[i] + b[i] * b[i]; }
  for (int off = 32; off; off >>= 1) vs += __shfl_xor(vs, off);
  float rs = rsqrtf(vs * (1.f / 512.f) + 1e-5f);
  f4 g0 = *(const f4*)(g + lane * 8), g1 = *(const f4*)(g + lane * 8 + 4);
  f4 c0 = *(const f4*)(bta + lane * 8), c1 = *(const f4*)(bta + lane * 8 + 4);
  u16 ob[8];
#pragma unroll
  for (int i = 0; i < 4; ++i) {
    float r1 = a[i] * rs * g0[i] + c0[i]; x[lane * 8 + i] = r1;     ob[i] = f2b(r1);
    float r2 = b[i] * rs * g1[i] + c1[i]; x[lane * 8 + 4 + i] = r2; ob[4 + i] = f2b(r2);
  }
  *(s8v*)(outb + (size_t)row * DM_ + lane * 8) = *(s8v*)ob;
}

// ---------------- ProbSparse sparsity measure M (bf16 qkv), swizzled --------
__global__ __launch_bounds__(256) void probM(const u16* __restrict__ qkv,
                                             const int* __restrict__ sidx,
                                             float* __restrict__ Mout) {
  int wid = threadIdx.x / 64, lane = threadIdx.x % 64;
  int o = xswz(blockIdx.x, (B_ * H_ * L_ / 4) >> 3);
  int g = o * 4 + wid;
  int l = g % L_;
  int bh = g / L_;
  int h = bh % H_, b = bh / H_;
  __shared__ float qs[4][64];
  qs[wid][lane] = b2f(qkv[((size_t)b * L_ + l) * 1536 + h * 64 + lane]);
  __syncthreads();
  float dot = 0.f;
  if (lane < SK_) {
    int ks = sidx[l * SK_ + lane];
    const u16* kr = qkv + ((size_t)b * L_ + ks) * 1536 + 512 + h * 64;
#pragma unroll
    for (int j = 0; j < 8; ++j) {
      s8v v = *(const s8v*)(kr + j * 8);
#pragma unroll
      for (int i = 0; i < 8; ++i) dot += qs[wid][j * 8 + i] * b2f((u16)v[i]);
    }
  }
  float vmax = (lane < SK_) ? dot : -INFINITY;
  float vsum = (lane < SK_) ? dot : 0.f;
  for (int off = 32; off; off >>= 1) {
    vmax = fmaxf(vmax, __shfl_xor(vmax, off));
    vsum += __shfl_xor(vsum, off);
  }
  if (lane == 0) Mout[g] = vmax - vsum / (float)L_;
}

// ---------------- radix-select top-40 (matches lax.top_k selection set) -----
__global__ __launch_bounds__(256) void radix_topk(const float* __restrict__ Mv,
                                                  int* __restrict__ top) {
  const int bh = blockIdx.x;
  const int t = threadIdx.x;
  const int base = t * 6;
  unsigned key[6];
#pragma unroll
  for (int i = 0; i < 6; ++i) {
    int ix = base + i;
    unsigned k = 0u;
    if (ix < L_) {
      union { float f; unsigned u; } c; c.f = Mv[(size_t)bh * L_ + ix];
      k = c.u ^ ((c.u & 0x80000000u) ? 0xFFFFFFFFu : 0x80000000u);
    }
    key[i] = k;
  }
  __shared__ int wred[4];
  __shared__ int s_a[256], s_b[256];
  unsigned prefix = 0u;
  for (int b = 31; b >= 0; --b) {
    unsigned cand = prefix | (1u << b);
    int c = 0;
#pragma unroll
    for (int i = 0; i < 6; ++i) c += (key[i] >= cand);
    for (int off = 32; off; off >>= 1) c += __shfl_xor(c, off);
    if ((t & 63) == 0) wred[t >> 6] = c;
    __syncthreads();
    int tot = wred[0] + wred[1] + wred[2] + wred[3];
    if (tot >= SK_) prefix = cand;
    __syncthreads();
  }
  const unsigned T = prefix;
  int gt = 0, tie = 0;
#pragma unroll
  for (int i = 0; i < 6; ++i) { gt += (key[i] > T); tie += (key[i] == T); }
  s_a[t] = gt; s_b[t] = tie;
  __syncthreads();
  for (int off = 1; off < 256; off <<= 1) {
    int va = (t >= off) ? s_a[t - off] : 0;
    int vb = (t >= off) ? s_b[t - off] : 0;
    __syncthreads();
    s_a[t] += va; s_b[t] += vb;
    __syncthreads();
  }
  const int n_strict = s_a[255];
  const int gt_base = s_a[t] - gt;
  const int tie_base = s_b[t] - tie;
  const int need = SK_ - n_strict;
  int lgt = 0, ltie = 0;
#pragma unroll
  for (int i = 0; i < 6; ++i) {
    int ix = base + i;
    if (key[i] > T) {
      top[bh * SK_ + gt_base + lgt] = ix; ++lgt;
    } else if (key[i] == T) {
      int r = tie_base + ltie; ++ltie;
      if (r < need) top[bh * SK_ + n_strict + r] = ix;
    }
  }
}

// ---------------- V^T build: VT[bh][64][LP_] from V columns, swizzled -------
__global__ __launch_bounds__(256) void transpose_v(const u16* __restrict__ src,
                                                   int stride, int voff0,
                                                   u16* __restrict__ VT) {
  int o = xswz(blockIdx.x, (B_ * H_ * 24) >> 3);
  int kt = o % 24, bh = o / 24;
  int h = bh & 7, b = bh >> 3;
  int kb = kt * 64;
  __shared__ u16 tile[64][72];
  int t = threadIdx.x;
#pragma unroll
  for (int rr = 0; rr < 2; ++rr) {
    int slot = rr * 256 + t;
    int key = slot >> 3, d = (slot & 7) * 8;
    int gk = kb + key; if (gk >= L_) gk = L_ - 1;
    s8v v = *(const s8v*)(src + (size_t)(b * L_ + gk) * stride + voff0 + h * 64 + d);
    *(s8v*)(&tile[key][d]) = v;
  }
  __syncthreads();
  int dim = t >> 2, k0 = (t & 3) * 16;
  u16 buf[16];
#pragma unroll
  for (int i = 0; i < 16; ++i) {
    int key = k0 + i;
    buf[i] = (kb + key < L_) ? tile[key][dim] : (u16)0;
  }
  *(s8v*)(VT + ((size_t)bh * 64 + dim) * LP_ + kb + k0) = *(s8v*)buf;
  *(s8v*)(VT + ((size_t)bh * 64 + dim) * LP_ + kb + k0 + 8) = *(s8v*)(buf + 8);
}

// ---------------- LDS-staged swapped-operand MFMA flash attention -----------
// K and V^T tiles staged once per block via global_load_lds (coalesced,
// XOR slot-swizzled source -> linear LDS; reads apply the same XOR).
// S^T = K@Q^T so lane li owns q-row; m/l per-lane scalars, 2 shfls/tile.
// MODE 0: cross attn, 2-way K-split. orig = bh*48 + qb*2 + sp (12 tiles).
// MODE 1: prob attn (top-40 rows), 8 splits x 3 tiles; f32 partials POf.
template<int MODE>
__global__ __launch_bounds__(256) void flash_attn(
    const u16* __restrict__ Qm, const u16* __restrict__ Kg,
    const u16* __restrict__ VT, const int* __restrict__ top,
    float* __restrict__ POf, u16* POa, u16* POb,
    float* __restrict__ PM, float* __restrict__ PL) {
  constexpr int QSTR = (MODE == 0) ? 512 : 1536;
  constexpr int KSTR = (MODE == 0) ? 512 : 1536;
  constexpr int TILES = (MODE == 0) ? 12 : 3;
  constexpr int NB = (MODE == 0) ? 48 : 8;
  __shared__ __align__(16) u16 Kt[64 * 64];        // [key][slot^(key&7)]
  __shared__ __align__(16) u16 Vt[64 * 64];        // [dim][slot^(dim&7)]
  __shared__ __align__(16) unsigned Xch[4][576];   // per-wave P exchange
  const int o = xswz(blockIdx.x, (B_ * H_ * NB) >> 3);
  int bh, sp, qb;
  if (MODE == 0) {
    bh = o / 48; int rem = o % 48; qb = rem >> 1; sp = rem & 1;
  } else {
    bh = o / 8; sp = o % 8; qb = 0;
  }
  const int h = bh & 7, b = bh >> 3;
  const int qoff = h * 64;
  const int koff = ((MODE == 0) ? 0 : 512) + h * 64;
  const int t = threadIdx.x, w = t >> 6, lane = t & 63;
  const int lg = lane >> 4, li = lane & 15;
  const u16* vtg = VT + (size_t)bh * 64 * LP_;
  unsigned* xw = Xch[w];
  u16* xw16 = (u16*)xw;

  // Q as B-operand fragment: lane li = q column
  int qrow;
  if (MODE == 0) {
    int q = qb * 64 + w * 16 + li;
    qrow = b * L_ + ((q < L_) ? q : (L_ - 1));
  } else {
    int u = w * 16 + li; if (u >= SK_) u = SK_ - 1;
    qrow = b * L_ + top[bh * SK_ + u];
  }
  s8v qf0 = *(const s8v*)(Qm + (size_t)qrow * QSTR + qoff + lg * 8);
  s8v qf1 = *(const s8v*)(Qm + (size_t)qrow * QSTR + qoff + 32 + lg * 8);

  f4 o4[4];                          // o4[n][r] = O^T[d=n*16+lg*4+r][q=li]
#pragma unroll
  for (int n = 0; n < 4; ++n) o4[n] = f4{0.f, 0.f, 0.f, 0.f};
  float m_run = -INFINITY, l_run = 0.f;   // per-lane (q=li)
  const int kt0 = sp * TILES;
  const int skey = lane >> 3;        // staging: key/dim offset within 8-group
  const int sslot = lane & 7;        // staging: linear LDS slot

#pragma unroll 1
  for (int ki = 0; ki < TILES; ++ki) {
    const int kb = (kt0 + ki) * 64;
    // ---- cooperative staging: wave w covers rows w*16..w*16+15 ----
#pragma unroll
    for (int j = 0; j < 2; ++j) {
      int row = w * 16 + j * 8 + skey;
      int gk = kb + row; if (gk >= L_) gk = L_ - 1;
      int ck = sslot ^ (row & 7);
      __builtin_amdgcn_global_load_lds(
          (const __attribute__((address_space(1))) void*)(Kg + (size_t)(b * L_ + gk) * KSTR + koff + ck * 8),
          (__attribute__((address_space(3))) void*)(Kt + (w * 16 + j * 8) * 64),
          16, 0, 0);
      int cv = sslot ^ (row & 7);
      __builtin_amdgcn_global_load_lds(
          (const __attribute__((address_space(1))) void*)(vtg + (size_t)row * LP_ + kb + cv * 8),
          (__attribute__((address_space(3))) void*)(Vt + (w * 16 + j * 8) * 64),
          16, 0, 0);
    }
    __syncthreads();
    // ---- S^T = K @ Q^T / 8 : s[c][r] = S[key=kb+c*16+lg*4+r][q=li] ----
    f4 s[4];
#pragma unroll
    for (int c = 0; c < 4; ++c) {
      int key = c * 16 + li;
      s8v kf = *(const s8v*)(Kt + key * 64 + ((lg ^ (key & 7)) * 8));
      s8v kg2 = *(const s8v*)(Kt + key * 64 + (((lg + 4) ^ (key & 7)) * 8));
      f4 z = f4{0.f, 0.f, 0.f, 0.f};
      z = __builtin_amdgcn_mfma_f32_16x16x32_bf16(kf, qf0, z, 0, 0, 0);
      z = __builtin_amdgcn_mfma_f32_16x16x32_bf16(kg2, qf1, z, 0, 0, 0);
      s[c] = z * 0.125f;
    }
    if (kb + 64 > L_) {
#pragma unroll
      for (int c = 0; c < 4; ++c)
#pragma unroll
        for (int r = 0; r < 4; ++r)
          if (kb + c * 16 + lg * 4 + r >= L_) s[c][r] = -INFINITY;
    }
    // ---- online softmax (per-lane row) ----
    float tm = -INFINITY;
#pragma unroll
    for (int c = 0; c < 4; ++c)
      tm = fmaxf(tm, fmaxf(fmaxf(s[c][0], s[c][1]), fmaxf(s[c][2], s[c][3])));
    tm = fmaxf(tm, __shfl_xor(tm, 16));
    tm = fmaxf(tm, __shfl_xor(tm, 32));
    float mn = fmaxf(m_run, tm);
    float sc = __expf(m_run - mn);
    float p[4][4];
    float rs = 0.f;
#pragma unroll
    for (int c = 0; c < 4; ++c)
#pragma unroll
      for (int r = 0; r < 4; ++r) { p[c][r] = __expf(s[c][r] - mn); rs += p[c][r]; }
    rs += __shfl_xor(rs, 16);
    rs += __shfl_xor(rs, 32);
    l_run = l_run * sc + rs;
    m_run = mn;
#pragma unroll
    for (int n = 0; n < 4; ++n) o4[n] *= sc;
    // ---- P exchange (per-wave, no block barrier) ----
#pragma unroll
    for (int c = 0; c < 4; ++c)
#pragma unroll
      for (int rp = 0; rp < 2; ++rp) {
        unsigned v = (unsigned)f2b(p[c][2 * rp]) | ((unsigned)f2b(p[c][2 * rp + 1]) << 16);
        xw[li * 36 + c * 8 + lg * 2 + rp] = v;
      }
    s8v pb0 = *(const s8v*)(xw + li * 36 + lg * 4);
    s8v pb1 = *(const s8v*)(xw + li * 36 + 16 + lg * 4);
    // ---- O^T += V^T @ P^T ----
#pragma unroll
    for (int n = 0; n < 4; ++n) {
      int dim = n * 16 + li;
      s8v vb0 = *(const s8v*)(Vt + dim * 64 + ((lg ^ (dim & 7)) * 8));
      o4[n] = __builtin_amdgcn_mfma_f32_16x16x32_bf16(vb0, pb0, o4[n], 0, 0, 0);
    }
#pragma unroll
    for (int n = 0; n < 4; ++n) {
      int dim = n * 16 + li;
      s8v vb1 = *(const s8v*)(Vt + dim * 64 + (((lg + 4) ^ (dim & 7)) * 8));
      o4[n] = __builtin_amdgcn_mfma_f32_16x16x32_bf16(vb1, pb1, o4[n], 0, 0, 0);
    }
    __syncthreads();   // protect Kt/Vt before next staging
  }

  if (MODE == 0) {
    // per-wave LDS transpose [q][d], then coalesced unnormalized bf16 store
#pragma unroll
    for (int n = 0; n < 4; ++n)
#pragma unroll
      for (int r = 0; r < 4; ++r)
        xw16[li * 72 + n * 16 + lg * 4 + r] = f2b(o4[n][r]);
    u16* PO = sp ? POb : POa;
    const int pid = (bh * 24 + qb) * 2 + sp;
    int q_local = lane >> 2, d0 = (lane & 3) * 16;
    int q = qb * 64 + w * 16 + q_local;
    s8v v0 = *(const s8v*)(xw16 + q_local * 72 + d0);
    s8v v1 = *(const s8v*)(xw16 + q_local * 72 + d0 + 8);
    if (q < L_) {
      u16* dst = PO + ((size_t)(b * L_ + q)) * DM_ + qoff + d0;
      *(s8v*)dst = v0;
      *(s8v*)(dst + 8) = v1;
    }
    if (lg == 0) {
      PM[pid * 64 + w * 16 + li] = m_run;
      PL[pid * 64 + w * 16 + li] = l_run;
    }
  } else {
    int base = (bh * 8 + sp) * 64 + w * 16 + li;
#pragma unroll
    for (int n = 0; n < 4; ++n)
#pragma unroll
      for (int r = 0; r < 4; ++r)
        POf[(size_t)base * 64 + n * 16 + lg * 4 + r] = o4[n][r];
    if (lg == 0) {
      PM[base] = m_run;
      PL[base] = l_run;
    }
  }
}

// ---------------- combine 2-way cross partials (POb == ctxb, in place) ------
__global__ __launch_bounds__(256) void combine_cross(const u16* __restrict__ PO0,
                                                     const float* __restrict__ PM,
                                                     const float* __restrict__ PL,
                                                     u16* ctxb) {
  int idx = blockIdx.x * 256 + threadIdx.x;   // grid exact: ML_*DM_/256
  int row = idx >> 9, col = idx & 511;
  int b = row / L_, q = row - b * L_;
  int h = col >> 6;
  int bh = b * 8 + h, qbk = q >> 6, qi = q & 63;
  int p0 = ((bh * 24 + qbk) * 2) * 64 + qi;
  float m0 = PM[p0], m1 = PM[p0 + 64];
  float l0 = PL[p0], l1 = PL[p0 + 64];
  float M = fmaxf(m0, m1);
  float w0 = __expf(m0 - M), w1 = __expf(m1 - M);
  float inv = 1.f / (w0 * l0 + w1 * l1);
  float o0 = b2f(PO0[idx]);
  float o1 = b2f(ctxb[idx]);
  ctxb[idx] = f2b((w0 * o0 + w1 * o1) * inv);
}

// ---------------- combine split-K partials -> ctt ----------------------------
__global__ __launch_bounds__(256) void combine_prob(const float* __restrict__ PO,
                                                    const float* __restrict__ PM,
                                                    const float* __restrict__ PL,
                                                    float* __restrict__ ctt) {
  int bh = blockIdx.x;
  int t = threadIdx.x;
  int u = t >> 2, dg = (t & 3) * 16;
  if (u >= SK_) return;
  float M = -INFINITY;
  for (int s = 0; s < 8; ++s) M = fmaxf(M, PM[(bh * 8 + s) * 64 + u]);
  float wgt[8];
  float den = 0.f;
  for (int s = 0; s < 8; ++s) {
    wgt[s] = __expf(PM[(bh * 8 + s) * 64 + u] - M);
    den += wgt[s] * PL[(bh * 8 + s) * 64 + u];
  }
  float inv = 1.f / den;
  for (int d = dg; d < dg + 16; ++d) {
    float acc = 0.f;
    for (int s = 0; s < 8; ++s) acc += wgt[s] * PO[(((size_t)bh * 8 + s) * 64 + u) * 64 + d];
    ctt[((size_t)bh * SK_ + u) * 64 + d] = acc * inv;
  }
}

// ---------------- V mean: 8-way partial + combine, swizzled -----------------
__global__ __launch_bounds__(256) void vmean_part(const u16* __restrict__ qkv,
                                                  float* __restrict__ part) {
  int g = xswz(blockIdx.x, (B_ * H_ * 8) >> 3);
  int bh = g >> 3, seg = g & 7;
  int h = bh & 7, b = bh >> 3;
  int lane = threadIdx.x & 63, grp = threadIdx.x >> 6;
  int k0 = seg * 190, k1 = k0 + 190;
  float acc = 0.f;
  for (int k = k0 + grp; k < k1; k += 4)
    acc += b2f(qkv[((size_t)b * L_ + k) * 1536 + 1024 + h * 64 + lane]);
  __shared__ float pv[4][64];
  pv[grp][lane] = acc;
  __syncthreads();
  if (threadIdx.x < 64)
    part[g * 64 + threadIdx.x] =
        pv[0][threadIdx.x] + pv[1][threadIdx.x] + pv[2][threadIdx.x] + pv[3][threadIdx.x];
}

__global__ __launch_bounds__(256) void vmean_comb(const float* __restrict__ part,
                                                  float* __restrict__ vmean) {
  int idx = blockIdx.x * 256 + threadIdx.x;   // 2048
  int bh = idx >> 6, d = idx & 63;
  float s = 0.f;
#pragma unroll
  for (int seg = 0; seg < 8; ++seg) s += part[(bh * 8 + seg) * 64 + d];
  vmean[idx] = s / (float)L_;
}

// ---------------- ctx = broadcast vmean (bf16), then scatter top ------------
__global__ __launch_bounds__(256) void fill_ctx(const float* __restrict__ vmean,
                                                u16* __restrict__ ctxb) {
  int idx = blockIdx.x * 256 + threadIdx.x;
  int d = idx % 64;
  int h = (idx / 64) % H_;
  int b = idx / (L_ * DM_);
  ctxb[idx] = f2b(vmean[(b * H_ + h) * 64 + d]);
}

__global__ __launch_bounds__(256) void scatter_ctx(const float* __restrict__ ctt,
                                                   const int* __restrict__ top,
                                                   u16* __restrict__ ctxb) {
  int idx = blockIdx.x * 256 + threadIdx.x;
  int d = idx % 64;
  int u = (idx / 64) % SK_;
  int bh = idx / (64 * SK_);
  int h = bh % H_, b = bh / H_;
  int l = top[bh * SK_ + u];
  ctxb[((size_t)b * L_ + l) * DM_ + h * 64 + d] = f2b(ctt[idx]);
}

// ---------------- host side --------------------------------------------------
extern "C" void kernel_launch(void* const* d_in, const int* in_sizes, int n_in,
                              void* d_out, int out_size, void* d_ws, size_t ws_size,
                              hipStream_t stream) {
  const float* inflow   = (const float*)d_in[4];
  const float* W_emb_e  = (const float*)d_in[5];
  const float* b_emb_e  = (const float*)d_in[6];
  const float* W_emb_d  = (const float*)d_in[7];
  const float* b_emb_d  = (const float*)d_in[8];
  const float* enc_Wqkv = (const float*)d_in[9];
  const float* enc_bqkv = (const float*)d_in[10];
  const float* enc_Wo   = (const float*)d_in[11];
  const float* enc_bo   = (const float*)d_in[12];
  const float* enc_ln1g = (const float*)d_in[13];
  const float* enc_ln1b = (const float*)d_in[14];
  const float* enc_Wf1  = (const float*)d_in[15];
  const float* enc_bf1  = (const float*)d_in[16];
  const float* enc_Wf2  = (const float*)d_in[17];
  const float* enc_bf2  = (const float*)d_in[18];
  const float* enc_ln2g = (const float*)d_in[19];
  const float* enc_ln2b = (const float*)d_in[20];
  const float* enc_ng   = (const float*)d_in[21];
  const float* enc_nb   = (const float*)d_in[22];
  const float* dec_Wqkv = (const float*)d_in[23];
  const float* dec_bqkv = (const float*)d_in[24];
  const float* dec_Wo_s = (const float*)d_in[25];
  const float* dec_bo_s = (const float*)d_in[26];
  const float* dec_ln1g = (const float*)d_in[27];
  const float* dec_ln1b = (const float*)d_in[28];
  const float* dec_Wq_c = (const float*)d_in[29];
  const float* dec_bq_c = (const float*)d_in[30];
  const float* dec_Wkv  = (const float*)d_in[31];
  const float* dec_bkv  = (const float*)d_in[32];
  const float* dec_Wo_c = (const float*)d_in[33];
  const float* dec_bo_c = (const float*)d_in[34];
  const float* dec_ln2g = (const float*)d_in[35];
  const float* dec_ln2b = (const float*)d_in[36];
  const float* dec_Wf1  = (const float*)d_in[37];
  const float* dec_bf1  = (const float*)d_in[38];
  const float* dec_Wf2  = (const float*)d_in[39];
  const float* dec_bf2  = (const float*)d_in[40];
  const float* dec_ln3g = (const float*)d_in[41];
  const float* dec_ln3b = (const float*)d_in[42];
  const float* W_proj   = (const float*)d_in[43];
  const float* b_proj   = (const float*)d_in[44];
  const float* W1       = (const float*)d_in[45];
  const float* b1       = (const float*)d_in[46];
  const float* W3       = (const float*)d_in[47];
  const float* b3       = (const float*)d_in[48];
  const int*   samp     = (const int*)d_in[49];
  float* out = (float*)d_out;

  float* ws  = (float*)d_ws;
  float* PE  = ws;                       // 778240 f (dead after embeds -> PM/PL)
  float* X   = PE + 778240;              // 72960 f
  float* ACT = X + 72960;                // 3112960 f
  float* REG = ACT + 3112960;            // 6291456 f shared region
  float* MME = REG + 6291456;            // 48640 f (VME8 overlay after topk)
  float* CTT = MME + 48640;              // 81920 f
  float* VME = CTT + 81920;              // 2048 f
  int*   TOP = (int*)(VME + 2048);       // 1280 i
  float* TAIL = VME + 2048 + 1280;
  u16* ENCb = (u16*)TAIL;                       // 6144*512 u16
  u16* DECb = (u16*)(TAIL + 1572864);
  u16* CTXb = (u16*)(TAIL + 2 * 1572864);
  u16* WBF  = (u16*)(TAIL + 3 * 1572864);       // 10485760 u16

  // region overlays (prob phase)
  u16* QKVb = (u16*)REG;                 // [6144][1536]
  u16* FFb  = (u16*)REG;                 // [6144][2048]
  u16* VT   = (u16*)REG + 9437184;       // [32][64][1536] u16
  // region overlays (cross phase)
  u16* QCb  = (u16*)REG;                 // [6144][512]
  u16* Kc   = (u16*)REG + 3145728;       // [6144][512]
  u16* Vc   = (u16*)REG + 6291456;       // [6144][512]; becomes PO-split0 after transpose
  float* O12 = REG;                      // head overlays
  float* H1  = REG + 72960;
  // prob split-K partials overlay CTXb (rebuilt by fill_ctx afterwards)
  float* POp = (float*)CTXb;             // 32*8*64*64 f
  float* PMp = POp + 1048576;
  float* PLp = PMp + 16384;
  // cross partial stats in dead PE region (32*24*2*64 = 98304 each)
  float* PMc = PE;
  float* PLc = PE + 98304;
  float* VME8 = MME;                     // 16384 f (after radix_topk)

  auto GB = [&](const u16* A, const u16* Bt, const float* bias, const float* res,
                float* Cf, u16* Cb, int N, int K, int act) {
    if (N <= 512) {
      dim3 g(N / 128, MP_ / 64);
      gemm_bf16<64><<<g, 256, 0, stream>>>(A, Bt, bias, res, Cf, Cb, N, K, act);
    } else {
      dim3 g(N / 128, MP_ / 128);
      gemm_bf16<128><<<g, 256, 0, stream>>>(A, Bt, bias, res, Cf, Cb, N, K, act);
    }
  };
  auto GF = [&](const float* A, const float* Bm, const float* bias, const float* res,
                float* C, int M, int N, int K, int res_mod, int act) {
    dim3 g((N + 63) / 64, (M + 63) / 64);
    gemm_f32<<<g, 256, 0, stream>>>(A, Bm, bias, res, C, M, N, K, res_mod, act);
  };
  auto PROB = [&](const int* sidx) {
    probM<<<B_ * H_ * L_ / 4, 256, 0, stream>>>(QKVb, sidx, MME);
    radix_topk<<<B_ * H_, 256, 0, stream>>>(MME, TOP);
    transpose_v<<<B_ * H_ * 24, 256, 0, stream>>>(QKVb, 1536, 1024, VT);
    flash_attn<1><<<B_ * H_ * 8, 256, 0, stream>>>(QKVb, QKVb, VT, TOP, POp,
                                                   nullptr, nullptr, PMp, PLp);
    combine_prob<<<B_ * H_, 256, 0, stream>>>(POp, PMp, PLp, CTT);
    vmean_part<<<B_ * H_ * 8, 256, 0, stream>>>(QKVb, VME8);
    vmean_comb<<<8, 256, 0, stream>>>(VME8, VME);
    fill_ctx<<<ML_ * DM_ / 256, 256, 0, stream>>>(VME, CTXb);
    scatter_ctx<<<B_ * H_ * SK_ * 64 / 256, 256, 0, stream>>>(CTT, TOP, CTXb);
  };

  pe_kernel<<<(L_ * DM_ + 255) / 256, 256, 0, stream>>>(PE);
  extract_x<<<(ML_ * 12 + 255) / 256, 256, 0, stream>>>(inflow, X);

  // one fused weight-conversion dispatch (WBF slots are contiguous)
  {
    CvtArgs a;
    const float* s[15] = {
      enc_Wqkv, enc_Wqkv + 512 * 1536, enc_Wo, enc_Wo + 512 * 512,
      enc_Wf1, enc_Wf1 + 512 * 2048, enc_Wf2, enc_Wf2 + 2048 * 512,
      dec_Wqkv, dec_Wo_s, dec_Wq_c, dec_Wkv, dec_Wo_c, dec_Wf1, dec_Wf2 };
    unsigned cum[16] = { 0u, 786432u, 1572864u, 1835008u, 2097152u, 3145728u,
                         4194304u, 5242880u, 6291456u, 7077888u, 7340032u,
                         7602176u, 8126464u, 8388608u, 9437184u, 10485760u };
    unsigned lk[15] = { 9, 9, 9, 9, 9, 9, 11, 11, 9, 9, 9, 9, 9, 9, 11 };
    for (int i = 0; i < 15; ++i) { a.src[i] = s[i]; a.lk[i] = lk[i]; }
    for (int i = 0; i < 16; ++i) a.cum[i] = cum[i];
    cvt_all<<<10485760 / 256, 256, 0, stream>>>(a, WBF);
  }
  u16* Wt_qkv_e0 = WBF + 0;
  u16* Wt_qkv_e1 = WBF + 786432;
  u16* Wt_o_e0   = WBF + 1572864;
  u16* Wt_o_e1   = WBF + 1835008;
  u16* Wt_f1_e0  = WBF + 2097152;
  u16* Wt_f1_e1  = WBF + 3145728;
  u16* Wt_f2_e0  = WBF + 4194304;
  u16* Wt_f2_e1  = WBF + 5242880;
  u16* Wt_qkv_d  = WBF + 6291456;
  u16* Wt_o_s    = WBF + 7077888;
  u16* Wt_q_c    = WBF + 7340032;
  u16* Wt_kv_c   = WBF + 7602176;
  u16* Wt_o_c    = WBF + 8126464;
  u16* Wt_f1_d   = WBF + 8388608;
  u16* Wt_f2_d   = WBF + 9437184;

  // ---------------- encoder ----------------
  GF(X, W_emb_e, b_emb_e, PE, ACT, ML_, DM_, 12, L_, 0);
  cvt_act<<<MP_ * DM_ / 256, 256, 0, stream>>>(ACT, ENCb);

  const u16* Wqkv_e[2] = {Wt_qkv_e0, Wt_qkv_e1};
  const u16* Wo_e[2]   = {Wt_o_e0, Wt_o_e1};
  const u16* Wf1_e[2]  = {Wt_f1_e0, Wt_f1_e1};
  const u16* Wf2_e[2]  = {Wt_f2_e0, Wt_f2_e1};
  for (int i = 0; i < 2; ++i) {
    GB(ENCb, Wqkv_e[i], enc_bqkv + i * 1536, nullptr, nullptr, QKVb, 1536, 512, 0);
    PROB(samp + (size_t)i * L_ * SK_);
    GB(CTXb, Wo_e[i], enc_bo + i * 512, ACT, ACT, nullptr, 512, 512, 0);
    layernorm_ip<<<ML_ / 4, 256, 0, stream>>>(ACT, enc_ln1g + i * 512, enc_ln1b + i * 512, ENCb);
    GB(ENCb, Wf1_e[i], enc_bf1 + i * 2048, nullptr, nullptr, FFb, 2048, 512, 1);
    GB(FFb, Wf2_e[i], enc_bf2 + i * 512, ACT, ACT, nullptr, 512, 2048, 0);
    layernorm_ip<<<ML_ / 4, 256, 0, stream>>>(ACT, enc_ln2g + i * 512, enc_ln2b + i * 512, ENCb);
  }
  layernorm_ip<<<ML_ / 4, 256, 0, stream>>>(ACT, enc_ng, enc_nb, ENCb);

  // ---------------- decoder ----------------
  GF(X, W_emb_d, b_emb_d, PE, ACT, ML_, DM_, 12, L_, 0);
  cvt_act<<<MP_ * DM_ / 256, 256, 0, stream>>>(ACT, DECb);
  GB(DECb, Wt_qkv_d, dec_bqkv, nullptr, nullptr, QKVb, 1536, 512, 0);
  PROB(samp + (size_t)2 * L_ * SK_);
  GB(CTXb, Wt_o_s, dec_bo_s, ACT, ACT, nullptr, 512, 512, 0);
  layernorm_ip<<<ML_ / 4, 256, 0, stream>>>(ACT, dec_ln1g, dec_ln1b, DECb);

  // cross attention: Q, K, V as separate [*,512] GEMMs; V buffer becomes split-0
  GB(DECb, Wt_q_c, dec_bq_c, nullptr, nullptr, QCb, 512, 512, 0);
  GB(ENCb, Wt_kv_c, dec_bkv, nullptr, nullptr, Kc, 512, 512, 0);
  GB(ENCb, Wt_kv_c + 512 * 512, dec_bkv + 512, nullptr, nullptr, Vc, 512, 512, 0);
  transpose_v<<<B_ * H_ * 24, 256, 0, stream>>>(Vc, 512, 0, VT);
  flash_attn<0><<<B_ * H_ * 48, 256, 0, stream>>>(QCb, Kc, VT, nullptr, nullptr,
                                                  Vc, CTXb, PMc, PLc);
  combine_cross<<<ML_ * DM_ / 256, 256, 0, stream>>>(Vc, PMc, PLc, CTXb);
  GB(CTXb, Wt_o_c, dec_bo_c, ACT, ACT, nullptr, 512, 512, 0);
  layernorm_ip<<<ML_ / 4, 256, 0, stream>>>(ACT, dec_ln2g, dec_ln2b, DECb);

  GB(DECb, Wt_f1_d, dec_bf1, nullptr, nullptr, FFb, 2048, 512, 1);
  GB(FFb, Wt_f2_d, dec_bf2, ACT, ACT, nullptr, 512, 2048, 0);
  layernorm_ip<<<ML_ / 4, 256, 0, stream>>>(ACT, dec_ln3g, dec_ln3b, DECb);

  GF(ACT, W_proj, b_proj, X, O12, ML_, 12, DM_, ML_, 0);
  GF(O12, W1, b1, nullptr, H1, ML_, 128, 12, ML_, 2);
  GF(H1, W3, b3, nullptr, out, ML_, 3, 128, ML_, 0);
}

// Round 9
// 918.881 us; speedup vs baseline: 1.6389x; 1.1188x over previous
//
#include <hip/hip_runtime.h>
#include <math.h>

#define B_ 4
#define H_ 8
#define L_ 1520
#define DM_ 512
#define DFF_ 2048
#define SK_ 40
#define ML_ (B_*L_)   /* 6080 rows */
#define MP_ 6144      /* padded rows for MFMA GEMM */
#define LP_ 1536      /* padded key count for V^T */

typedef unsigned short u16;
typedef short s8v __attribute__((ext_vector_type(8)));
typedef float f4 __attribute__((ext_vector_type(4)));

__device__ __forceinline__ u16 f2b(float x) {
  union { float f; unsigned u; } c; c.f = x;
  unsigned r = c.u + 0x7FFFu + ((c.u >> 16) & 1u);
  return (u16)(r >> 16);
}
__device__ __forceinline__ float b2f(u16 h) {
  union { unsigned u; float f; } c; c.u = ((unsigned)h) << 16;
  return c.f;
}
__device__ __forceinline__ float gelu_tanh(float x) {
  float x3 = x * x * x;
  return 0.5f * x * (1.f + tanhf(0.79788456080286536f * (x + 0.044715f * x3)));
}
// XCD-chunked bijective swizzle; requires nwg % 8 == 0 (cpx = nwg/8).
__device__ __forceinline__ int xswz(int bid, int cpx) {
  return (bid & 7) * cpx + (bid >> 3);
}

// ---------------- positional encoding (double precision to match numpy) ----
__global__ __launch_bounds__(256) void pe_kernel(float* __restrict__ pe) {
  int idx = blockIdx.x * 256 + threadIdx.x;
  if (idx >= L_ * DM_) return;
  int pos = idx / DM_, i = idx % DM_;
  double expo = (double)(2 * (i / 2)) / (double)DM_;
  double ang = (double)pos / pow(10000.0, expo);
  pe[idx] = (i & 1) ? (float)cos(ang) : (float)sin(ang);
}

// ---------------- x = inflow[:,2:14].reshape (contiguous slice) -------------
__global__ __launch_bounds__(256) void extract_x(const float* __restrict__ inflow,
                                                 float* __restrict__ X) {
  int idx = blockIdx.x * 256 + threadIdx.x;
  if (idx >= ML_ * 12) return;
  int b = idx / (L_ * 12);
  int rem = idx - b * (L_ * 12);
  X[idx] = inflow[(size_t)b * 14 * L_ + 2 * L_ + rem];
}

// ---------------- fused weight convert+transpose into contiguous WBF --------
struct CvtArgs {
  const float* src[15];
  unsigned cum[16];
  unsigned lk[15];
};
__global__ __launch_bounds__(256) void cvt_all(CvtArgs a, u16* __restrict__ dst) {
  unsigned idx = blockIdx.x * 256 + threadIdx.x;   // grid exact: 10485760/256
  int s = 0;
#pragma unroll
  for (int i = 1; i < 15; ++i) s += (idx >= a.cum[i]);
  unsigned local = idx - a.cum[s];
  unsigned lk = a.lk[s];
  unsigned K = 1u << lk;
  unsigned N = (a.cum[s + 1] - a.cum[s]) >> lk;
  unsigned n = local >> lk, k = local & (K - 1);
  dst[idx] = f2b(a.src[s][(size_t)k * N + n]);
}

// ---------------- fused embed: ACT = X@W + b + PE ; ACTb = bf16(ACT) --------
// grid = MP_/4 blocks; pad rows (>= ML_) get bf16 zeros only.
__global__ __launch_bounds__(256) void embed_fused(
    const float* __restrict__ X, const float* __restrict__ W,
    const float* __restrict__ bias, const float* __restrict__ PE,
    float* __restrict__ ACT, u16* __restrict__ ACTb) {
  int row = blockIdx.x * 4 + (threadIdx.x >> 6);
  int lane = threadIdx.x & 63;
  int d0 = lane * 8;
  if (row >= ML_) {
    s8v z = {0, 0, 0, 0, 0, 0, 0, 0};
    *(s8v*)(ACTb + (size_t)row * DM_ + d0) = z;
    return;
  }
  int prow = row % L_;
  f4 a0 = *(const f4*)(bias + d0);
  f4 a1 = *(const f4*)(bias + d0 + 4);
  a0 += *(const f4*)(PE + (size_t)prow * DM_ + d0);
  a1 += *(const f4*)(PE + (size_t)prow * DM_ + d0 + 4);
  const float* xr = X + (size_t)row * 12;
#pragma unroll
  for (int t = 0; t < 12; ++t) {
    float xv = xr[t];
    a0 += xv * *(const f4*)(W + (size_t)t * DM_ + d0);
    a1 += xv * *(const f4*)(W + (size_t)t * DM_ + d0 + 4);
  }
  float* dst = ACT + (size_t)row * DM_ + d0;
  *(f4*)dst = a0;
  *(f4*)(dst + 4) = a1;
  u16 ob[8];
#pragma unroll
  for (int i = 0; i < 4; ++i) { ob[i] = f2b(a0[i]); ob[4 + i] = f2b(a1[i]); }
  *(s8v*)(ACTb + (size_t)row * DM_ + d0) = *(s8v*)ob;
}

// ---------------- fused head: out = relu((DEC@Wp+bp+X)@W1+b1)@W3+b3 ---------
// grid = ML_/4 blocks; one wave per row.
__global__ __launch_bounds__(256) void head_fused(
    const float* __restrict__ DEC, const float* __restrict__ X,
    const float* __restrict__ Wp, const float* __restrict__ bp,
    const float* __restrict__ W1, const float* __restrict__ b1,
    const float* __restrict__ W3, const float* __restrict__ b3,
    float* __restrict__ out) {
  int row = blockIdx.x * 4 + (threadIdx.x >> 6);
  int lane = threadIdx.x & 63;
  int d0 = lane * 8;
  const float* dec = DEC + (size_t)row * DM_ + d0;
  f4 v0 = *(const f4*)dec;
  f4 v1 = *(const f4*)(dec + 4);
  float pj[12];
#pragma unroll
  for (int j = 0; j < 12; ++j) pj[j] = 0.f;
#pragma unroll
  for (int i = 0; i < 8; ++i) {
    float dv = (i < 4) ? v0[i] : v1[i - 4];
    const float* wr = Wp + (size_t)(d0 + i) * 12;
#pragma unroll
    for (int j = 0; j < 12; ++j) pj[j] += dv * wr[j];
  }
  for (int off = 32; off; off >>= 1) {
#pragma unroll
    for (int j = 0; j < 12; ++j) pj[j] += __shfl_xor(pj[j], off);
  }
  float o12[12];
#pragma unroll
  for (int j = 0; j < 12; ++j) o12[j] = pj[j] + bp[j] + X[(size_t)row * 12 + j];
  int k0 = lane * 2;
  float h0 = b1[k0], h1 = b1[k0 + 1];
#pragma unroll
  for (int j = 0; j < 12; ++j) {
    h0 += o12[j] * W1[j * 128 + k0];
    h1 += o12[j] * W1[j * 128 + k0 + 1];
  }
  h0 = fmaxf(h0, 0.f);
  h1 = fmaxf(h1, 0.f);
  float op[3];
#pragma unroll
  for (int p = 0; p < 3; ++p)
    op[p] = h0 * W3[k0 * 3 + p] + h1 * W3[(k0 + 1) * 3 + p];
  for (int off = 32; off; off >>= 1) {
#pragma unroll
    for (int p = 0; p < 3; ++p) op[p] += __shfl_xor(op[p], off);
  }
  if (lane == 0) {
#pragma unroll
    for (int p = 0; p < 3; ++p) out[(size_t)row * 3 + p] = op[p] + b3[p];
  }
}

// ---------------- bf16 MFMA GEMM, templated tile height, XCD-swizzled -------
template<int BM>
__global__ __launch_bounds__(256) void gemm_bf16(
    const u16* __restrict__ A, const u16* __restrict__ Bt,
    const float* __restrict__ bias, const float* __restrict__ res,
    float* __restrict__ Cf, u16* __restrict__ Cb,
    int N, int K, int act) {
  __shared__ __align__(16) u16 As[BM * 32];
  __shared__ __align__(16) u16 Bs[128 * 32];
  constexpr int MI = BM / 32;
  const int nwg = gridDim.x * gridDim.y;
  const int lin = blockIdx.y * gridDim.x + blockIdx.x;
  const int o = xswz(lin, nwg >> 3);
  const int bxi = o % gridDim.x, byi = o / gridDim.x;
  const int t = threadIdx.x, w = t >> 6, lane = t & 63;
  const int lg = lane >> 4, li = lane & 15;
  const int bm = byi * BM, bn = bxi * 128;
  const int wr = (w >> 1) * (BM / 2), wc = (w & 1) * 64;
  f4 acc[MI][4];
#pragma unroll
  for (int i = 0; i < MI; ++i)
#pragma unroll
    for (int j = 0; j < 4; ++j) acc[i][j] = f4{0.f, 0.f, 0.f, 0.f};
  const int rB = w * 32 + (lane >> 2);
  const int rA = (BM == 128) ? rB : (w * 16 + (lane >> 2));
  const int ps = lane & 3;
  for (int k0 = 0; k0 < K; k0 += 32) {
    if (BM == 128) {
#pragma unroll
      for (int j = 0; j < 2; ++j) {
        int r = rA + j * 16;
        int ls = ps ^ ((r >> 1) & 3);
        __builtin_amdgcn_global_load_lds(
            (const __attribute__((address_space(1))) void*)(A + (size_t)(bm + r) * K + k0 + ls * 8),
            (__attribute__((address_space(3))) void*)(As + (w * 32 + j * 16) * 32),
            16, 0, 0);
      }
    } else {
      int ls = ps ^ ((rA >> 1) & 3);
      __builtin_amdgcn_global_load_lds(
          (const __attribute__((address_space(1))) void*)(A + (size_t)(bm + rA) * K + k0 + ls * 8),
          (__attribute__((address_space(3))) void*)(As + (w * 16) * 32),
          16, 0, 0);
    }
#pragma unroll
    for (int j = 0; j < 2; ++j) {
      int r = rB + j * 16;
      int ls = ps ^ ((r >> 1) & 3);
      __builtin_amdgcn_global_load_lds(
          (const __attribute__((address_space(1))) void*)(Bt + (size_t)(bn + r) * K + k0 + ls * 8),
          (__attribute__((address_space(3))) void*)(Bs + (w * 32 + j * 16) * 32),
          16, 0, 0);
    }
    __syncthreads();
    s8v af[MI], bf[4];
#pragma unroll
    for (int f = 0; f < MI; ++f) {
      int ra = wr + f * 16 + li;
      af[f] = *(const s8v*)(As + ra * 32 + ((lg ^ ((ra >> 1) & 3)) * 8));
    }
#pragma unroll
    for (int f = 0; f < 4; ++f) {
      int rb = wc + f * 16 + li;
      bf[f] = *(const s8v*)(Bs + rb * 32 + ((lg ^ ((rb >> 1) & 3)) * 8));
    }
#pragma unroll
    for (int fi = 0; fi < MI; ++fi)
#pragma unroll
      for (int fj = 0; fj < 4; ++fj)
        acc[fi][fj] = __builtin_amdgcn_mfma_f32_16x16x32_bf16(af[fi], bf[fj], acc[fi][fj], 0, 0, 0);
    __syncthreads();
  }
#pragma unroll
  for (int fi = 0; fi < MI; ++fi)
#pragma unroll
    for (int fj = 0; fj < 4; ++fj)
#pragma unroll
      for (int r = 0; r < 4; ++r) {
        int row = bm + wr + fi * 16 + lg * 4 + r;
        int col = bn + wc + fj * 16 + li;
        float v = acc[fi][fj][r] + bias[col];
        if (res && row < ML_) v += res[(size_t)row * N + col];
        if (act == 1) v = gelu_tanh(v);
        if (Cf && row < ML_) Cf[(size_t)row * N + col] = v;
        if (Cb) Cb[(size_t)row * N + col] = f2b(v);
      }
}

// ---------------- layernorm: wave per row, vectorized -----------------------
__global__ __launch_bounds__(256) void layernorm_ip(float* __restrict__ Xb,
                                                    const float* __restrict__ g,
                                                    const float* __restrict__ bta,
                                                    u16* __restrict__ outb) {
  int row = blockIdx.x * 4 + (threadIdx.x >> 6);
  int lane = threadIdx.x & 63;
  float* x = Xb + (size_t)row * DM_;
  f4 a = *(f4*)(x + lane * 8);
  f4 b = *(f4*)(x + lane * 8 + 4);
  float s = a[0] + a[1] + a[2] + a[3] + b[0] + b[1] + b[2] + b[3];
  for (int off = 32; off; off >>= 1) s += __shfl_xor(s, off);
  float mu = s * (1.f / 512.f);
  float vs = 0.f;
#pragma unroll
  for (int i = 0; i < 4; ++i) { a[i] -= mu; b[i] -= mu; vs += a[i] * a[i] + b[i] * b[i]; }
  for (int off = 32; off; off >>= 1) vs += __shfl_xor(vs, off);
  float rs = rsqrtf(vs * (1.f / 512.f) + 1e-5f);
  f4 g0 = *(const f4*)(g + lane * 8), g1 = *(const f4*)(g + lane * 8 + 4);
  f4 c0 = *(const f4*)(bta + lane * 8), c1 = *(const f4*)(bta + lane * 8 + 4);
  u16 ob[8];
#pragma unroll
  for (int i = 0; i < 4; ++i) {
    float r1 = a[i] * rs * g0[i] + c0[i]; x[lane * 8 + i] = r1;     ob[i] = f2b(r1);
    float r2 = b[i] * rs * g1[i] + c1[i]; x[lane * 8 + 4 + i] = r2; ob[4 + i] = f2b(r2);
  }
  *(s8v*)(outb + (size_t)row * DM_ + lane * 8) = *(s8v*)ob;
}

// ---------------- ProbSparse sparsity measure M (bf16 qkv), swizzled --------
__global__ __launch_bounds__(256) void probM(const u16* __restrict__ qkv,
                                             const int* __restrict__ sidx,
                                             float* __restrict__ Mout) {
  int wid = threadIdx.x / 64, lane = threadIdx.x % 64;
  int o = xswz(blockIdx.x, (B_ * H_ * L_ / 4) >> 3);
  int g = o * 4 + wid;
  int l = g % L_;
  int bh = g / L_;
  int h = bh % H_, b = bh / H_;
  __shared__ float qs[4][64];
  qs[wid][lane] = b2f(qkv[((size_t)b * L_ + l) * 1536 + h * 64 + lane]);
  __syncthreads();
  float dot = 0.f;
  if (lane < SK_) {
    int ks = sidx[l * SK_ + lane];
    const u16* kr = qkv + ((size_t)b * L_ + ks) * 1536 + 512 + h * 64;
#pragma unroll
    for (int j = 0; j < 8; ++j) {
      s8v v = *(const s8v*)(kr + j * 8);
#pragma unroll
      for (int i = 0; i < 8; ++i) dot += qs[wid][j * 8 + i] * b2f((u16)v[i]);
    }
  }
  float vmax = (lane < SK_) ? dot : -INFINITY;
  float vsum = (lane < SK_) ? dot : 0.f;
  for (int off = 32; off; off >>= 1) {
    vmax = fmaxf(vmax, __shfl_xor(vmax, off));
    vsum += __shfl_xor(vsum, off);
  }
  if (lane == 0) Mout[g] = vmax - vsum / (float)L_;
}

// ---------------- radix-select top-40 (matches lax.top_k selection set) -----
__global__ __launch_bounds__(256) void radix_topk(const float* __restrict__ Mv,
                                                  int* __restrict__ top) {
  const int bh = blockIdx.x;
  const int t = threadIdx.x;
  const int base = t * 6;
  unsigned key[6];
#pragma unroll
  for (int i = 0; i < 6; ++i) {
    int ix = base + i;
    unsigned k = 0u;
    if (ix < L_) {
      union { float f; unsigned u; } c; c.f = Mv[(size_t)bh * L_ + ix];
      k = c.u ^ ((c.u & 0x80000000u) ? 0xFFFFFFFFu : 0x80000000u);
    }
    key[i] = k;
  }
  __shared__ int wred[4];
  __shared__ int s_a[256], s_b[256];
  unsigned prefix = 0u;
  for (int b = 31; b >= 0; --b) {
    unsigned cand = prefix | (1u << b);
    int c = 0;
#pragma unroll
    for (int i = 0; i < 6; ++i) c += (key[i] >= cand);
    for (int off = 32; off; off >>= 1) c += __shfl_xor(c, off);
    if ((t & 63) == 0) wred[t >> 6] = c;
    __syncthreads();
    int tot = wred[0] + wred[1] + wred[2] + wred[3];
    if (tot >= SK_) prefix = cand;
    __syncthreads();
  }
  const unsigned T = prefix;
  int gt = 0, tie = 0;
#pragma unroll
  for (int i = 0; i < 6; ++i) { gt += (key[i] > T); tie += (key[i] == T); }
  s_a[t] = gt; s_b[t] = tie;
  __syncthreads();
  for (int off = 1; off < 256; off <<= 1) {
    int va = (t >= off) ? s_a[t - off] : 0;
    int vb = (t >= off) ? s_b[t - off] : 0;
    __syncthreads();
    s_a[t] += va; s_b[t] += vb;
    __syncthreads();
  }
  const int n_strict = s_a[255];
  const int gt_base = s_a[t] - gt;
  const int tie_base = s_b[t] - tie;
  const int need = SK_ - n_strict;
  int lgt = 0, ltie = 0;
#pragma unroll
  for (int i = 0; i < 6; ++i) {
    int ix = base + i;
    if (key[i] > T) {
      top[bh * SK_ + gt_base + lgt] = ix; ++lgt;
    } else if (key[i] == T) {
      int r = tie_base + ltie; ++ltie;
      if (r < need) top[bh * SK_ + n_strict + r] = ix;
    }
  }
}

// ---------------- V^T build: VT[bh][64][LP_] from V columns, swizzled -------
__global__ __launch_bounds__(256) void transpose_v(const u16* __restrict__ src,
                                                   int stride, int voff0,
                                                   u16* __restrict__ VT) {
  int o = xswz(blockIdx.x, (B_ * H_ * 24) >> 3);
  int kt = o % 24, bh = o / 24;
  int h = bh & 7, b = bh >> 3;
  int kb = kt * 64;
  __shared__ u16 tile[64][72];
  int t = threadIdx.x;
#pragma unroll
  for (int rr = 0; rr < 2; ++rr) {
    int slot = rr * 256 + t;
    int key = slot >> 3, d = (slot & 7) * 8;
    int gk = kb + key; if (gk >= L_) gk = L_ - 1;
    s8v v = *(const s8v*)(src + (size_t)(b * L_ + gk) * stride + voff0 + h * 64 + d);
    *(s8v*)(&tile[key][d]) = v;
  }
  __syncthreads();
  int dim = t >> 2, k0 = (t & 3) * 16;
  u16 buf[16];
#pragma unroll
  for (int i = 0; i < 16; ++i) {
    int key = k0 + i;
    buf[i] = (kb + key < L_) ? tile[key][dim] : (u16)0;
  }
  *(s8v*)(VT + ((size_t)bh * 64 + dim) * LP_ + kb + k0) = *(s8v*)buf;
  *(s8v*)(VT + ((size_t)bh * 64 + dim) * LP_ + kb + k0 + 8) = *(s8v*)(buf + 8);
}

// ---------------- LDS-staged swapped-operand MFMA flash attention -----------
template<int MODE>
__global__ __launch_bounds__(256) void flash_attn(
    const u16* __restrict__ Qm, const u16* __restrict__ Kg,
    const u16* __restrict__ VT, const int* __restrict__ top,
    float* __restrict__ POf, u16* POa, u16* POb,
    float* __restrict__ PM, float* __restrict__ PL) {
  constexpr int QSTR = (MODE == 0) ? 512 : 1536;
  constexpr int KSTR = (MODE == 0) ? 512 : 1536;
  constexpr int TILES = (MODE == 0) ? 12 : 3;
  constexpr int NB = (MODE == 0) ? 48 : 8;
  __shared__ __align__(16) u16 Kt[64 * 64];        // [key][slot^(key&7)]
  __shared__ __align__(16) u16 Vt[64 * 64];        // [dim][slot^(dim&7)]
  __shared__ __align__(16) unsigned Xch[4][576];   // per-wave P exchange
  const int o = xswz(blockIdx.x, (B_ * H_ * NB) >> 3);
  int bh, sp, qb;
  if (MODE == 0) {
    bh = o / 48; int rem = o % 48; qb = rem >> 1; sp = rem & 1;
  } else {
    bh = o / 8; sp = o % 8; qb = 0;
  }
  const int h = bh & 7, b = bh >> 3;
  const int qoff = h * 64;
  const int koff = ((MODE == 0) ? 0 : 512) + h * 64;
  const int t = threadIdx.x, w = t >> 6, lane = t & 63;
  const int lg = lane >> 4, li = lane & 15;
  const u16* vtg = VT + (size_t)bh * 64 * LP_;
  unsigned* xw = Xch[w];
  u16* xw16 = (u16*)xw;

  int qrow;
  if (MODE == 0) {
    int q = qb * 64 + w * 16 + li;
    qrow = b * L_ + ((q < L_) ? q : (L_ - 1));
  } else {
    int u = w * 16 + li; if (u >= SK_) u = SK_ - 1;
    qrow = b * L_ + top[bh * SK_ + u];
  }
  s8v qf0 = *(const s8v*)(Qm + (size_t)qrow * QSTR + qoff + lg * 8);
  s8v qf1 = *(const s8v*)(Qm + (size_t)qrow * QSTR + qoff + 32 + lg * 8);

  f4 o4[4];                          // o4[n][r] = O^T[d=n*16+lg*4+r][q=li]
#pragma unroll
  for (int n = 0; n < 4; ++n) o4[n] = f4{0.f, 0.f, 0.f, 0.f};
  float m_run = -INFINITY, l_run = 0.f;   // per-lane (q=li)
  const int kt0 = sp * TILES;
  const int skey = lane >> 3;
  const int sslot = lane & 7;

#pragma unroll 1
  for (int ki = 0; ki < TILES; ++ki) {
    const int kb = (kt0 + ki) * 64;
#pragma unroll
    for (int j = 0; j < 2; ++j) {
      int row = w * 16 + j * 8 + skey;
      int gk = kb + row; if (gk >= L_) gk = L_ - 1;
      int ck = sslot ^ (row & 7);
      __builtin_amdgcn_global_load_lds(
          (const __attribute__((address_space(1))) void*)(Kg + (size_t)(b * L_ + gk) * KSTR + koff + ck * 8),
          (__attribute__((address_space(3))) void*)(Kt + (w * 16 + j * 8) * 64),
          16, 0, 0);
      int cv = sslot ^ (row & 7);
      __builtin_amdgcn_global_load_lds(
          (const __attribute__((address_space(1))) void*)(vtg + (size_t)row * LP_ + kb + cv * 8),
          (__attribute__((address_space(3))) void*)(Vt + (w * 16 + j * 8) * 64),
          16, 0, 0);
    }
    __syncthreads();
    f4 s[4];
#pragma unroll
    for (int c = 0; c < 4; ++c) {
      int key = c * 16 + li;
      s8v kf = *(const s8v*)(Kt + key * 64 + ((lg ^ (key & 7)) * 8));
      s8v kg2 = *(const s8v*)(Kt + key * 64 + (((lg + 4) ^ (key & 7)) * 8));
      f4 z = f4{0.f, 0.f, 0.f, 0.f};
      z = __builtin_amdgcn_mfma_f32_16x16x32_bf16(kf, qf0, z, 0, 0, 0);
      z = __builtin_amdgcn_mfma_f32_16x16x32_bf16(kg2, qf1, z, 0, 0, 0);
      s[c] = z * 0.125f;
    }
    if (kb + 64 > L_) {
#pragma unroll
      for (int c = 0; c < 4; ++c)
#pragma unroll
        for (int r = 0; r < 4; ++r)
          if (kb + c * 16 + lg * 4 + r >= L_) s[c][r] = -INFINITY;
    }
    float tm = -INFINITY;
#pragma unroll
    for (int c = 0; c < 4; ++c)
      tm = fmaxf(tm, fmaxf(fmaxf(s[c][0], s[c][1]), fmaxf(s[c][2], s[c][3])));
    tm = fmaxf(tm, __shfl_xor(tm, 16));
    tm = fmaxf(tm, __shfl_xor(tm, 32));
    float mn = fmaxf(m_run, tm);
    float sc = __expf(m_run - mn);
    float p[4][4];
    float rs = 0.f;
#pragma unroll
    for (int c = 0; c < 4; ++c)
#pragma unroll
      for (int r = 0; r < 4; ++r) { p[c][r] = __expf(s[c][r] - mn); rs += p[c][r]; }
    rs += __shfl_xor(rs, 16);
    rs += __shfl_xor(rs, 32);
    l_run = l_run * sc + rs;
    m_run = mn;
#pragma unroll
    for (int n = 0; n < 4; ++n) o4[n] *= sc;
#pragma unroll
    for (int c = 0; c < 4; ++c)
#pragma unroll
      for (int rp = 0; rp < 2; ++rp) {
        unsigned v = (unsigned)f2b(p[c][2 * rp]) | ((unsigned)f2b(p[c][2 * rp + 1]) << 16);
        xw[li * 36 + c * 8 + lg * 2 + rp] = v;
      }
    s8v pb0 = *(const s8v*)(xw + li * 36 + lg * 4);
    s8v pb1 = *(const s8v*)(xw + li * 36 + 16 + lg * 4);
#pragma unroll
    for (int n = 0; n < 4; ++n) {
      int dim = n * 16 + li;
      s8v vb0 = *(const s8v*)(Vt + dim * 64 + ((lg ^ (dim & 7)) * 8));
      o4[n] = __builtin_amdgcn_mfma_f32_16x16x32_bf16(vb0, pb0, o4[n], 0, 0, 0);
    }
#pragma unroll
    for (int n = 0; n < 4; ++n) {
      int dim = n * 16 + li;
      s8v vb1 = *(const s8v*)(Vt + dim * 64 + (((lg + 4) ^ (dim & 7)) * 8));
      o4[n] = __builtin_amdgcn_mfma_f32_16x16x32_bf16(vb1, pb1, o4[n], 0, 0, 0);
    }
    __syncthreads();
  }

  if (MODE == 0) {
#pragma unroll
    for (int n = 0; n < 4; ++n)
#pragma unroll
      for (int r = 0; r < 4; ++r)
        xw16[li * 72 + n * 16 + lg * 4 + r] = f2b(o4[n][r]);
    u16* PO = sp ? POb : POa;
    const int pid = (bh * 24 + qb) * 2 + sp;
    int q_local = lane >> 2, d0 = (lane & 3) * 16;
    int q = qb * 64 + w * 16 + q_local;
    s8v v0 = *(const s8v*)(xw16 + q_local * 72 + d0);
    s8v v1 = *(const s8v*)(xw16 + q_local * 72 + d0 + 8);
    if (q < L_) {
      u16* dst = PO + ((size_t)(b * L_ + q)) * DM_ + qoff + d0;
      *(s8v*)dst = v0;
      *(s8v*)(dst + 8) = v1;
    }
    if (lg == 0) {
      PM[pid * 64 + w * 16 + li] = m_run;
      PL[pid * 64 + w * 16 + li] = l_run;
    }
  } else {
    int base = (bh * 8 + sp) * 64 + w * 16 + li;
#pragma unroll
    for (int n = 0; n < 4; ++n)
#pragma unroll
      for (int r = 0; r < 4; ++r)
        POf[(size_t)base * 64 + n * 16 + lg * 4 + r] = o4[n][r];
    if (lg == 0) {
      PM[base] = m_run;
      PL[base] = l_run;
    }
  }
}

// ---------------- combine 2-way cross partials (POb == ctxb, in place) ------
__global__ __launch_bounds__(256) void combine_cross(const u16* __restrict__ PO0,
                                                     const float* __restrict__ PM,
                                                     const float* __restrict__ PL,
                                                     u16* ctxb) {
  int idx = blockIdx.x * 256 + threadIdx.x;
  int row = idx >> 9, col = idx & 511;
  int b = row / L_, q = row - b * L_;
  int h = col >> 6;
  int bh = b * 8 + h, qbk = q >> 6, qi = q & 63;
  int p0 = ((bh * 24 + qbk) * 2) * 64 + qi;
  float m0 = PM[p0], m1 = PM[p0 + 64];
  float l0 = PL[p0], l1 = PL[p0 + 64];
  float M = fmaxf(m0, m1);
  float w0 = __expf(m0 - M), w1 = __expf(m1 - M);
  float inv = 1.f / (w0 * l0 + w1 * l1);
  float o0 = b2f(PO0[idx]);
  float o1 = b2f(ctxb[idx]);
  ctxb[idx] = f2b((w0 * o0 + w1 * o1) * inv);
}

// ---------------- combine split-K partials -> ctt ----------------------------
__global__ __launch_bounds__(256) void combine_prob(const float* __restrict__ PO,
                                                    const float* __restrict__ PM,
                                                    const float* __restrict__ PL,
                                                    float* __restrict__ ctt) {
  int bh = blockIdx.x;
  int t = threadIdx.x;
  int u = t >> 2, dg = (t & 3) * 16;
  if (u >= SK_) return;
  float M = -INFINITY;
  for (int s = 0; s < 8; ++s) M = fmaxf(M, PM[(bh * 8 + s) * 64 + u]);
  float wgt[8];
  float den = 0.f;
  for (int s = 0; s < 8; ++s) {
    wgt[s] = __expf(PM[(bh * 8 + s) * 64 + u] - M);
    den += wgt[s] * PL[(bh * 8 + s) * 64 + u];
  }
  float inv = 1.f / den;
  for (int d = dg; d < dg + 16; ++d) {
    float acc = 0.f;
    for (int s = 0; s < 8; ++s) acc += wgt[s] * PO[(((size_t)bh * 8 + s) * 64 + u) * 64 + d];
    ctt[((size_t)bh * SK_ + u) * 64 + d] = acc * inv;
  }
}

// ---------------- V mean: 8-way partial + combine, swizzled -----------------
__global__ __launch_bounds__(256) void vmean_part(const u16* __restrict__ qkv,
                                                  float* __restrict__ part) {
  int g = xswz(blockIdx.x, (B_ * H_ * 8) >> 3);
  int bh = g >> 3, seg = g & 7;
  int h = bh & 7, b = bh >> 3;
  int lane = threadIdx.x & 63, grp = threadIdx.x >> 6;
  int k0 = seg * 190, k1 = k0 + 190;
  float acc = 0.f;
  for (int k = k0 + grp; k < k1; k += 4)
    acc += b2f(qkv[((size_t)b * L_ + k) * 1536 + 1024 + h * 64 + lane]);
  __shared__ float pv[4][64];
  pv[grp][lane] = acc;
  __syncthreads();
  if (threadIdx.x < 64)
    part[g * 64 + threadIdx.x] =
        pv[0][threadIdx.x] + pv[1][threadIdx.x] + pv[2][threadIdx.x] + pv[3][threadIdx.x];
}

__global__ __launch_bounds__(256) void vmean_comb(const float* __restrict__ part,
                                                  float* __restrict__ vmean) {
  int idx = blockIdx.x * 256 + threadIdx.x;
  int bh = idx >> 6, d = idx & 63;
  float s = 0.f;
#pragma unroll
  for (int seg = 0; seg < 8; ++seg) s += part[(bh * 8 + seg) * 64 + d];
  vmean[idx] = s / (float)L_;
}

// ---------------- ctx = broadcast vmean (bf16), then scatter top ------------
__global__ __launch_bounds__(256) void fill_ctx(const float* __restrict__ vmean,
                                                u16* __restrict__ ctxb) {
  int idx = blockIdx.x * 256 + threadIdx.x;
  int d = idx % 64;
  int h = (idx / 64) % H_;
  int b = idx / (L_ * DM_);
  ctxb[idx] = f2b(vmean[(b * H_ + h) * 64 + d]);
}

__global__ __launch_bounds__(256) void scatter_ctx(const float* __restrict__ ctt,
                                                   const int* __restrict__ top,
                                                   u16* __restrict__ ctxb) {
  int idx = blockIdx.x * 256 + threadIdx.x;
  int d = idx % 64;
  int u = (idx / 64) % SK_;
  int bh = idx / (64 * SK_);
  int h = bh % H_, b = bh / H_;
  int l = top[bh * SK_ + u];
  ctxb[((size_t)b * L_ + l) * DM_ + h * 64 + d] = f2b(ctt[idx]);
}

// ---------------- host side --------------------------------------------------
extern "C" void kernel_launch(void* const* d_in, const int* in_sizes, int n_in,
                              void* d_out, int out_size, void* d_ws, size_t ws_size,
                              hipStream_t stream) {
  const float* inflow   = (const float*)d_in[4];
  const float* W_emb_e  = (const float*)d_in[5];
  const float* b_emb_e  = (const float*)d_in[6];
  const float* W_emb_d  = (const float*)d_in[7];
  const float* b_emb_d  = (const float*)d_in[8];
  const float* enc_Wqkv = (const float*)d_in[9];
  const float* enc_bqkv = (const float*)d_in[10];
  const float* enc_Wo   = (const float*)d_in[11];
  const float* enc_bo   = (const float*)d_in[12];
  const float* enc_ln1g = (const float*)d_in[13];
  const float* enc_ln1b = (const float*)d_in[14];
  const float* enc_Wf1  = (const float*)d_in[15];
  const float* enc_bf1  = (const float*)d_in[16];
  const float* enc_Wf2  = (const float*)d_in[17];
  const float* enc_bf2  = (const float*)d_in[18];
  const float* enc_ln2g = (const float*)d_in[19];
  const float* enc_ln2b = (const float*)d_in[20];
  const float* enc_ng   = (const float*)d_in[21];
  const float* enc_nb   = (const float*)d_in[22];
  const float* dec_Wqkv = (const float*)d_in[23];
  const float* dec_bqkv = (const float*)d_in[24];
  const float* dec_Wo_s = (const float*)d_in[25];
  const float* dec_bo_s = (const float*)d_in[26];
  const float* dec_ln1g = (const float*)d_in[27];
  const float* dec_ln1b = (const float*)d_in[28];
  const float* dec_Wq_c = (const float*)d_in[29];
  const float* dec_bq_c = (const float*)d_in[30];
  const float* dec_Wkv  = (const float*)d_in[31];
  const float* dec_bkv  = (const float*)d_in[32];
  const float* dec_Wo_c = (const float*)d_in[33];
  const float* dec_bo_c = (const float*)d_in[34];
  const float* dec_ln2g = (const float*)d_in[35];
  const float* dec_ln2b = (const float*)d_in[36];
  const float* dec_Wf1  = (const float*)d_in[37];
  const float* dec_bf1  = (const float*)d_in[38];
  const float* dec_Wf2  = (const float*)d_in[39];
  const float* dec_bf2  = (const float*)d_in[40];
  const float* dec_ln3g = (const float*)d_in[41];
  const float* dec_ln3b = (const float*)d_in[42];
  const float* W_proj   = (const float*)d_in[43];
  const float* b_proj   = (const float*)d_in[44];
  const float* W1       = (const float*)d_in[45];
  const float* b1       = (const float*)d_in[46];
  const float* W3       = (const float*)d_in[47];
  const float* b3       = (const float*)d_in[48];
  const int*   samp     = (const int*)d_in[49];
  float* out = (float*)d_out;

  float* ws  = (float*)d_ws;
  float* PE  = ws;                       // 778240 f (dead after embeds -> PM/PL)
  float* X   = PE + 778240;              // 72960 f
  float* ACT = X + 72960;                // 3112960 f
  float* REG = ACT + 3112960;            // 6291456 f shared region
  float* MME = REG + 6291456;            // 48640 f (VME8 overlay after topk)
  float* CTT = MME + 48640;              // 81920 f
  float* VME = CTT + 81920;              // 2048 f
  int*   TOP = (int*)(VME + 2048);       // 1280 i
  float* TAIL = VME + 2048 + 1280;
  u16* ENCb = (u16*)TAIL;                       // 6144*512 u16
  u16* DECb = (u16*)(TAIL + 1572864);
  u16* CTXb = (u16*)(TAIL + 2 * 1572864);
  u16* WBF  = (u16*)(TAIL + 3 * 1572864);       // 10485760 u16

  // region overlays (prob phase)
  u16* QKVb = (u16*)REG;                 // [6144][1536]
  u16* FFb  = (u16*)REG;                 // [6144][2048]
  u16* VT   = (u16*)REG + 9437184;       // [32][64][1536] u16
  // region overlays (cross phase)
  u16* QCb  = (u16*)REG;                 // [6144][512]
  u16* Kc   = (u16*)REG + 3145728;       // [6144][512]
  u16* Vc   = (u16*)REG + 6291456;       // [6144][512]; becomes PO-split0 after transpose
  // prob split-K partials overlay CTXb (rebuilt by fill_ctx afterwards)
  float* POp = (float*)CTXb;             // 32*8*64*64 f
  float* PMp = POp + 1048576;
  float* PLp = PMp + 16384;
  // cross partial stats in dead PE region (32*24*2*64 = 98304 each)
  float* PMc = PE;
  float* PLc = PE + 98304;
  float* VME8 = MME;                     // 16384 f (after radix_topk)

  auto GB = [&](const u16* A, const u16* Bt, const float* bias, const float* res,
                float* Cf, u16* Cb, int N, int K, int act) {
    if (N <= 512) {
      dim3 g(N / 128, MP_ / 64);
      gemm_bf16<64><<<g, 256, 0, stream>>>(A, Bt, bias, res, Cf, Cb, N, K, act);
    } else {
      dim3 g(N / 128, MP_ / 128);
      gemm_bf16<128><<<g, 256, 0, stream>>>(A, Bt, bias, res, Cf, Cb, N, K, act);
    }
  };
  auto PROB = [&](const int* sidx) {
    probM<<<B_ * H_ * L_ / 4, 256, 0, stream>>>(QKVb, sidx, MME);
    radix_topk<<<B_ * H_, 256, 0, stream>>>(MME, TOP);
    transpose_v<<<B_ * H_ * 24, 256, 0, stream>>>(QKVb, 1536, 1024, VT);
    flash_attn<1><<<B_ * H_ * 8, 256, 0, stream>>>(QKVb, QKVb, VT, TOP, POp,
                                                   nullptr, nullptr, PMp, PLp);
    combine_prob<<<B_ * H_, 256, 0, stream>>>(POp, PMp, PLp, CTT);
    vmean_part<<<B_ * H_ * 8, 256, 0, stream>>>(QKVb, VME8);
    vmean_comb<<<8, 256, 0, stream>>>(VME8, VME);
    fill_ctx<<<ML_ * DM_ / 256, 256, 0, stream>>>(VME, CTXb);
    scatter_ctx<<<B_ * H_ * SK_ * 64 / 256, 256, 0, stream>>>(CTT, TOP, CTXb);
  };

  pe_kernel<<<(L_ * DM_ + 255) / 256, 256, 0, stream>>>(PE);
  extract_x<<<(ML_ * 12 + 255) / 256, 256, 0, stream>>>(inflow, X);

  // one fused weight-conversion dispatch (WBF slots are contiguous)
  {
    CvtArgs a;
    const float* s[15] = {
      enc_Wqkv, enc_Wqkv + 512 * 1536, enc_Wo, enc_Wo + 512 * 512,
      enc_Wf1, enc_Wf1 + 512 * 2048, enc_Wf2, enc_Wf2 + 2048 * 512,
      dec_Wqkv, dec_Wo_s, dec_Wq_c, dec_Wkv, dec_Wo_c, dec_Wf1, dec_Wf2 };
    unsigned cum[16] = { 0u, 786432u, 1572864u, 1835008u, 2097152u, 3145728u,
                         4194304u, 5242880u, 6291456u, 7077888u, 7340032u,
                         7602176u, 8126464u, 8388608u, 9437184u, 10485760u };
    unsigned lk[15] = { 9, 9, 9, 9, 9, 9, 11, 11, 9, 9, 9, 9, 9, 9, 11 };
    for (int i = 0; i < 15; ++i) { a.src[i] = s[i]; a.lk[i] = lk[i]; }
    for (int i = 0; i < 16; ++i) a.cum[i] = cum[i];
    cvt_all<<<10485760 / 256, 256, 0, stream>>>(a, WBF);
  }
  u16* Wt_qkv_e0 = WBF + 0;
  u16* Wt_qkv_e1 = WBF + 786432;
  u16* Wt_o_e0   = WBF + 1572864;
  u16* Wt_o_e1   = WBF + 1835008;
  u16* Wt_f1_e0  = WBF + 2097152;
  u16* Wt_f1_e1  = WBF + 3145728;
  u16* Wt_f2_e0  = WBF + 4194304;
  u16* Wt_f2_e1  = WBF + 5242880;
  u16* Wt_qkv_d  = WBF + 6291456;
  u16* Wt_o_s    = WBF + 7077888;
  u16* Wt_q_c    = WBF + 7340032;
  u16* Wt_kv_c   = WBF + 7602176;
  u16* Wt_o_c    = WBF + 8126464;
  u16* Wt_f1_d   = WBF + 8388608;
  u16* Wt_f2_d   = WBF + 9437184;

  // ---------------- encoder ----------------
  embed_fused<<<MP_ / 4, 256, 0, stream>>>(X, W_emb_e, b_emb_e, PE, ACT, ENCb);

  const u16* Wqkv_e[2] = {Wt_qkv_e0, Wt_qkv_e1};
  const u16* Wo_e[2]   = {Wt_o_e0, Wt_o_e1};
  const u16* Wf1_e[2]  = {Wt_f1_e0, Wt_f1_e1};
  const u16* Wf2_e[2]  = {Wt_f2_e0, Wt_f2_e1};
  for (int i = 0; i < 2; ++i) {
    GB(ENCb, Wqkv_e[i], enc_bqkv + i * 1536, nullptr, nullptr, QKVb, 1536, 512, 0);
    PROB(samp + (size_t)i * L_ * SK_);
    GB(CTXb, Wo_e[i], enc_bo + i * 512, ACT, ACT, nullptr, 512, 512, 0);
    layernorm_ip<<<ML_ / 4, 256, 0, stream>>>(ACT, enc_ln1g + i * 512, enc_ln1b + i * 512, ENCb);
    GB(ENCb, Wf1_e[i], enc_bf1 + i * 2048, nullptr, nullptr, FFb, 2048, 512, 1);
    GB(FFb, Wf2_e[i], enc_bf2 + i * 512, ACT, ACT, nullptr, 512, 2048, 0);
    layernorm_ip<<<ML_ / 4, 256, 0, stream>>>(ACT, enc_ln2g + i * 512, enc_ln2b + i * 512, ENCb);
  }
  layernorm_ip<<<ML_ / 4, 256, 0, stream>>>(ACT, enc_ng, enc_nb, ENCb);

  // ---------------- decoder ----------------
  embed_fused<<<MP_ / 4, 256, 0, stream>>>(X, W_emb_d, b_emb_d, PE, ACT, DECb);
  GB(DECb, Wt_qkv_d, dec_bqkv, nullptr, nullptr, QKVb, 1536, 512, 0);
  PROB(samp + (size_t)2 * L_ * SK_);
  GB(CTXb, Wt_o_s, dec_bo_s, ACT, ACT, nullptr, 512, 512, 0);
  layernorm_ip<<<ML_ / 4, 256, 0, stream>>>(ACT, dec_ln1g, dec_ln1b, DECb);

  // cross attention: Q, K, V as separate [*,512] GEMMs; V buffer becomes split-0
  GB(DECb, Wt_q_c, dec_bq_c, nullptr, nullptr, QCb, 512, 512, 0);
  GB(ENCb, Wt_kv_c, dec_bkv, nullptr, nullptr, Kc, 512, 512, 0);
  GB(ENCb, Wt_kv_c + 512 * 512, dec_bkv + 512, nullptr, nullptr, Vc, 512, 512, 0);
  transpose_v<<<B_ * H_ * 24, 256, 0, stream>>>(Vc, 512, 0, VT);
  flash_attn<0><<<B_ * H_ * 48, 256, 0, stream>>>(QCb, Kc, VT, nullptr, nullptr,
                                                  Vc, CTXb, PMc, PLc);
  combine_cross<<<ML_ * DM_ / 256, 256, 0, stream>>>(Vc, PMc, PLc, CTXb);
  GB(CTXb, Wt_o_c, dec_bo_c, ACT, ACT, nullptr, 512, 512, 0);
  layernorm_ip<<<ML_ / 4, 256, 0, stream>>>(ACT, dec_ln2g, dec_ln2b, DECb);

  GB(DECb, Wt_f1_d, dec_bf1, nullptr, nullptr, FFb, 2048, 512, 1);
  GB(FFb, Wt_f2_d, dec_bf2, ACT, ACT, nullptr, 512, 2048, 0);
  layernorm_ip<<<ML_ / 4, 256, 0, stream>>>(ACT, dec_ln3g, dec_ln3b, DECb);

  // fused head
  head_fused<<<ML_ / 4, 256, 0, stream>>>(ACT, X, W_proj, b_proj, W1, b1, W3, b3, out);
}